// Round 13
// baseline (1115.977 us; speedup 1.0000x reference)
//
#include <hip/hip_runtime.h>

#define DEV __device__ __forceinline__

constexpr int   kH  = 128;
constexpr int   kN  = 32768;    // B*NP rows
constexpr int   kE  = 262144;   // edges
constexpr float kEPS = 1e-5f;
constexpr float kLOG2E = 1.4426950408889634f;

typedef short  s16x8 __attribute__((ext_vector_type(8)));
typedef ushort u16x8 __attribute__((ext_vector_type(8)));
typedef ushort u16x4 __attribute__((ext_vector_type(4)));
typedef float  f32x4 __attribute__((ext_vector_type(4)));

DEV float sigmoidf_(float v) { return 1.f / (1.f + __expf(-v)); }

DEV ushort f2bf(float f) {  // RTNE f32 -> bf16
  union { float f; unsigned u; } x{f};
  unsigned r = x.u + 0x7fff + ((x.u >> 16) & 1);
  return (ushort)(r >> 16);
}
DEV float bf2f(ushort u) {
  union { unsigned u; float f; } x{(unsigned)u << 16};
  return x.f;
}
DEV float4 L4(const float* p) { return *(const float4*)p; }
DEV s16x8 pk8(const float* v) {
  s16x8 r;
#pragma unroll
  for (int j = 0; j < 8; ++j) r[j] = (short)f2bf(v[j]);
  return r;
}

// ---------------- batchnorm column stats, vectorized ----------------
__global__ __launch_bounds__(256) void bn_partial2(const float* __restrict__ X, int R,
                                                   float* __restrict__ sum,
                                                   float* __restrict__ sq) {
  int t = threadIdx.x;
  int cg = (t & 31) * 4, rs = t >> 5;
  float sx = 0.f, sy = 0.f, sz = 0.f, sw = 0.f;
  float qx = 0.f, qy = 0.f, qz = 0.f, qw = 0.f;
  for (int r = blockIdx.x * 8 + rs; r < R; r += gridDim.x * 8) {
    float4 v = L4(X + (size_t)r * 128 + cg);
    sx += v.x; sy += v.y; sz += v.z; sw += v.w;
    qx = fmaf(v.x, v.x, qx); qy = fmaf(v.y, v.y, qy);
    qz = fmaf(v.z, v.z, qz); qw = fmaf(v.w, v.w, qw);
  }
  __shared__ float red[8][256];
  red[rs][(t & 31) * 8 + 0] = sx; red[rs][(t & 31) * 8 + 1] = sy;
  red[rs][(t & 31) * 8 + 2] = sz; red[rs][(t & 31) * 8 + 3] = sw;
  red[rs][(t & 31) * 8 + 4] = qx; red[rs][(t & 31) * 8 + 5] = qy;
  red[rs][(t & 31) * 8 + 6] = qz; red[rs][(t & 31) * 8 + 7] = qw;
  __syncthreads();
  if (rs == 0) {
    int cq = t & 31;
#pragma unroll
    for (int jj = 0; jj < 4; ++jj) {
      float S = 0.f, Q = 0.f;
#pragma unroll
      for (int i = 0; i < 8; ++i) {
        S += red[i][cq * 8 + jj];
        Q += red[i][cq * 8 + 4 + jj];
      }
      atomicAdd(&sum[cq * 4 + jj], S);
      atomicAdd(&sq[cq * 4 + jj], Q);
    }
  }
}

__global__ void bn_finalize(const float* __restrict__ acc,
                            const float* __restrict__ gx, const float* __restrict__ bx,
                            const float* __restrict__ ge, const float* __restrict__ be,
                            float* __restrict__ coef) {
  int t = threadIdx.x;
  if (t < 128) {
    float m  = acc[t]       * (1.f / 32768.f);
    float v  = acc[128 + t] * (1.f / 32768.f) - m * m;
    float sc = gx[t] * rsqrtf(v + kEPS);
    coef[t] = sc; coef[128 + t] = bx[t] - m * sc;
  } else {
    int c = t - 128;
    float m  = acc[256 + c] * (1.f / 262144.f);
    float v  = acc[384 + c] * (1.f / 262144.f) - m * m;
    float sc = ge[c] * rsqrtf(v + kEPS);
    coef[256 + c] = sc; coef[384 + c] = be[c] - m * sc;
  }
}

__global__ void bn_apply(const float* __restrict__ x, const float* __restrict__ coef,
                         float* __restrict__ xn) {
  size_t i = ((size_t)blockIdx.x * 256 + threadIdx.x) * 4;
  int c = (int)(i & 127);
  float4 v = L4(x + i);
  float4 s = L4(coef + c), h = L4(coef + 128 + c);
  float4 o;
  o.x = fmaf(v.x, s.x, h.x); o.y = fmaf(v.y, s.y, h.y);
  o.z = fmaf(v.z, s.z, h.z); o.w = fmaf(v.w, s.w, h.w);
  *(float4*)(xn + i) = o;
}

__global__ void a2prep(const float* __restrict__ A_log, float* __restrict__ A2) {
  int i = blockIdx.x * 256 + threadIdx.x;
  A2[i] = -__expf(A_log[i]) * kLOG2E;
}

// convert weight W[K][N] f32 -> Wt[Npad][K] bf16 (transposed, zero-padded cols)
__global__ void prep_wt(const float* __restrict__ W, int Kdim, int Ncols,
                        ushort* __restrict__ Wt) {
  int idx = blockIdx.x * 256 + threadIdx.x;
  int n = idx / Kdim, k = idx - n * Kdim;
  float v = (n < Ncols) ? W[(size_t)k * Ncols + n] : 0.f;
  Wt[idx] = f2bf(v);
}

__global__ void prep_uv(const float* __restrict__ cw1, const float* __restrict__ g1,
                        ushort* __restrict__ Wt) {
  int idx = blockIdx.x * 256 + threadIdx.x;  // 512*128
  int n = idx >> 7, k = idx & 127;
  int krow = (n < 256) ? k : 128 + k;
  int ncol = n & 255;
  Wt[idx] = f2bf(g1[krow] * cw1[(size_t)krow * 256 + ncol]);
}

// vecs layout: G1[256] B1c[256] G2[128] B2c[128] G3[2] B3c[2]
__global__ void prep_vecs(const float* __restrict__ cw1, const float* __restrict__ b1v,
                          const float* __restrict__ cb1,
                          const float* __restrict__ cw2, const float* __restrict__ g2v,
                          const float* __restrict__ b2v, const float* __restrict__ cb2,
                          const float* __restrict__ cw3, const float* __restrict__ g3v,
                          const float* __restrict__ b3v, const float* __restrict__ cb3,
                          const float* __restrict__ g1v, float* __restrict__ vecs) {
  int t = threadIdx.x;
  {
    float gs = 0.f, bs = 0.f;
    for (int k = 0; k < 256; ++k) {
      float w = cw1[(size_t)k * 256 + t];
      gs = fmaf(g1v[k], w, gs);
      bs = fmaf(b1v[k], w, bs);
    }
    vecs[t] = gs; vecs[256 + t] = bs + cb1[t];
  }
  if (t < 128) {
    float gs = 0.f, bs = 0.f;
    for (int k = 0; k < 256; ++k) {
      float w = cw2[(size_t)k * 128 + t];
      gs = fmaf(g2v[k], w, gs);
      bs = fmaf(b2v[k], w, bs);
    }
    vecs[512 + t] = gs; vecs[640 + t] = bs + cb2[t];
  }
  if (t < 2) {
    float gs = 0.f, bs = 0.f;
    for (int c = 0; c < 128; ++c) {
      float w = cw3[c * 2 + t];
      gs = fmaf(g3v[c], w, gs);
      bs = fmaf(b3v[c], w, bs);
    }
    vecs[768 + t] = gs; vecs[770 + t] = bs + cb3[t];
  }
}

// ---------------- edge sort (counting sort by dst) ----------------
__global__ void hist_kernel(const int* __restrict__ dst, int* __restrict__ cnt) {
  int e = blockIdx.x * 256 + threadIdx.x;
  atomicAdd(&cnt[dst[e]], 1);
}

__global__ __launch_bounds__(1024) void scan32k(const int* __restrict__ cnt,
                                                int* __restrict__ base,
                                                int* __restrict__ run) {
  __shared__ int part[1024];
  int t = threadIdx.x;
  int loc[32]; int s = 0;
  const int* p = cnt + t * 32;
#pragma unroll
  for (int i = 0; i < 32; ++i) { loc[i] = s; s += p[i]; }
  part[t] = s;
  __syncthreads();
  for (int o = 1; o < 1024; o <<= 1) {
    int v = (t >= o) ? part[t - o] : 0;
    __syncthreads();
    part[t] += v;
    __syncthreads();
  }
  int ex = part[t] - s;
#pragma unroll
  for (int i = 0; i < 32; ++i) {
    int b = ex + loc[i];
    base[t * 32 + i] = b; run[t * 32 + i] = b;
  }
  if (t == 1023) base[32768] = part[1023];
}

__global__ void scatter_ids(const int* __restrict__ dst, int* __restrict__ run,
                            int* __restrict__ eorder) {
  int e = blockIdx.x * 256 + threadIdx.x;
  int p = atomicAdd(&run[dst[e]], 1);
  eorder[p] = e;
}

// agg[v] = sum over sorted in-edges: relu(msg0[e] + lin_b + xn[src[e]])
__global__ __launch_bounds__(256) void agg_fused(
    const ushort* __restrict__ msg0, const float* __restrict__ xn,
    const int* __restrict__ eorder, const int* __restrict__ base,
    const int* __restrict__ src, const float* __restrict__ lin_b,
    float* __restrict__ agg) {
  int node = blockIdx.x * 2 + (threadIdx.x >> 7);
  int c = threadIdx.x & 127;
  int b0 = base[node], b1 = base[node + 1];
  float bias = lin_b[c];
  float s = 0.f;
  for (int j = b0; j < b1; ++j) {
    int e = eorder[j];
    float m = bf2f(msg0[(size_t)e * 128 + c]) + bias + xn[(size_t)src[e] * 128 + c];
    s += fmaxf(m, 0.f);
  }
  agg[(size_t)node * 128 + c] = s;
}

// per-node sum & sumsq of h rows (for edge LN1 stats)
__global__ void s12_kernel(const float* __restrict__ h, float* __restrict__ s1,
                           float* __restrict__ s2) {
  int wid = threadIdx.x >> 6, lane = threadIdx.x & 63;
  int r = blockIdx.x * 4 + wid;
  const float* row = h + (size_t)r * 128;
  float v0 = row[lane], v1 = row[lane + 64];
  float s = v0 + v1;
  float q = v0 * v0 + v1 * v1;
#pragma unroll
  for (int o = 32; o; o >>= 1) { s += __shfl_xor(s, o); q += __shfl_xor(q, o); }
  if (lane == 0) { s1[r] = s; s2[r] = q; }
}

// ---------------- rowwise LN stats (mamba) ----------------
__global__ void stats_rows(const float* __restrict__ X, float* __restrict__ mu,
                           float* __restrict__ rs) {
  int wid = threadIdx.x >> 6, lane = threadIdx.x & 63;
  int r = blockIdx.x * 4 + wid;
  const float* row = X + (size_t)r * 128;
  float v0 = row[lane], v1 = row[lane + 64];
  float s = v0 + v1;
#pragma unroll
  for (int o = 32; o; o >>= 1) s += __shfl_xor(s, o);
  float m = s * (1.f / 128.f);
  float d0 = v0 - m, d1 = v1 - m;
  float q = d0 * d0 + d1 * d1;
#pragma unroll
  for (int o = 32; o; o >>= 1) q += __shfl_xor(q, o);
  if (lane == 0) { mu[r] = m; rs[r] = rsqrtf(q * (1.f / 128.f) + kEPS); }
}

// ---------------- A-load functors: ld8 returns bf16x8 ---------------------
struct ALPlainF {  // f32 source
  const float* A; int lda;
  DEV s16x8 ld8(int r, int k) const {
    float b[8];
    const float* p = A + (size_t)r * lda + k;
    *(float4*)b = L4(p); *(float4*)(b + 4) = L4(p + 4);
    return pk8(b);
  }
};
struct ALBf {  // already-bf16 source, pure copy
  const ushort* A; int lda;
  DEV s16x8 ld8(int r, int k) const {
    return *(const s16x8*)(A + (size_t)r * lda + k);
  }
};
struct ALBN {
  const float* A; const float* coef;
  DEV s16x8 ld8(int r, int k) const {
    const float* p = A + (size_t)r * 128 + k;
    float4 a0 = L4(p), a1 = L4(p + 4);
    float4 s0 = L4(coef + k), s1 = L4(coef + k + 4);
    float4 h0 = L4(coef + 128 + k), h1 = L4(coef + 132 + k);
    float b[8];
    b[0] = fmaf(a0.x, s0.x, h0.x); b[1] = fmaf(a0.y, s0.y, h0.y);
    b[2] = fmaf(a0.z, s0.z, h0.z); b[3] = fmaf(a0.w, s0.w, h0.w);
    b[4] = fmaf(a1.x, s1.x, h1.x); b[5] = fmaf(a1.y, s1.y, h1.y);
    b[6] = fmaf(a1.z, s1.z, h1.z); b[7] = fmaf(a1.w, s1.w, h1.w);
    return pk8(b);
  }
};
struct ALAdd2 {
  const float* X; const float* Y;
  DEV s16x8 ld8(int r, int k) const {
    const float* p = X + (size_t)r * 128 + k;
    const float* q = Y + (size_t)r * 128 + k;
    float4 a0 = L4(p), a1 = L4(p + 4), b0 = L4(q), b1 = L4(q + 4);
    float b[8];
    b[0] = a0.x + b0.x; b[1] = a0.y + b0.y; b[2] = a0.z + b0.z; b[3] = a0.w + b0.w;
    b[4] = a1.x + b1.x; b[5] = a1.y + b1.y; b[6] = a1.z + b1.z; b[7] = a1.w + b1.w;
    return pk8(b);
  }
};
struct ALLN {
  const float* A; int lda; const float* mu; const float* rs;
  const float* g; const float* b;
  DEV s16x8 ld8(int r, int k) const {
    float m = mu[r], s = rs[r];
    const float* p = A + (size_t)r * lda + k;
    float4 a0 = L4(p), a1 = L4(p + 4);
    float4 g0 = L4(g + k), g1 = L4(g + k + 4), b0 = L4(b + k), b1 = L4(b + k + 4);
    float o[8];
    o[0] = fmaf((a0.x - m) * s, g0.x, b0.x); o[1] = fmaf((a0.y - m) * s, g0.y, b0.y);
    o[2] = fmaf((a0.z - m) * s, g0.z, b0.z); o[3] = fmaf((a0.w - m) * s, g0.w, b0.w);
    o[4] = fmaf((a1.x - m) * s, g1.x, b1.x); o[5] = fmaf((a1.y - m) * s, g1.y, b1.y);
    o[6] = fmaf((a1.z - m) * s, g1.z, b1.z); o[7] = fmaf((a1.w - m) * s, g1.w, b1.w);
    return pk8(o);
  }
};
struct ALMambaY {  // (scan_y + Dm*xc) * silu(z), all bf16 inputs
  const ushort* y; const ushort* xc; const ushort* xz; const float* Dm;
  DEV s16x8 ld8(int r, int k) const {
    u16x8 yv = *(const u16x8*)(y + (size_t)r * 256 + k);
    u16x8 cv = *(const u16x8*)(xc + (size_t)r * 256 + k);
    u16x8 zv = *(const u16x8*)(xz + (size_t)r * 512 + 256 + k);
    s16x8 o;
#pragma unroll
    for (int j = 0; j < 8; ++j) {
      float zf = bf2f(zv[j]);
      float val = fmaf(Dm[k + j], bf2f(cv[j]), bf2f(yv[j])) * (zf * sigmoidf_(zf));
      o[j] = (short)f2bf(val);
    }
    return o;
  }
};

struct EPStore {
  float* C; int ldc;
  DEV void operator()(int r, int c, float v) const { C[(size_t)r * ldc + c] = v; }
};
struct EPStoreBf {
  ushort* C; int ldc;
  DEV void operator()(int r, int c, float v) const { C[(size_t)r * ldc + c] = f2bf(v); }
};
struct EPBiasLeakyBf {
  ushort* C; int ldc; const float* bias;
  DEV void operator()(int r, int c, float v) const {
    v += bias[c];
    v = v >= 0.f ? v : 0.01f * v;
    C[(size_t)r * ldc + c] = f2bf(v);
  }
};
struct EPBiasRelu {
  float* C; int ldc; const float* bias;
  DEV void operator()(int r, int c, float v) const {
    C[(size_t)r * ldc + c] = fmaxf(v + bias[c], 0.f);
  }
};
struct EPResidH {
  float* h;
  DEV void operator()(int r, int c, float v) const {
    size_t i = (size_t)r * 128 + c; h[i] = h[i] + v;
  }
};

// ------------- bf16 MFMA GEMM: 128x128 tile, BK=64, 256 thr (4 waves 2x2) ---
template <class AL, class EP>
__global__ __launch_bounds__(256) void gemm_mfma(AL aload, const ushort* __restrict__ Wt,
                                                 int Kdim, int Ncols, EP epi) {
  __shared__ __align__(16) char lds[32768];
  const int tid = threadIdx.x;
  const int lane = tid & 63;
  const int w = tid >> 6;
  const int wr = w >> 1, wc = w & 1;
  const int row0 = blockIdx.x * 128, col0 = blockIdx.y * 128;
  const int sm = tid >> 3;
  const int sk = (tid & 7) * 8;
  f32x4 acc[4][4];
#pragma unroll
  for (int i = 0; i < 4; ++i)
#pragma unroll
    for (int j = 0; j < 4; ++j) acc[i][j] = f32x4{0.f, 0.f, 0.f, 0.f};

  for (int kt = 0; kt < Kdim; kt += 64) {
#pragma unroll
    for (int i = 0; i < 4; ++i) {
      int n = i * 32 + sm;
      s16x8 v = *(const s16x8*)(Wt + (size_t)(col0 + n) * Kdim + kt + sk);
      *(s16x8*)(lds + 16384 + ((n * 128 + sk * 2) ^ ((n & 7) << 4))) = v;
    }
#pragma unroll
    for (int i = 0; i < 4; ++i) {
      int m = i * 32 + sm;
      s16x8 v = aload.ld8(row0 + m, kt + sk);
      *(s16x8*)(lds + ((m * 128 + sk * 2) ^ ((m & 7) << 4))) = v;
    }
    __syncthreads();
#pragma unroll
    for (int ks = 0; ks < 2; ++ks) {
      const int kb = ks * 64 + (lane >> 4) * 16;
      s16x8 av[4], bv[4];
#pragma unroll
      for (int i = 0; i < 4; ++i) {
        int r = wr * 64 + i * 16 + (lane & 15);
        av[i] = *(const s16x8*)(lds + ((r * 128 + kb) ^ ((r & 7) << 4)));
      }
#pragma unroll
      for (int j = 0; j < 4; ++j) {
        int n = wc * 64 + j * 16 + (lane & 15);
        bv[j] = *(const s16x8*)(lds + 16384 + ((n * 128 + kb) ^ ((n & 7) << 4)));
      }
#pragma unroll
      for (int i = 0; i < 4; ++i)
#pragma unroll
        for (int j = 0; j < 4; ++j)
          acc[i][j] = __builtin_amdgcn_mfma_f32_16x16x32_bf16(av[i], bv[j],
                                                              acc[i][j], 0, 0, 0);
    }
    __syncthreads();
  }
#pragma unroll
  for (int i = 0; i < 4; ++i)
#pragma unroll
    for (int q = 0; q < 4; ++q) {
      int r = row0 + wr * 64 + i * 16 + (lane >> 4) * 4 + q;
#pragma unroll
      for (int j = 0; j < 4; ++j) {
        int c = col0 + wc * 64 + j * 16 + (lane & 15);
        if (c < Ncols) epi(r, c, acc[i][j][q]);
      }
    }
}

// ---------------- mamba pieces ----------------
__global__ void conv_silu(const ushort* __restrict__ xz, const float* __restrict__ cw,
                          const float* __restrict__ cb, ushort* __restrict__ xc) {
  int r = blockIdx.x;       // b*512 + t
  int d = threadIdx.x;      // 256
  int t = r & 511;
  float acc = cb[d];
#pragma unroll
  for (int k = 0; k < 4; ++k) {
    int tt = t - 3 + k;
    if (tt >= 0) acc = fmaf(cw[d * 4 + k], bf2f(xz[(size_t)(r - 3 + k) * 512 + d]), acc);
  }
  float v = acc * sigmoidf_(acc);
  xc[(size_t)r * 256 + d] = f2bf(v);
}

// dt = softplus(dbl[:,:8] @ w_dt + b_dt); 8 rows/block, w_dt in regs
__global__ __launch_bounds__(256) void dt_kernel(const float* __restrict__ dbl,
                                                 const float* __restrict__ w_dt,
                                                 const float* __restrict__ b_dt,
                                                 float* __restrict__ dtb) {
  int d = threadIdx.x;
  size_t r0 = (size_t)blockIdx.x * 8;
  float wd[8];
#pragma unroll
  for (int j = 0; j < 8; ++j) wd[j] = w_dt[j * 256 + d];
  float bd = b_dt[d];
#pragma unroll
  for (int rr = 0; rr < 8; ++rr) {
    size_t r = r0 + rr;
    float a = bd;
#pragma unroll
    for (int j = 0; j < 8; ++j) a = fmaf(dbl[r * 40 + j], wd[j], a);
    dtb[r * 256 + d] = fmaxf(a, 0.f) + log1pf(__expf(-fabsf(a)));
  }
}

// scan v5: 4 n-states/thread. wave = 16 d x 4 ng (lane = ng*16 + dl);
// block = 256 thr = 64 d; grid = 64 b x 4 dblk = 256 blocks (1/CU).
// LDS double-buffered 32-t chunks (dt f32, xc bf16, B/C f32).
__global__ __launch_bounds__(256) void scan_kernel(
    const float* __restrict__ dtb, const ushort* __restrict__ xcb,
    const float* __restrict__ dbl, const float* __restrict__ A2,
    ushort* __restrict__ y) {
  constexpr int TC = 32;
  constexpr int NC = 512 / TC;
  __shared__ float  s_dt[2][TC * 64];   // 8KB x2
  __shared__ ushort s_xc[2][TC * 64];   // 4KB x2
  __shared__ float  s_bc[2][TC * 32];   // 4KB x2: [j<16]=B[j], [16+j]=C[j]
  int b    = blockIdx.x >> 2;
  int dblk = blockIdx.x & 3;
  int d0   = dblk * 64;
  int tid  = threadIdx.x;
  int w = tid >> 6, lane = tid & 63;
  int ng = lane >> 4, dl = lane & 15;
  int wdl = w * 16 + dl;            // d within 64-slab
  int d  = d0 + wdl;
  int n0 = ng * 4;
  float a0 = A2[d * 16 + n0 + 0], a1 = A2[d * 16 + n0 + 1];
  float a2 = A2[d * 16 + n0 + 2], a3 = A2[d * 16 + n0 + 3];
  float h0 = 0.f, h1 = 0.f, h2 = 0.f, h3 = 0.f;
  const float*  pdt = dtb + (size_t)b * 512 * 256 + d0;
  const ushort* pxc = xcb + (size_t)b * 512 * 256 + d0;
  const float*  pbl = dbl + (size_t)b * 512 * 40;
  ushort* py = y + (size_t)b * 512 * 256 + d;

  // staging: 8 threads per t-row. dt: 2 x float4 (64 f32/row); xc: u16x8;
  // bc: float4 of dbl[t][8 + q*4]
  const int stt = tid >> 3;         // 0..31
  const int sq4 = (tid & 7) * 4;    // 0..28
  const int sq8 = (tid & 7) * 8;    // 0..56

  {  // prologue: stage chunk 0
    float4 r0a = L4(pdt + (size_t)stt * 256 + sq8);
    float4 r0b = L4(pdt + (size_t)stt * 256 + sq8 + 4);
    u16x8  r1  = *(const u16x8*)(pxc + (size_t)stt * 256 + sq8);
    float4 r2  = L4(pbl + (size_t)stt * 40 + 8 + sq4);
    *(float4*)&s_dt[0][stt * 64 + sq8]     = r0a;
    *(float4*)&s_dt[0][stt * 64 + sq8 + 4] = r0b;
    *(u16x8*)&s_xc[0][stt * 64 + sq8]      = r1;
    *(float4*)&s_bc[0][stt * 32 + sq4]     = r2;
  }
  __syncthreads();

  for (int c = 0; c < NC; ++c) {
    const int buf = c & 1;
    float4 r0a, r0b, r2; u16x8 r1;
    const bool more = (c + 1 < NC);
    if (more) {  // issue next chunk's loads early
      size_t t1 = (size_t)(c + 1) * TC + stt;
      r0a = L4(pdt + t1 * 256 + sq8);
      r0b = L4(pdt + t1 * 256 + sq8 + 4);
      r1  = *(const u16x8*)(pxc + t1 * 256 + sq8);
      r2  = L4(pbl + t1 * 40 + 8 + sq4);
    }
#pragma unroll
    for (int tt = 0; tt < TC; ++tt) {
      float dt = s_dt[buf][tt * 64 + wdl];
      float xc = bf2f(s_xc[buf][tt * 64 + wdl]);
      float4 B4 = *(const float4*)&s_bc[buf][tt * 32 + n0];
      float4 C4 = *(const float4*)&s_bc[buf][tt * 32 + 16 + n0];
      float u = dt * xc;
      h0 = fmaf(exp2f(dt * a0), h0, u * B4.x);
      h1 = fmaf(exp2f(dt * a1), h1, u * B4.y);
      h2 = fmaf(exp2f(dt * a2), h2, u * B4.z);
      h3 = fmaf(exp2f(dt * a3), h3, u * B4.w);
      float p = fmaf(h3, C4.w, fmaf(h2, C4.z, fmaf(h1, C4.y, h0 * C4.x)));
      p += __shfl_xor(p, 16);
      p += __shfl_xor(p, 32);
      if (ng == 0) py[(size_t)(c * TC + tt) * 256] = f2bf(p);
    }
    if (more) {  // write-late into the other buffer
      *(float4*)&s_dt[buf ^ 1][stt * 64 + sq8]     = r0a;
      *(float4*)&s_dt[buf ^ 1][stt * 64 + sq8 + 4] = r0b;
      *(u16x8*)&s_xc[buf ^ 1][stt * 64 + sq8]      = r1;
      *(float4*)&s_bc[buf ^ 1][stt * 32 + sq4]     = r2;
    }
    __syncthreads();
  }
}

// ------------- fused edge classifier; edges processed in dst-sorted order ---
__global__ __launch_bounds__(256) void cls_fused(
    const float* __restrict__ UV, const int* __restrict__ src,
    const int* __restrict__ dst, const int* __restrict__ eorder,
    const float* __restrict__ s1, const float* __restrict__ s2,
    const float* __restrict__ vecs, const float* __restrict__ g2v,
    const ushort* __restrict__ cw2t, const float* __restrict__ g3v,
    const float* __restrict__ cw3, float* __restrict__ out) {
  __shared__ __align__(16) char ldsA[32768];
  __shared__ __align__(16) char ldsB[16384];
  __shared__ float lmu1[64], lrs1[64], lmu2[64], lrs2[64];
  __shared__ int   lsrc[64], ldst[64], le[64];
  __shared__ float lred[64][2][4];
  const float* G1  = vecs;
  const float* B1c = vecs + 256;
  const float* G2  = vecs + 512;
  const float* B2c = vecs + 640;
  const float* G3  = vecs + 768;
  const float* B3c = vecs + 770;
  int tid = threadIdx.x, lane = tid & 63, w = tid >> 6;
  int e0 = blockIdx.x * 64;
  if (tid < 64) {
    int e = eorder[e0 + tid];
    le[tid] = e;
    int sN = src[e], dN = dst[e];
    lsrc[tid] = sN; ldst[tid] = dN;
    float sum = s1[sN] + s1[dN];
    float sq  = s2[sN] + s2[dN];
    float m = sum * (1.f / 256.f);
    float v = sq * (1.f / 256.f) - m * m;
    lmu1[tid] = m; lrs1[tid] = rsqrtf(v + kEPS);
  }
  __syncthreads();
  {
    int row = tid >> 2, qq = tid & 3;
    const float* pu = UV + (size_t)lsrc[row] * 512;
    const float* pv = UV + (size_t)ldst[row] * 512 + 256;
    float r1 = lrs1[row];
    float rm1 = r1 * lmu1[row];
    float s = 0.f, q = 0.f;
#pragma unroll
    for (int it = 0; it < 8; ++it) {
      int k0 = qq * 8 + it * 32;
      float4 ua = L4(pu + k0), ub = L4(pu + k0 + 4);
      float4 va = L4(pv + k0), vb = L4(pv + k0 + 4);
      float4 Ga = L4(G1 + k0), Gb = L4(G1 + k0 + 4);
      float4 Ba = L4(B1c + k0), Bb = L4(B1c + k0 + 4);
      float4 ga = L4(g2v + k0), gb = L4(g2v + k0 + 4);
      float tv[8], gg[8];
      tv[0] = fmaf(r1, ua.x + va.x, fmaf(-rm1, Ga.x, Ba.x)); gg[0] = ga.x;
      tv[1] = fmaf(r1, ua.y + va.y, fmaf(-rm1, Ga.y, Ba.y)); gg[1] = ga.y;
      tv[2] = fmaf(r1, ua.z + va.z, fmaf(-rm1, Ga.z, Ba.z)); gg[2] = ga.z;
      tv[3] = fmaf(r1, ua.w + va.w, fmaf(-rm1, Ga.w, Ba.w)); gg[3] = ga.w;
      tv[4] = fmaf(r1, ub.x + vb.x, fmaf(-rm1, Gb.x, Bb.x)); gg[4] = gb.x;
      tv[5] = fmaf(r1, ub.y + vb.y, fmaf(-rm1, Gb.y, Bb.y)); gg[5] = gb.y;
      tv[6] = fmaf(r1, ub.z + vb.z, fmaf(-rm1, Gb.z, Bb.z)); gg[6] = gb.z;
      tv[7] = fmaf(r1, ub.w + vb.w, fmaf(-rm1, Gb.w, Bb.w)); gg[7] = gb.w;
      s16x8 pk;
#pragma unroll
      for (int jj = 0; jj < 8; ++jj) {
        float t = tv[jj];
        t = t >= 0.f ? t : 0.01f * t;
        s += t; q += t * t;
        pk[jj] = (short)f2bf(t * gg[jj]);
      }
      *(s16x8*)(ldsA + ((row * 512 + k0 * 2) ^ ((row & 7) << 4))) = pk;
    }
    s += __shfl_xor(s, 1); s += __shfl_xor(s, 2);
    q += __shfl_xor(q, 1); q += __shfl_xor(q, 2);
    if (qq == 0) {
      float m2 = s * (1.f / 256.f);
      float v2 = q * (1.f / 256.f) - m2 * m2;
      lmu2[row] = m2; lrs2[row] = rsqrtf(v2 + kEPS);
    }
  }
  const int wr = w >> 1, wc = w & 1;
  const int sm = tid >> 3, sk8 = (tid & 7) * 8;
  f32x4 acc[2][4];
#pragma unroll
  for (int i = 0; i < 2; ++i)
#pragma unroll
    for (int j = 0; j < 4; ++j) acc[i][j] = f32x4{0.f, 0.f, 0.f, 0.f};
  for (int kt = 0; kt < 4; ++kt) {
    __syncthreads();
#pragma unroll
    for (int i = 0; i < 4; ++i) {
      int n = i * 32 + sm;
      s16x8 bvv = *(const s16x8*)(cw2t + (size_t)n * 256 + kt * 64 + sk8);
      *(s16x8*)(ldsB + ((n * 128 + sk8 * 2) ^ ((n & 7) << 4))) = bvv;
    }
    __syncthreads();
#pragma unroll
    for (int ks = 0; ks < 2; ++ks) {
      const int kbB = ks * 64 + (lane >> 4) * 16;
      const int kbA = kt * 128 + kbB;
      s16x8 av[2], bv[4];
#pragma unroll
      for (int i = 0; i < 2; ++i) {
        int r = wr * 32 + i * 16 + (lane & 15);
        av[i] = *(const s16x8*)(ldsA + ((r * 512 + kbA) ^ ((r & 7) << 4)));
      }
#pragma unroll
      for (int j = 0; j < 4; ++j) {
        int n = wc * 64 + j * 16 + (lane & 15);
        bv[j] = *(const s16x8*)(ldsB + ((n * 128 + kbB) ^ ((n & 7) << 4)));
      }
#pragma unroll
      for (int i = 0; i < 2; ++i)
#pragma unroll
        for (int j = 0; j < 4; ++j)
          acc[i][j] = __builtin_amdgcn_mfma_f32_16x16x32_bf16(av[i], bv[j],
                                                              acc[i][j], 0, 0, 0);
    }
  }
  {
    int g = lane >> 4, lo = lane & 15;
#pragma unroll
    for (int i = 0; i < 2; ++i) {
#pragma unroll
      for (int qv = 0; qv < 4; ++qv) {
        int row = wr * 32 + i * 16 + g * 4 + qv;
        float rs2v = lrs2[row];
        float rm2  = rs2v * lmu2[row];
        float sS = 0.f, sQ = 0.f, sP0 = 0.f, sP1 = 0.f;
#pragma unroll
        for (int j = 0; j < 4; ++j) {
          int col = wc * 64 + j * 16 + lo;
          float t2 = fmaf(rs2v, acc[i][j][qv], fmaf(-rm2, G2[col], B2c[col]));
          t2 = t2 >= 0.f ? t2 : 0.01f * t2;
          sS += t2; sQ += t2 * t2;
          float tg = t2 * g3v[col];
          sP0 = fmaf(tg, cw3[col * 2 + 0], sP0);
          sP1 = fmaf(tg, cw3[col * 2 + 1], sP1);
        }
#pragma unroll
        for (int o = 1; o < 16; o <<= 1) {
          sS += __shfl_xor(sS, o); sQ += __shfl_xor(sQ, o);
          sP0 += __shfl_xor(sP0, o); sP1 += __shfl_xor(sP1, o);
        }
        if (lo == 0) {
          lred[row][wc][0] = sS; lred[row][wc][1] = sQ;
          lred[row][wc][2] = sP0; lred[row][wc][3] = sP1;
        }
      }
    }
  }
  __syncthreads();
  if (tid < 64) {
    float S  = lred[tid][0][0] + lred[tid][1][0];
    float Q  = lred[tid][0][1] + lred[tid][1][1];
    float P0 = lred[tid][0][2] + lred[tid][1][2];
    float P1 = lred[tid][0][3] + lred[tid][1][3];
    float m3 = S * (1.f / 128.f);
    float v3 = Q * (1.f / 128.f) - m3 * m3;
    float r3 = rsqrtf(v3 + kEPS);
    size_t e = (size_t)le[tid];
    out[e * 2 + 0] = fmaf(r3, P0 - m3 * G3[0], B3c[0]);
    out[e * 2 + 1] = fmaf(r3, P1 - m3 * G3[1], B3c[1]);
  }
}

extern "C" void kernel_launch(void* const* d_in, const int* in_sizes, int n_in,
                              void* d_out, int out_size, void* d_ws, size_t ws_size,
                              hipStream_t stream) {
  const float* x      = (const float*)d_in[0];
  const int*   eidx   = (const int*)  d_in[1];
  const float* eattr  = (const float*)d_in[2];
  const float* bn_ng  = (const float*)d_in[3];
  const float* bn_nb  = (const float*)d_in[4];
  const float* bn_eg  = (const float*)d_in[5];
  const float* bn_eb  = (const float*)d_in[6];
  const float* lin_w  = (const float*)d_in[7];
  const float* lin_b  = (const float*)d_in[8];
  const float* w1     = (const float*)d_in[9];
  const float* b1     = (const float*)d_in[10];
  const float* w2     = (const float*)d_in[11];
  const float* b2     = (const float*)d_in[12];
  const float* mlng   = (const float*)d_in[13];
  const float* mlnb   = (const float*)d_in[14];
  const float* w_in   = (const float*)d_in[15];
  const float* conv_w = (const float*)d_in[16];
  const float* conv_b = (const float*)d_in[17];
  const float* w_x    = (const float*)d_in[18];
  const float* w_dt   = (const float*)d_in[19];
  const float* b_dt   = (const float*)d_in[20];
  const float* A_log  = (const float*)d_in[21];
  const float* Dm     = (const float*)d_in[22];
  const float* w_out  = (const float*)d_in[23];
  const float* ln1g   = (const float*)d_in[24];
  const float* ln1b   = (const float*)d_in[25];
  const float* cw1    = (const float*)d_in[26];
  const float* cb1    = (const float*)d_in[27];
  const float* ln2g   = (const float*)d_in[28];
  const float* ln2b   = (const float*)d_in[29];
  const float* cw2    = (const float*)d_in[30];
  const float* cb2    = (const float*)d_in[31];
  const float* ln3g   = (const float*)d_in[32];
  const float* ln3b   = (const float*)d_in[33];
  const float* cw3    = (const float*)d_in[34];
  const float* cb3    = (const float*)d_in[35];
  const int* src = eidx;
  const int* dst = eidx + kE;
  float* out = (float*)d_out;

  // ---- workspace layout ----
  char* ws = (char*)d_ws;
  const size_t MB = 1ull << 20;
  const size_t KB = 1024;
  if (ws_size < 212 * MB) return;
  float* bn_acc = (float*)ws;                       // 512 f32
  float* coef   = (float*)(ws + 4096);              // 512 f32
  float* A2     = (float*)(ws + 8192);              // 4096 f32
  ushort* wt = (ushort*)(ws + 64 * KB);
  ushort* wt_lin  = wt;             // 128x128
  ushort* wt_w1   = wt + 16384;     // 128x128
  ushort* wt_w2   = wt + 32768;     // 128x128
  ushort* wt_win  = wt + 49152;     // 512x128
  ushort* wt_wx   = wt + 114688;    // 128x256 (N=40 padded)
  ushort* wt_wout = wt + 147456;    // 128x256
  ushort* wt_uv   = wt + 180224;    // 512x128
  ushort* wt_cw2  = wt + 245760;    // 128x256
  float* mu   = (float*)(ws + 1 * MB);
  float* rsb  = (float*)(ws + 1 * MB + 256 * KB);
  float* s1b  = (float*)(ws + 1 * MB + 512 * KB);
  float* s2b  = (float*)(ws + 1 * MB + 768 * KB);
  float* vecs = (float*)(ws + 2 * MB);              // 772 f32
  int* cnt    = (int*)(ws + 2 * MB + 128 * KB);     // 32768
  int* base   = (int*)(ws + 2 * MB + 256 * KB);     // 32769
  int* run    = (int*)(ws + 2 * MB + 512 * KB);     // 32768
  int* eorder = (int*)(ws + 3 * MB);                // 262144
  float* h    = (float*)(ws + 4 * MB);              // 16 MB
  char*  S    = ws + 20 * MB;                       // phase-shared region
  // GNN phase
  float*  xn   = (float*)S;                    // 16 MB
  float*  agg  = (float*)(S + 16 * MB);        // 16 MB
  ushort* tmpb = (ushort*)(S + 32 * MB);       // 8 MB (bf16)
  ushort* msg0 = (ushort*)(S + 48 * MB);       // 64 MB (bf16)
  // mamba phase
  ushort* xzb = (ushort*)S;                    // N x 512 bf16 (32 MB)
  ushort* xcb = (ushort*)(S + 32 * MB);        // N x 256 bf16 (16 MB)
  float*  dbl = (float*)(S + 48 * MB);         // N x 40 f32 (5.25 MB)
  ushort* yb  = (ushort*)(S + 56 * MB);        // N x 256 bf16 (16 MB)
  float*  dtb = (float*)(S + 72 * MB);         // N x 256 f32 (32 MB)
  // classifier phase
  float* UV = (float*)S;                       // N x 512 f32 (64 MB)

  // ---- weight prep ----
  prep_wt<<<64,  256, 0, stream>>>(lin_w, 128, 128, wt_lin);
  prep_wt<<<64,  256, 0, stream>>>(w1,    128, 128, wt_w1);
  prep_wt<<<64,  256, 0, stream>>>(w2,    128, 128, wt_w2);
  prep_wt<<<256, 256, 0, stream>>>(w_in,  128, 512, wt_win);
  prep_wt<<<128, 256, 0, stream>>>(w_x,   256, 40,  wt_wx);
  prep_wt<<<128, 256, 0, stream>>>(w_out, 256, 128, wt_wout);
  prep_wt<<<128, 256, 0, stream>>>(cw2,   256, 128, wt_cw2);
  prep_uv<<<256, 256, 0, stream>>>(cw1, ln1g, wt_uv);
  prep_vecs<<<1, 256, 0, stream>>>(cw1, ln1b, cb1, cw2, ln2g, ln2b, cb2,
                                   cw3, ln3g, ln3b, cb3, ln1g, vecs);

  // ---- edge sort by dst (counting sort) ----
  hipMemsetAsync(cnt, 0, 32768 * 4, stream);
  hist_kernel<<<kE / 256, 256, 0, stream>>>(dst, cnt);
  scan32k<<<1, 1024, 0, stream>>>(cnt, base, run);
  scatter_ids<<<kE / 256, 256, 0, stream>>>(dst, run, eorder);

  // ---- GNN ----
  hipMemsetAsync(bn_acc, 0, 512 * 4, stream);
  bn_partial2<<<256, 256, 0, stream>>>(x, kN, bn_acc, bn_acc + 128);
  bn_partial2<<<512, 256, 0, stream>>>(eattr, kE, bn_acc + 256, bn_acc + 384);
  bn_finalize<<<1, 256, 0, stream>>>(bn_acc, bn_ng, bn_nb, bn_eg, bn_eb, coef);
  a2prep<<<16, 256, 0, stream>>>(A_log, A2);
  bn_apply<<<kN * kH / 1024, 256, 0, stream>>>(x, coef, xn);

  // msg0 = BN(ea)@lin_w  (pure streaming GEMM, bf16 out, no gather)
  gemm_mfma<<<dim3(kE / 128, 1), 256, 0, stream>>>(
      ALBN{eattr, coef + 256}, wt_lin, 128, 128, EPStoreBf{msg0, 128});
  // agg[dst] = sum relu(msg0 + lin_b + xn[src]) over sorted edge lists
  agg_fused<<<kN / 2, 256, 0, stream>>>(msg0, xn, eorder, base, src, lin_b, agg);

  // h = relu(leaky((xn+agg)@w1 + b1)@w2 + b2)
  gemm_mfma<<<dim3(kN / 128, 1), 256, 0, stream>>>(
      ALAdd2{xn, agg}, wt_w1, 128, 128, EPBiasLeakyBf{tmpb, 128, b1});
  gemm_mfma<<<dim3(kN / 128, 1), 256, 0, stream>>>(
      ALBf{tmpb, 128}, wt_w2, 128, 128, EPBiasRelu{h, 128, b2});

  // ---- mamba x2 ----
  for (int pass = 0; pass < 2; ++pass) {
    stats_rows<<<kN / 4, 256, 0, stream>>>(h, mu, rsb);
    gemm_mfma<<<dim3(kN / 128, 4), 256, 0, stream>>>(
        ALLN{h, 128, mu, rsb, mlng, mlnb}, wt_win, 128, 512, EPStoreBf{xzb, 512});
    conv_silu<<<kN, 256, 0, stream>>>(xzb, conv_w, conv_b, xcb);
    gemm_mfma<<<dim3(kN / 128, 1), 256, 0, stream>>>(
        ALBf{xcb, 256}, wt_wx, 256, 40, EPStore{dbl, 40});
    dt_kernel<<<kN / 8, 256, 0, stream>>>(dbl, w_dt, b_dt, dtb);
    scan_kernel<<<256, 256, 0, stream>>>(dtb, xcb, dbl, A2, yb);
    gemm_mfma<<<dim3(kN / 128, 1), 256, 0, stream>>>(
        ALMambaY{yb, xcb, xzb, Dm}, wt_wout, 256, 128, EPResidH{h});
  }

  // ---- fused edge classifier (dst-sorted edge order, scatter out) ----
  s12_kernel<<<kN / 4, 256, 0, stream>>>(h, s1b, s2b);
  gemm_mfma<<<dim3(kN / 128, 4), 256, 0, stream>>>(
      ALPlainF{h, 128}, wt_uv, 128, 512, EPStore{UV, 512});
  cls_fused<<<kE / 64, 256, 0, stream>>>(UV, src, dst, eorder, s1b, s2b, vecs,
                                         ln2g, wt_cw2, ln3g, cw3, out);
}

// Round 14
// 1102.905 us; speedup vs baseline: 1.0119x; 1.0119x over previous
//
#include <hip/hip_runtime.h>

#define DEV __device__ __forceinline__

constexpr int   kH  = 128;
constexpr int   kN  = 32768;    // B*NP rows
constexpr int   kE  = 262144;   // edges
constexpr float kEPS = 1e-5f;
constexpr float kLOG2E = 1.4426950408889634f;

typedef short  s16x8 __attribute__((ext_vector_type(8)));
typedef ushort u16x8 __attribute__((ext_vector_type(8)));
typedef ushort u16x4 __attribute__((ext_vector_type(4)));
typedef float  f32x4 __attribute__((ext_vector_type(4)));

DEV float sigmoidf_(float v) { return 1.f / (1.f + __expf(-v)); }

DEV ushort f2bf(float f) {  // RTNE f32 -> bf16
  union { float f; unsigned u; } x{f};
  unsigned r = x.u + 0x7fff + ((x.u >> 16) & 1);
  return (ushort)(r >> 16);
}
DEV float bf2f(ushort u) {
  union { unsigned u; float f; } x{(unsigned)u << 16};
  return x.f;
}
DEV float4 L4(const float* p) { return *(const float4*)p; }
DEV s16x8 pk8(const float* v) {
  s16x8 r;
#pragma unroll
  for (int j = 0; j < 8; ++j) r[j] = (short)f2bf(v[j]);
  return r;
}

// ---------------- batchnorm column stats, vectorized ----------------
__global__ __launch_bounds__(256) void bn_partial2(const float* __restrict__ X, int R,
                                                   float* __restrict__ sum,
                                                   float* __restrict__ sq) {
  int t = threadIdx.x;
  int cg = (t & 31) * 4, rs = t >> 5;
  float sx = 0.f, sy = 0.f, sz = 0.f, sw = 0.f;
  float qx = 0.f, qy = 0.f, qz = 0.f, qw = 0.f;
  for (int r = blockIdx.x * 8 + rs; r < R; r += gridDim.x * 8) {
    float4 v = L4(X + (size_t)r * 128 + cg);
    sx += v.x; sy += v.y; sz += v.z; sw += v.w;
    qx = fmaf(v.x, v.x, qx); qy = fmaf(v.y, v.y, qy);
    qz = fmaf(v.z, v.z, qz); qw = fmaf(v.w, v.w, qw);
  }
  __shared__ float red[8][256];
  red[rs][(t & 31) * 8 + 0] = sx; red[rs][(t & 31) * 8 + 1] = sy;
  red[rs][(t & 31) * 8 + 2] = sz; red[rs][(t & 31) * 8 + 3] = sw;
  red[rs][(t & 31) * 8 + 4] = qx; red[rs][(t & 31) * 8 + 5] = qy;
  red[rs][(t & 31) * 8 + 6] = qz; red[rs][(t & 31) * 8 + 7] = qw;
  __syncthreads();
  if (rs == 0) {
    int cq = t & 31;
#pragma unroll
    for (int jj = 0; jj < 4; ++jj) {
      float S = 0.f, Q = 0.f;
#pragma unroll
      for (int i = 0; i < 8; ++i) {
        S += red[i][cq * 8 + jj];
        Q += red[i][cq * 8 + 4 + jj];
      }
      atomicAdd(&sum[cq * 4 + jj], S);
      atomicAdd(&sq[cq * 4 + jj], Q);
    }
  }
}

__global__ void bn_finalize(const float* __restrict__ acc,
                            const float* __restrict__ gx, const float* __restrict__ bx,
                            const float* __restrict__ ge, const float* __restrict__ be,
                            float* __restrict__ coef) {
  int t = threadIdx.x;
  if (t < 128) {
    float m  = acc[t]       * (1.f / 32768.f);
    float v  = acc[128 + t] * (1.f / 32768.f) - m * m;
    float sc = gx[t] * rsqrtf(v + kEPS);
    coef[t] = sc; coef[128 + t] = bx[t] - m * sc;
  } else {
    int c = t - 128;
    float m  = acc[256 + c] * (1.f / 262144.f);
    float v  = acc[384 + c] * (1.f / 262144.f) - m * m;
    float sc = ge[c] * rsqrtf(v + kEPS);
    coef[256 + c] = sc; coef[384 + c] = be[c] - m * sc;
  }
}

__global__ void bn_apply(const float* __restrict__ x, const float* __restrict__ coef,
                         float* __restrict__ xn) {
  size_t i = ((size_t)blockIdx.x * 256 + threadIdx.x) * 4;
  int c = (int)(i & 127);
  float4 v = L4(x + i);
  float4 s = L4(coef + c), h = L4(coef + 128 + c);
  float4 o;
  o.x = fmaf(v.x, s.x, h.x); o.y = fmaf(v.y, s.y, h.y);
  o.z = fmaf(v.z, s.z, h.z); o.w = fmaf(v.w, s.w, h.w);
  *(float4*)(xn + i) = o;
}

__global__ void a2prep(const float* __restrict__ A_log, float* __restrict__ A2) {
  int i = blockIdx.x * 256 + threadIdx.x;
  A2[i] = -__expf(A_log[i]) * kLOG2E;
}

// convert weight W[K][N] f32 -> Wt[Npad][K] bf16 (transposed, zero-padded cols)
__global__ void prep_wt(const float* __restrict__ W, int Kdim, int Ncols,
                        ushort* __restrict__ Wt) {
  int idx = blockIdx.x * 256 + threadIdx.x;
  int n = idx / Kdim, k = idx - n * Kdim;
  float v = (n < Ncols) ? W[(size_t)k * Ncols + n] : 0.f;
  Wt[idx] = f2bf(v);
}

__global__ void prep_uv(const float* __restrict__ cw1, const float* __restrict__ g1,
                        ushort* __restrict__ Wt) {
  int idx = blockIdx.x * 256 + threadIdx.x;  // 512*128
  int n = idx >> 7, k = idx & 127;
  int krow = (n < 256) ? k : 128 + k;
  int ncol = n & 255;
  Wt[idx] = f2bf(g1[krow] * cw1[(size_t)krow * 256 + ncol]);
}

// vecs layout: G1[256] B1c[256] G2[128] B2c[128] G3[2] B3c[2]
__global__ void prep_vecs(const float* __restrict__ cw1, const float* __restrict__ b1v,
                          const float* __restrict__ cb1,
                          const float* __restrict__ cw2, const float* __restrict__ g2v,
                          const float* __restrict__ b2v, const float* __restrict__ cb2,
                          const float* __restrict__ cw3, const float* __restrict__ g3v,
                          const float* __restrict__ b3v, const float* __restrict__ cb3,
                          const float* __restrict__ g1v, float* __restrict__ vecs) {
  int t = threadIdx.x;
  {
    float gs = 0.f, bs = 0.f;
    for (int k = 0; k < 256; ++k) {
      float w = cw1[(size_t)k * 256 + t];
      gs = fmaf(g1v[k], w, gs);
      bs = fmaf(b1v[k], w, bs);
    }
    vecs[t] = gs; vecs[256 + t] = bs + cb1[t];
  }
  if (t < 128) {
    float gs = 0.f, bs = 0.f;
    for (int k = 0; k < 256; ++k) {
      float w = cw2[(size_t)k * 128 + t];
      gs = fmaf(g2v[k], w, gs);
      bs = fmaf(b2v[k], w, bs);
    }
    vecs[512 + t] = gs; vecs[640 + t] = bs + cb2[t];
  }
  if (t < 2) {
    float gs = 0.f, bs = 0.f;
    for (int c = 0; c < 128; ++c) {
      float w = cw3[c * 2 + t];
      gs = fmaf(g3v[c], w, gs);
      bs = fmaf(b3v[c], w, bs);
    }
    vecs[768 + t] = gs; vecs[770 + t] = bs + cb3[t];
  }
}

// ---------------- edge sort (counting sort by dst) ----------------
__global__ void hist_kernel(const int* __restrict__ dst, int* __restrict__ cnt) {
  int e = blockIdx.x * 256 + threadIdx.x;
  atomicAdd(&cnt[dst[e]], 1);
}

__global__ __launch_bounds__(1024) void scan32k(const int* __restrict__ cnt,
                                                int* __restrict__ base,
                                                int* __restrict__ run) {
  __shared__ int part[1024];
  int t = threadIdx.x;
  int loc[32]; int s = 0;
  const int* p = cnt + t * 32;
#pragma unroll
  for (int i = 0; i < 32; ++i) { loc[i] = s; s += p[i]; }
  part[t] = s;
  __syncthreads();
  for (int o = 1; o < 1024; o <<= 1) {
    int v = (t >= o) ? part[t - o] : 0;
    __syncthreads();
    part[t] += v;
    __syncthreads();
  }
  int ex = part[t] - s;
#pragma unroll
  for (int i = 0; i < 32; ++i) {
    int b = ex + loc[i];
    base[t * 32 + i] = b; run[t * 32 + i] = b;
  }
  if (t == 1023) base[32768] = part[1023];
}

__global__ void scatter_ids(const int* __restrict__ dst, int* __restrict__ run,
                            int* __restrict__ eorder) {
  int e = blockIdx.x * 256 + threadIdx.x;
  int p = atomicAdd(&run[dst[e]], 1);
  eorder[p] = e;
}

// agg[v] = sum over sorted in-edges: relu(msg0[e] + lin_b + xn[src[e]])
__global__ __launch_bounds__(256) void agg_fused(
    const ushort* __restrict__ msg0, const float* __restrict__ xn,
    const int* __restrict__ eorder, const int* __restrict__ base,
    const int* __restrict__ src, const float* __restrict__ lin_b,
    float* __restrict__ agg) {
  int node = blockIdx.x * 2 + (threadIdx.x >> 7);
  int c = threadIdx.x & 127;
  int b0 = base[node], b1 = base[node + 1];
  float bias = lin_b[c];
  float s = 0.f;
  for (int j = b0; j < b1; ++j) {
    int e = eorder[j];
    float m = bf2f(msg0[(size_t)e * 128 + c]) + bias + xn[(size_t)src[e] * 128 + c];
    s += fmaxf(m, 0.f);
  }
  agg[(size_t)node * 128 + c] = s;
}

// per-node sum & sumsq of h rows (for edge LN1 stats)
__global__ void s12_kernel(const float* __restrict__ h, float* __restrict__ s1,
                           float* __restrict__ s2) {
  int wid = threadIdx.x >> 6, lane = threadIdx.x & 63;
  int r = blockIdx.x * 4 + wid;
  const float* row = h + (size_t)r * 128;
  float v0 = row[lane], v1 = row[lane + 64];
  float s = v0 + v1;
  float q = v0 * v0 + v1 * v1;
#pragma unroll
  for (int o = 32; o; o >>= 1) { s += __shfl_xor(s, o); q += __shfl_xor(q, o); }
  if (lane == 0) { s1[r] = s; s2[r] = q; }
}

// ---------------- rowwise LN stats (mamba) ----------------
__global__ void stats_rows(const float* __restrict__ X, float* __restrict__ mu,
                           float* __restrict__ rs) {
  int wid = threadIdx.x >> 6, lane = threadIdx.x & 63;
  int r = blockIdx.x * 4 + wid;
  const float* row = X + (size_t)r * 128;
  float v0 = row[lane], v1 = row[lane + 64];
  float s = v0 + v1;
#pragma unroll
  for (int o = 32; o; o >>= 1) s += __shfl_xor(s, o);
  float m = s * (1.f / 128.f);
  float d0 = v0 - m, d1 = v1 - m;
  float q = d0 * d0 + d1 * d1;
#pragma unroll
  for (int o = 32; o; o >>= 1) q += __shfl_xor(q, o);
  if (lane == 0) { mu[r] = m; rs[r] = rsqrtf(q * (1.f / 128.f) + kEPS); }
}

// ---------------- A-load functors: ld8 returns bf16x8 ---------------------
struct ALPlainF {  // f32 source
  const float* A; int lda;
  DEV s16x8 ld8(int r, int k) const {
    float b[8];
    const float* p = A + (size_t)r * lda + k;
    *(float4*)b = L4(p); *(float4*)(b + 4) = L4(p + 4);
    return pk8(b);
  }
};
struct ALBf {  // already-bf16 source, pure copy
  const ushort* A; int lda;
  DEV s16x8 ld8(int r, int k) const {
    return *(const s16x8*)(A + (size_t)r * lda + k);
  }
};
struct ALBN {
  const float* A; const float* coef;
  DEV s16x8 ld8(int r, int k) const {
    const float* p = A + (size_t)r * 128 + k;
    float4 a0 = L4(p), a1 = L4(p + 4);
    float4 s0 = L4(coef + k), s1 = L4(coef + k + 4);
    float4 h0 = L4(coef + 128 + k), h1 = L4(coef + 132 + k);
    float b[8];
    b[0] = fmaf(a0.x, s0.x, h0.x); b[1] = fmaf(a0.y, s0.y, h0.y);
    b[2] = fmaf(a0.z, s0.z, h0.z); b[3] = fmaf(a0.w, s0.w, h0.w);
    b[4] = fmaf(a1.x, s1.x, h1.x); b[5] = fmaf(a1.y, s1.y, h1.y);
    b[6] = fmaf(a1.z, s1.z, h1.z); b[7] = fmaf(a1.w, s1.w, h1.w);
    return pk8(b);
  }
};
struct ALAdd2 {
  const float* X; const float* Y;
  DEV s16x8 ld8(int r, int k) const {
    const float* p = X + (size_t)r * 128 + k;
    const float* q = Y + (size_t)r * 128 + k;
    float4 a0 = L4(p), a1 = L4(p + 4), b0 = L4(q), b1 = L4(q + 4);
    float b[8];
    b[0] = a0.x + b0.x; b[1] = a0.y + b0.y; b[2] = a0.z + b0.z; b[3] = a0.w + b0.w;
    b[4] = a1.x + b1.x; b[5] = a1.y + b1.y; b[6] = a1.z + b1.z; b[7] = a1.w + b1.w;
    return pk8(b);
  }
};
struct ALLN {
  const float* A; int lda; const float* mu; const float* rs;
  const float* g; const float* b;
  DEV s16x8 ld8(int r, int k) const {
    float m = mu[r], s = rs[r];
    const float* p = A + (size_t)r * lda + k;
    float4 a0 = L4(p), a1 = L4(p + 4);
    float4 g0 = L4(g + k), g1 = L4(g + k + 4), b0 = L4(b + k), b1 = L4(b + k + 4);
    float o[8];
    o[0] = fmaf((a0.x - m) * s, g0.x, b0.x); o[1] = fmaf((a0.y - m) * s, g0.y, b0.y);
    o[2] = fmaf((a0.z - m) * s, g0.z, b0.z); o[3] = fmaf((a0.w - m) * s, g0.w, b0.w);
    o[4] = fmaf((a1.x - m) * s, g1.x, b1.x); o[5] = fmaf((a1.y - m) * s, g1.y, b1.y);
    o[6] = fmaf((a1.z - m) * s, g1.z, b1.z); o[7] = fmaf((a1.w - m) * s, g1.w, b1.w);
    return pk8(o);
  }
};
struct ALMambaY {  // (scan_y + Dm*xc) * silu(z), all bf16 inputs
  const ushort* y; const ushort* xc; const ushort* xz; const float* Dm;
  DEV s16x8 ld8(int r, int k) const {
    u16x8 yv = *(const u16x8*)(y + (size_t)r * 256 + k);
    u16x8 cv = *(const u16x8*)(xc + (size_t)r * 256 + k);
    u16x8 zv = *(const u16x8*)(xz + (size_t)r * 512 + 256 + k);
    s16x8 o;
#pragma unroll
    for (int j = 0; j < 8; ++j) {
      float zf = bf2f(zv[j]);
      float val = fmaf(Dm[k + j], bf2f(cv[j]), bf2f(yv[j])) * (zf * sigmoidf_(zf));
      o[j] = (short)f2bf(val);
    }
    return o;
  }
};

struct EPStore {
  float* C; int ldc;
  DEV void operator()(int r, int c, float v) const { C[(size_t)r * ldc + c] = v; }
};
struct EPStoreBf {
  ushort* C; int ldc;
  DEV void operator()(int r, int c, float v) const { C[(size_t)r * ldc + c] = f2bf(v); }
};
struct EPBiasLeakyBf {
  ushort* C; int ldc; const float* bias;
  DEV void operator()(int r, int c, float v) const {
    v += bias[c];
    v = v >= 0.f ? v : 0.01f * v;
    C[(size_t)r * ldc + c] = f2bf(v);
  }
};
struct EPBiasRelu {
  float* C; int ldc; const float* bias;
  DEV void operator()(int r, int c, float v) const {
    C[(size_t)r * ldc + c] = fmaxf(v + bias[c], 0.f);
  }
};
struct EPResidH {
  float* h;
  DEV void operator()(int r, int c, float v) const {
    size_t i = (size_t)r * 128 + c; h[i] = h[i] + v;
  }
};

// ------------- bf16 MFMA GEMM: 128x128 tile, BK=64, 256 thr (4 waves 2x2) ---
template <class AL, class EP>
__global__ __launch_bounds__(256) void gemm_mfma(AL aload, const ushort* __restrict__ Wt,
                                                 int Kdim, int Ncols, EP epi) {
  __shared__ __align__(16) char lds[32768];
  const int tid = threadIdx.x;
  const int lane = tid & 63;
  const int w = tid >> 6;
  const int wr = w >> 1, wc = w & 1;
  const int row0 = blockIdx.x * 128, col0 = blockIdx.y * 128;
  const int sm = tid >> 3;
  const int sk = (tid & 7) * 8;
  f32x4 acc[4][4];
#pragma unroll
  for (int i = 0; i < 4; ++i)
#pragma unroll
    for (int j = 0; j < 4; ++j) acc[i][j] = f32x4{0.f, 0.f, 0.f, 0.f};

  for (int kt = 0; kt < Kdim; kt += 64) {
#pragma unroll
    for (int i = 0; i < 4; ++i) {
      int n = i * 32 + sm;
      s16x8 v = *(const s16x8*)(Wt + (size_t)(col0 + n) * Kdim + kt + sk);
      *(s16x8*)(lds + 16384 + ((n * 128 + sk * 2) ^ ((n & 7) << 4))) = v;
    }
#pragma unroll
    for (int i = 0; i < 4; ++i) {
      int m = i * 32 + sm;
      s16x8 v = aload.ld8(row0 + m, kt + sk);
      *(s16x8*)(lds + ((m * 128 + sk * 2) ^ ((m & 7) << 4))) = v;
    }
    __syncthreads();
#pragma unroll
    for (int ks = 0; ks < 2; ++ks) {
      const int kb = ks * 64 + (lane >> 4) * 16;
      s16x8 av[4], bv[4];
#pragma unroll
      for (int i = 0; i < 4; ++i) {
        int r = wr * 64 + i * 16 + (lane & 15);
        av[i] = *(const s16x8*)(lds + ((r * 128 + kb) ^ ((r & 7) << 4)));
      }
#pragma unroll
      for (int j = 0; j < 4; ++j) {
        int n = wc * 64 + j * 16 + (lane & 15);
        bv[j] = *(const s16x8*)(lds + 16384 + ((n * 128 + kb) ^ ((n & 7) << 4)));
      }
#pragma unroll
      for (int i = 0; i < 4; ++i)
#pragma unroll
        for (int j = 0; j < 4; ++j)
          acc[i][j] = __builtin_amdgcn_mfma_f32_16x16x32_bf16(av[i], bv[j],
                                                              acc[i][j], 0, 0, 0);
    }
    __syncthreads();
  }
#pragma unroll
  for (int i = 0; i < 4; ++i)
#pragma unroll
    for (int q = 0; q < 4; ++q) {
      int r = row0 + wr * 64 + i * 16 + (lane >> 4) * 4 + q;
#pragma unroll
      for (int j = 0; j < 4; ++j) {
        int c = col0 + wc * 64 + j * 16 + (lane & 15);
        if (c < Ncols) epi(r, c, acc[i][j][q]);
      }
    }
}

// ---------------- mamba pieces ----------------
__global__ void conv_silu(const ushort* __restrict__ xz, const float* __restrict__ cw,
                          const float* __restrict__ cb, ushort* __restrict__ xc) {
  int r = blockIdx.x;       // b*512 + t
  int d = threadIdx.x;      // 256
  int t = r & 511;
  float acc = cb[d];
#pragma unroll
  for (int k = 0; k < 4; ++k) {
    int tt = t - 3 + k;
    if (tt >= 0) acc = fmaf(cw[d * 4 + k], bf2f(xz[(size_t)(r - 3 + k) * 512 + d]), acc);
  }
  float v = acc * sigmoidf_(acc);
  xc[(size_t)r * 256 + d] = f2bf(v);
}

// dt = softplus(dbl[:,:8] @ w_dt + b_dt); 8 rows/block, w_dt in regs
__global__ __launch_bounds__(256) void dt_kernel(const float* __restrict__ dbl,
                                                 const float* __restrict__ w_dt,
                                                 const float* __restrict__ b_dt,
                                                 float* __restrict__ dtb) {
  int d = threadIdx.x;
  size_t r0 = (size_t)blockIdx.x * 8;
  float wd[8];
#pragma unroll
  for (int j = 0; j < 8; ++j) wd[j] = w_dt[j * 256 + d];
  float bd = b_dt[d];
#pragma unroll
  for (int rr = 0; rr < 8; ++rr) {
    size_t r = r0 + rr;
    float a = bd;
#pragma unroll
    for (int j = 0; j < 8; ++j) a = fmaf(dbl[r * 40 + j], wd[j], a);
    dtb[r * 256 + d] = fmaxf(a, 0.f) + log1pf(__expf(-fabsf(a)));
  }
}

// scan v6: v3 mapping (8d x 8ng, 2 n/thread, 512 blocks = 2/CU) with TC=64
// chunks -> 8 barriers instead of 16. LDS 40KB, double-buffered.
__global__ __launch_bounds__(256) void scan_kernel(
    const float* __restrict__ dtb, const ushort* __restrict__ xcb,
    const float* __restrict__ dbl, const float* __restrict__ A2,
    ushort* __restrict__ y) {
  constexpr int TC = 64;
  constexpr int NC = 512 / TC;  // 8
  __shared__ float  s_dt[2][TC * 32];   // 8KB x2
  __shared__ ushort s_xc[2][TC * 32];   // 4KB x2
  __shared__ float  s_bc[2][TC * 32];   // 8KB x2: [j<16]=B[j], [16+j]=C[j]
  int b    = blockIdx.x >> 3;
  int dblk = blockIdx.x & 7;
  int d0   = dblk * 32;
  int tid  = threadIdx.x;
  int w = tid >> 6, lane = tid & 63;
  int ng = lane >> 3, dl = lane & 7;
  int dd = w * 8 + dl;
  int d  = d0 + dd;
  int n0 = ng * 2;
  float a0 = A2[d * 16 + n0], a1 = A2[d * 16 + n0 + 1];
  float h0 = 0.f, h1 = 0.f;
  const float*  pdt = dtb + (size_t)b * 512 * 256 + d0;
  const ushort* pxc = xcb + (size_t)b * 512 * 256 + d0;
  const float*  pbl = dbl + (size_t)b * 512 * 40;
  ushort* py = y + (size_t)b * 512 * 256 + d;

  // staging: 8 threads per t-row, 2 rows per thread (stt, stt+32)
  const int stt = tid >> 3;         // 0..31
  const int sq  = (tid & 7) * 4;    // 0..28

  {  // prologue: stage chunk 0 (rows stt and stt+32)
#pragma unroll
    for (int rr = 0; rr < 2; ++rr) {
      int row = stt + rr * 32;
      float4 r0 = L4(pdt + (size_t)row * 256 + sq);
      u16x4  r1 = *(const u16x4*)(pxc + (size_t)row * 256 + sq);
      float4 r2 = L4(pbl + (size_t)row * 40 + 8 + sq);
      *(float4*)&s_dt[0][row * 32 + sq] = r0;
      *(u16x4*)&s_xc[0][row * 32 + sq]  = r1;
      *(float4*)&s_bc[0][row * 32 + sq] = r2;
    }
  }
  __syncthreads();

  for (int c = 0; c < NC; ++c) {
    const int buf = c & 1;
    float4 r0[2], r2[2]; u16x4 r1[2];
    const bool more = (c + 1 < NC);
    if (more) {  // issue next chunk's loads early (hide under compute)
#pragma unroll
      for (int rr = 0; rr < 2; ++rr) {
        size_t t1 = (size_t)(c + 1) * TC + stt + rr * 32;
        r0[rr] = L4(pdt + t1 * 256 + sq);
        r1[rr] = *(const u16x4*)(pxc + t1 * 256 + sq);
        r2[rr] = L4(pbl + t1 * 40 + 8 + sq);
      }
    }
#pragma unroll
    for (int tt = 0; tt < TC; ++tt) {
      float dt = s_dt[buf][tt * 32 + dd];
      float xc = bf2f(s_xc[buf][tt * 32 + dd]);
      float2 B2 = *(const float2*)&s_bc[buf][tt * 32 + n0];
      float2 C2 = *(const float2*)&s_bc[buf][tt * 32 + 16 + n0];
      float u = dt * xc;
      h0 = fmaf(exp2f(dt * a0), h0, u * B2.x);
      h1 = fmaf(exp2f(dt * a1), h1, u * B2.y);
      float p = fmaf(h1, C2.y, h0 * C2.x);
      p += __shfl_xor(p, 8);
      p += __shfl_xor(p, 16);
      p += __shfl_xor(p, 32);
      if (ng == 0) py[(size_t)(c * TC + tt) * 256] = f2bf(p);
    }
    if (more) {  // write-late into the other buffer
#pragma unroll
      for (int rr = 0; rr < 2; ++rr) {
        int row = stt + rr * 32;
        *(float4*)&s_dt[buf ^ 1][row * 32 + sq] = r0[rr];
        *(u16x4*)&s_xc[buf ^ 1][row * 32 + sq]  = r1[rr];
        *(float4*)&s_bc[buf ^ 1][row * 32 + sq] = r2[rr];
      }
    }
    __syncthreads();
  }
}

// ------------- fused edge classifier; edges processed in dst-sorted order ---
__global__ __launch_bounds__(256) void cls_fused(
    const float* __restrict__ UV, const int* __restrict__ src,
    const int* __restrict__ dst, const int* __restrict__ eorder,
    const float* __restrict__ s1, const float* __restrict__ s2,
    const float* __restrict__ vecs, const float* __restrict__ g2v,
    const ushort* __restrict__ cw2t, const float* __restrict__ g3v,
    const float* __restrict__ cw3, float* __restrict__ out) {
  __shared__ __align__(16) char ldsA[32768];
  __shared__ __align__(16) char ldsB[16384];
  __shared__ float lmu1[64], lrs1[64], lmu2[64], lrs2[64];
  __shared__ int   lsrc[64], ldst[64], le[64];
  __shared__ float lred[64][2][4];
  const float* G1  = vecs;
  const float* B1c = vecs + 256;
  const float* G2  = vecs + 512;
  const float* B2c = vecs + 640;
  const float* G3  = vecs + 768;
  const float* B3c = vecs + 770;
  int tid = threadIdx.x, lane = tid & 63, w = tid >> 6;
  int e0 = blockIdx.x * 64;
  if (tid < 64) {
    int e = eorder[e0 + tid];
    le[tid] = e;
    int sN = src[e], dN = dst[e];
    lsrc[tid] = sN; ldst[tid] = dN;
    float sum = s1[sN] + s1[dN];
    float sq  = s2[sN] + s2[dN];
    float m = sum * (1.f / 256.f);
    float v = sq * (1.f / 256.f) - m * m;
    lmu1[tid] = m; lrs1[tid] = rsqrtf(v + kEPS);
  }
  __syncthreads();
  {
    int row = tid >> 2, qq = tid & 3;
    const float* pu = UV + (size_t)lsrc[row] * 512;
    const float* pv = UV + (size_t)ldst[row] * 512 + 256;
    float r1 = lrs1[row];
    float rm1 = r1 * lmu1[row];
    float s = 0.f, q = 0.f;
#pragma unroll
    for (int it = 0; it < 8; ++it) {
      int k0 = qq * 8 + it * 32;
      float4 ua = L4(pu + k0), ub = L4(pu + k0 + 4);
      float4 va = L4(pv + k0), vb = L4(pv + k0 + 4);
      float4 Ga = L4(G1 + k0), Gb = L4(G1 + k0 + 4);
      float4 Ba = L4(B1c + k0), Bb = L4(B1c + k0 + 4);
      float4 ga = L4(g2v + k0), gb = L4(g2v + k0 + 4);
      float tv[8], gg[8];
      tv[0] = fmaf(r1, ua.x + va.x, fmaf(-rm1, Ga.x, Ba.x)); gg[0] = ga.x;
      tv[1] = fmaf(r1, ua.y + va.y, fmaf(-rm1, Ga.y, Ba.y)); gg[1] = ga.y;
      tv[2] = fmaf(r1, ua.z + va.z, fmaf(-rm1, Ga.z, Ba.z)); gg[2] = ga.z;
      tv[3] = fmaf(r1, ua.w + va.w, fmaf(-rm1, Ga.w, Ba.w)); gg[3] = ga.w;
      tv[4] = fmaf(r1, ub.x + vb.x, fmaf(-rm1, Gb.x, Bb.x)); gg[4] = gb.x;
      tv[5] = fmaf(r1, ub.y + vb.y, fmaf(-rm1, Gb.y, Bb.y)); gg[5] = gb.y;
      tv[6] = fmaf(r1, ub.z + vb.z, fmaf(-rm1, Gb.z, Bb.z)); gg[6] = gb.z;
      tv[7] = fmaf(r1, ub.w + vb.w, fmaf(-rm1, Gb.w, Bb.w)); gg[7] = gb.w;
      s16x8 pk;
#pragma unroll
      for (int jj = 0; jj < 8; ++jj) {
        float t = tv[jj];
        t = t >= 0.f ? t : 0.01f * t;
        s += t; q += t * t;
        pk[jj] = (short)f2bf(t * gg[jj]);
      }
      *(s16x8*)(ldsA + ((row * 512 + k0 * 2) ^ ((row & 7) << 4))) = pk;
    }
    s += __shfl_xor(s, 1); s += __shfl_xor(s, 2);
    q += __shfl_xor(q, 1); q += __shfl_xor(q, 2);
    if (qq == 0) {
      float m2 = s * (1.f / 256.f);
      float v2 = q * (1.f / 256.f) - m2 * m2;
      lmu2[row] = m2; lrs2[row] = rsqrtf(v2 + kEPS);
    }
  }
  const int wr = w >> 1, wc = w & 1;
  const int sm = tid >> 3, sk8 = (tid & 7) * 8;
  f32x4 acc[2][4];
#pragma unroll
  for (int i = 0; i < 2; ++i)
#pragma unroll
    for (int j = 0; j < 4; ++j) acc[i][j] = f32x4{0.f, 0.f, 0.f, 0.f};
  for (int kt = 0; kt < 4; ++kt) {
    __syncthreads();
#pragma unroll
    for (int i = 0; i < 4; ++i) {
      int n = i * 32 + sm;
      s16x8 bvv = *(const s16x8*)(cw2t + (size_t)n * 256 + kt * 64 + sk8);
      *(s16x8*)(ldsB + ((n * 128 + sk8 * 2) ^ ((n & 7) << 4))) = bvv;
    }
    __syncthreads();
#pragma unroll
    for (int ks = 0; ks < 2; ++ks) {
      const int kbB = ks * 64 + (lane >> 4) * 16;
      const int kbA = kt * 128 + kbB;
      s16x8 av[2], bv[4];
#pragma unroll
      for (int i = 0; i < 2; ++i) {
        int r = wr * 32 + i * 16 + (lane & 15);
        av[i] = *(const s16x8*)(ldsA + ((r * 512 + kbA) ^ ((r & 7) << 4)));
      }
#pragma unroll
      for (int j = 0; j < 4; ++j) {
        int n = wc * 64 + j * 16 + (lane & 15);
        bv[j] = *(const s16x8*)(ldsB + ((n * 128 + kbB) ^ ((n & 7) << 4)));
      }
#pragma unroll
      for (int i = 0; i < 2; ++i)
#pragma unroll
        for (int j = 0; j < 4; ++j)
          acc[i][j] = __builtin_amdgcn_mfma_f32_16x16x32_bf16(av[i], bv[j],
                                                              acc[i][j], 0, 0, 0);
    }
  }
  {
    int g = lane >> 4, lo = lane & 15;
#pragma unroll
    for (int i = 0; i < 2; ++i) {
#pragma unroll
      for (int qv = 0; qv < 4; ++qv) {
        int row = wr * 32 + i * 16 + g * 4 + qv;
        float rs2v = lrs2[row];
        float rm2  = rs2v * lmu2[row];
        float sS = 0.f, sQ = 0.f, sP0 = 0.f, sP1 = 0.f;
#pragma unroll
        for (int j = 0; j < 4; ++j) {
          int col = wc * 64 + j * 16 + lo;
          float t2 = fmaf(rs2v, acc[i][j][qv], fmaf(-rm2, G2[col], B2c[col]));
          t2 = t2 >= 0.f ? t2 : 0.01f * t2;
          sS += t2; sQ += t2 * t2;
          float tg = t2 * g3v[col];
          sP0 = fmaf(tg, cw3[col * 2 + 0], sP0);
          sP1 = fmaf(tg, cw3[col * 2 + 1], sP1);
        }
#pragma unroll
        for (int o = 1; o < 16; o <<= 1) {
          sS += __shfl_xor(sS, o); sQ += __shfl_xor(sQ, o);
          sP0 += __shfl_xor(sP0, o); sP1 += __shfl_xor(sP1, o);
        }
        if (lo == 0) {
          lred[row][wc][0] = sS; lred[row][wc][1] = sQ;
          lred[row][wc][2] = sP0; lred[row][wc][3] = sP1;
        }
      }
    }
  }
  __syncthreads();
  if (tid < 64) {
    float S  = lred[tid][0][0] + lred[tid][1][0];
    float Q  = lred[tid][0][1] + lred[tid][1][1];
    float P0 = lred[tid][0][2] + lred[tid][1][2];
    float P1 = lred[tid][0][3] + lred[tid][1][3];
    float m3 = S * (1.f / 128.f);
    float v3 = Q * (1.f / 128.f) - m3 * m3;
    float r3 = rsqrtf(v3 + kEPS);
    size_t e = (size_t)le[tid];
    out[e * 2 + 0] = fmaf(r3, P0 - m3 * G3[0], B3c[0]);
    out[e * 2 + 1] = fmaf(r3, P1 - m3 * G3[1], B3c[1]);
  }
}

extern "C" void kernel_launch(void* const* d_in, const int* in_sizes, int n_in,
                              void* d_out, int out_size, void* d_ws, size_t ws_size,
                              hipStream_t stream) {
  const float* x      = (const float*)d_in[0];
  const int*   eidx   = (const int*)  d_in[1];
  const float* eattr  = (const float*)d_in[2];
  const float* bn_ng  = (const float*)d_in[3];
  const float* bn_nb  = (const float*)d_in[4];
  const float* bn_eg  = (const float*)d_in[5];
  const float* bn_eb  = (const float*)d_in[6];
  const float* lin_w  = (const float*)d_in[7];
  const float* lin_b  = (const float*)d_in[8];
  const float* w1     = (const float*)d_in[9];
  const float* b1     = (const float*)d_in[10];
  const float* w2     = (const float*)d_in[11];
  const float* b2     = (const float*)d_in[12];
  const float* mlng   = (const float*)d_in[13];
  const float* mlnb   = (const float*)d_in[14];
  const float* w_in   = (const float*)d_in[15];
  const float* conv_w = (const float*)d_in[16];
  const float* conv_b = (const float*)d_in[17];
  const float* w_x    = (const float*)d_in[18];
  const float* w_dt   = (const float*)d_in[19];
  const float* b_dt   = (const float*)d_in[20];
  const float* A_log  = (const float*)d_in[21];
  const float* Dm     = (const float*)d_in[22];
  const float* w_out  = (const float*)d_in[23];
  const float* ln1g   = (const float*)d_in[24];
  const float* ln1b   = (const float*)d_in[25];
  const float* cw1    = (const float*)d_in[26];
  const float* cb1    = (const float*)d_in[27];
  const float* ln2g   = (const float*)d_in[28];
  const float* ln2b   = (const float*)d_in[29];
  const float* cw2    = (const float*)d_in[30];
  const float* cb2    = (const float*)d_in[31];
  const float* ln3g   = (const float*)d_in[32];
  const float* ln3b   = (const float*)d_in[33];
  const float* cw3    = (const float*)d_in[34];
  const float* cb3    = (const float*)d_in[35];
  const int* src = eidx;
  const int* dst = eidx + kE;
  float* out = (float*)d_out;

  // ---- workspace layout ----
  char* ws = (char*)d_ws;
  const size_t MB = 1ull << 20;
  const size_t KB = 1024;
  if (ws_size < 212 * MB) return;
  float* bn_acc = (float*)ws;                       // 512 f32
  float* coef   = (float*)(ws + 4096);              // 512 f32
  float* A2     = (float*)(ws + 8192);              // 4096 f32
  ushort* wt = (ushort*)(ws + 64 * KB);
  ushort* wt_lin  = wt;             // 128x128
  ushort* wt_w1   = wt + 16384;     // 128x128
  ushort* wt_w2   = wt + 32768;     // 128x128
  ushort* wt_win  = wt + 49152;     // 512x128
  ushort* wt_wx   = wt + 114688;    // 128x256 (N=40 padded)
  ushort* wt_wout = wt + 147456;    // 128x256
  ushort* wt_uv   = wt + 180224;    // 512x128
  ushort* wt_cw2  = wt + 245760;    // 128x256
  float* mu   = (float*)(ws + 1 * MB);
  float* rsb  = (float*)(ws + 1 * MB + 256 * KB);
  float* s1b  = (float*)(ws + 1 * MB + 512 * KB);
  float* s2b  = (float*)(ws + 1 * MB + 768 * KB);
  float* vecs = (float*)(ws + 2 * MB);              // 772 f32
  int* cnt    = (int*)(ws + 2 * MB + 128 * KB);     // 32768
  int* base   = (int*)(ws + 2 * MB + 256 * KB);     // 32769
  int* run    = (int*)(ws + 2 * MB + 512 * KB);     // 32768
  int* eorder = (int*)(ws + 3 * MB);                // 262144
  float* h    = (float*)(ws + 4 * MB);              // 16 MB
  char*  S    = ws + 20 * MB;                       // phase-shared region
  // GNN phase
  float*  xn   = (float*)S;                    // 16 MB
  float*  agg  = (float*)(S + 16 * MB);        // 16 MB
  ushort* tmpb = (ushort*)(S + 32 * MB);       // 8 MB (bf16)
  ushort* msg0 = (ushort*)(S + 48 * MB);       // 64 MB (bf16)
  // mamba phase
  ushort* xzb = (ushort*)S;                    // N x 512 bf16 (32 MB)
  ushort* xcb = (ushort*)(S + 32 * MB);        // N x 256 bf16 (16 MB)
  float*  dbl = (float*)(S + 48 * MB);         // N x 40 f32 (5.25 MB)
  ushort* yb  = (ushort*)(S + 56 * MB);        // N x 256 bf16 (16 MB)
  float*  dtb = (float*)(S + 72 * MB);         // N x 256 f32 (32 MB)
  // classifier phase
  float* UV = (float*)S;                       // N x 512 f32 (64 MB)

  // ---- weight prep ----
  prep_wt<<<64,  256, 0, stream>>>(lin_w, 128, 128, wt_lin);
  prep_wt<<<64,  256, 0, stream>>>(w1,    128, 128, wt_w1);
  prep_wt<<<64,  256, 0, stream>>>(w2,    128, 128, wt_w2);
  prep_wt<<<256, 256, 0, stream>>>(w_in,  128, 512, wt_win);
  prep_wt<<<128, 256, 0, stream>>>(w_x,   256, 40,  wt_wx);
  prep_wt<<<128, 256, 0, stream>>>(w_out, 256, 128, wt_wout);
  prep_wt<<<128, 256, 0, stream>>>(cw2,   256, 128, wt_cw2);
  prep_uv<<<256, 256, 0, stream>>>(cw1, ln1g, wt_uv);
  prep_vecs<<<1, 256, 0, stream>>>(cw1, ln1b, cb1, cw2, ln2g, ln2b, cb2,
                                   cw3, ln3g, ln3b, cb3, ln1g, vecs);

  // ---- edge sort by dst (counting sort) ----
  hipMemsetAsync(cnt, 0, 32768 * 4, stream);
  hist_kernel<<<kE / 256, 256, 0, stream>>>(dst, cnt);
  scan32k<<<1, 1024, 0, stream>>>(cnt, base, run);
  scatter_ids<<<kE / 256, 256, 0, stream>>>(dst, run, eorder);

  // ---- GNN ----
  hipMemsetAsync(bn_acc, 0, 512 * 4, stream);
  bn_partial2<<<256, 256, 0, stream>>>(x, kN, bn_acc, bn_acc + 128);
  bn_partial2<<<512, 256, 0, stream>>>(eattr, kE, bn_acc + 256, bn_acc + 384);
  bn_finalize<<<1, 256, 0, stream>>>(bn_acc, bn_ng, bn_nb, bn_eg, bn_eb, coef);
  a2prep<<<16, 256, 0, stream>>>(A_log, A2);
  bn_apply<<<kN * kH / 1024, 256, 0, stream>>>(x, coef, xn);

  // msg0 = BN(ea)@lin_w  (pure streaming GEMM, bf16 out, no gather)
  gemm_mfma<<<dim3(kE / 128, 1), 256, 0, stream>>>(
      ALBN{eattr, coef + 256}, wt_lin, 128, 128, EPStoreBf{msg0, 128});
  // agg[dst] = sum relu(msg0 + lin_b + xn[src]) over sorted edge lists
  agg_fused<<<kN / 2, 256, 0, stream>>>(msg0, xn, eorder, base, src, lin_b, agg);

  // h = relu(leaky((xn+agg)@w1 + b1)@w2 + b2)
  gemm_mfma<<<dim3(kN / 128, 1), 256, 0, stream>>>(
      ALAdd2{xn, agg}, wt_w1, 128, 128, EPBiasLeakyBf{tmpb, 128, b1});
  gemm_mfma<<<dim3(kN / 128, 1), 256, 0, stream>>>(
      ALBf{tmpb, 128}, wt_w2, 128, 128, EPBiasRelu{h, 128, b2});

  // ---- mamba x2 ----
  for (int pass = 0; pass < 2; ++pass) {
    stats_rows<<<kN / 4, 256, 0, stream>>>(h, mu, rsb);
    gemm_mfma<<<dim3(kN / 128, 4), 256, 0, stream>>>(
        ALLN{h, 128, mu, rsb, mlng, mlnb}, wt_win, 128, 512, EPStoreBf{xzb, 512});
    conv_silu<<<kN, 256, 0, stream>>>(xzb, conv_w, conv_b, xcb);
    gemm_mfma<<<dim3(kN / 128, 1), 256, 0, stream>>>(
        ALBf{xcb, 256}, wt_wx, 256, 40, EPStore{dbl, 40});
    dt_kernel<<<kN / 8, 256, 0, stream>>>(dbl, w_dt, b_dt, dtb);
    scan_kernel<<<512, 256, 0, stream>>>(dtb, xcb, dbl, A2, yb);
    gemm_mfma<<<dim3(kN / 128, 1), 256, 0, stream>>>(
        ALMambaY{yb, xcb, xzb, Dm}, wt_wout, 256, 128, EPResidH{h});
  }

  // ---- fused edge classifier (dst-sorted edge order, scatter out) ----
  s12_kernel<<<kN / 4, 256, 0, stream>>>(h, s1b, s2b);
  gemm_mfma<<<dim3(kN / 128, 4), 256, 0, stream>>>(
      ALPlainF{h, 128}, wt_uv, 128, 512, EPStore{UV, 512});
  cls_fused<<<kE / 64, 256, 0, stream>>>(UV, src, dst, eorder, s1b, s2b, vecs,
                                         ln2g, wt_cw2, ln3g, cw3, out);
}

// Round 15
// 1087.449 us; speedup vs baseline: 1.0262x; 1.0142x over previous
//
#include <hip/hip_runtime.h>

#define DEV __device__ __forceinline__

constexpr int   kH  = 128;
constexpr int   kN  = 32768;    // B*NP rows
constexpr int   kE  = 262144;   // edges
constexpr float kEPS = 1e-5f;
constexpr float kLOG2E = 1.4426950408889634f;

typedef short  s16x8 __attribute__((ext_vector_type(8)));
typedef ushort u16x8 __attribute__((ext_vector_type(8)));
typedef ushort u16x4 __attribute__((ext_vector_type(4)));
typedef float  f32x4 __attribute__((ext_vector_type(4)));

DEV float sigmoidf_(float v) { return 1.f / (1.f + __expf(-v)); }

DEV ushort f2bf(float f) {  // RTNE f32 -> bf16
  union { float f; unsigned u; } x{f};
  unsigned r = x.u + 0x7fff + ((x.u >> 16) & 1);
  return (ushort)(r >> 16);
}
DEV float bf2f(ushort u) {
  union { unsigned u; float f; } x{(unsigned)u << 16};
  return x.f;
}
DEV float4 L4(const float* p) { return *(const float4*)p; }
DEV s16x8 pk8(const float* v) {
  s16x8 r;
#pragma unroll
  for (int j = 0; j < 8; ++j) r[j] = (short)f2bf(v[j]);
  return r;
}

// ---------------- batchnorm column stats, vectorized ----------------
__global__ __launch_bounds__(256) void bn_partial2(const float* __restrict__ X, int R,
                                                   float* __restrict__ sum,
                                                   float* __restrict__ sq) {
  int t = threadIdx.x;
  int cg = (t & 31) * 4, rs = t >> 5;
  float sx = 0.f, sy = 0.f, sz = 0.f, sw = 0.f;
  float qx = 0.f, qy = 0.f, qz = 0.f, qw = 0.f;
  for (int r = blockIdx.x * 8 + rs; r < R; r += gridDim.x * 8) {
    float4 v = L4(X + (size_t)r * 128 + cg);
    sx += v.x; sy += v.y; sz += v.z; sw += v.w;
    qx = fmaf(v.x, v.x, qx); qy = fmaf(v.y, v.y, qy);
    qz = fmaf(v.z, v.z, qz); qw = fmaf(v.w, v.w, qw);
  }
  __shared__ float red[8][256];
  red[rs][(t & 31) * 8 + 0] = sx; red[rs][(t & 31) * 8 + 1] = sy;
  red[rs][(t & 31) * 8 + 2] = sz; red[rs][(t & 31) * 8 + 3] = sw;
  red[rs][(t & 31) * 8 + 4] = qx; red[rs][(t & 31) * 8 + 5] = qy;
  red[rs][(t & 31) * 8 + 6] = qz; red[rs][(t & 31) * 8 + 7] = qw;
  __syncthreads();
  if (rs == 0) {
    int cq = t & 31;
#pragma unroll
    for (int jj = 0; jj < 4; ++jj) {
      float S = 0.f, Q = 0.f;
#pragma unroll
      for (int i = 0; i < 8; ++i) {
        S += red[i][cq * 8 + jj];
        Q += red[i][cq * 8 + 4 + jj];
      }
      atomicAdd(&sum[cq * 4 + jj], S);
      atomicAdd(&sq[cq * 4 + jj], Q);
    }
  }
}

__global__ void bn_finalize(const float* __restrict__ acc,
                            const float* __restrict__ gx, const float* __restrict__ bx,
                            const float* __restrict__ ge, const float* __restrict__ be,
                            float* __restrict__ coef) {
  int t = threadIdx.x;
  if (t < 128) {
    float m  = acc[t]       * (1.f / 32768.f);
    float v  = acc[128 + t] * (1.f / 32768.f) - m * m;
    float sc = gx[t] * rsqrtf(v + kEPS);
    coef[t] = sc; coef[128 + t] = bx[t] - m * sc;
  } else {
    int c = t - 128;
    float m  = acc[256 + c] * (1.f / 262144.f);
    float v  = acc[384 + c] * (1.f / 262144.f) - m * m;
    float sc = ge[c] * rsqrtf(v + kEPS);
    coef[256 + c] = sc; coef[384 + c] = be[c] - m * sc;
  }
}

__global__ void bn_apply(const float* __restrict__ x, const float* __restrict__ coef,
                         float* __restrict__ xn) {
  size_t i = ((size_t)blockIdx.x * 256 + threadIdx.x) * 4;
  int c = (int)(i & 127);
  float4 v = L4(x + i);
  float4 s = L4(coef + c), h = L4(coef + 128 + c);
  float4 o;
  o.x = fmaf(v.x, s.x, h.x); o.y = fmaf(v.y, s.y, h.y);
  o.z = fmaf(v.z, s.z, h.z); o.w = fmaf(v.w, s.w, h.w);
  *(float4*)(xn + i) = o;
}

__global__ void a2prep(const float* __restrict__ A_log, float* __restrict__ A2) {
  int i = blockIdx.x * 256 + threadIdx.x;
  A2[i] = -__expf(A_log[i]) * kLOG2E;
}

// convert weight W[K][N] f32 -> Wt[Npad][K] bf16 (transposed, zero-padded cols)
__global__ void prep_wt(const float* __restrict__ W, int Kdim, int Ncols,
                        ushort* __restrict__ Wt) {
  int idx = blockIdx.x * 256 + threadIdx.x;
  int n = idx / Kdim, k = idx - n * Kdim;
  float v = (n < Ncols) ? W[(size_t)k * Ncols + n] : 0.f;
  Wt[idx] = f2bf(v);
}

__global__ void prep_uv(const float* __restrict__ cw1, const float* __restrict__ g1,
                        ushort* __restrict__ Wt) {
  int idx = blockIdx.x * 256 + threadIdx.x;  // 512*128
  int n = idx >> 7, k = idx & 127;
  int krow = (n < 256) ? k : 128 + k;
  int ncol = n & 255;
  Wt[idx] = f2bf(g1[krow] * cw1[(size_t)krow * 256 + ncol]);
}

// vecs layout: G1[256] B1c[256] G2[128] B2c[128] G3[2] B3c[2]
__global__ void prep_vecs(const float* __restrict__ cw1, const float* __restrict__ b1v,
                          const float* __restrict__ cb1,
                          const float* __restrict__ cw2, const float* __restrict__ g2v,
                          const float* __restrict__ b2v, const float* __restrict__ cb2,
                          const float* __restrict__ cw3, const float* __restrict__ g3v,
                          const float* __restrict__ b3v, const float* __restrict__ cb3,
                          const float* __restrict__ g1v, float* __restrict__ vecs) {
  int t = threadIdx.x;
  {
    float gs = 0.f, bs = 0.f;
    for (int k = 0; k < 256; ++k) {
      float w = cw1[(size_t)k * 256 + t];
      gs = fmaf(g1v[k], w, gs);
      bs = fmaf(b1v[k], w, bs);
    }
    vecs[t] = gs; vecs[256 + t] = bs + cb1[t];
  }
  if (t < 128) {
    float gs = 0.f, bs = 0.f;
    for (int k = 0; k < 256; ++k) {
      float w = cw2[(size_t)k * 128 + t];
      gs = fmaf(g2v[k], w, gs);
      bs = fmaf(b2v[k], w, bs);
    }
    vecs[512 + t] = gs; vecs[640 + t] = bs + cb2[t];
  }
  if (t < 2) {
    float gs = 0.f, bs = 0.f;
    for (int c = 0; c < 128; ++c) {
      float w = cw3[c * 2 + t];
      gs = fmaf(g3v[c], w, gs);
      bs = fmaf(b3v[c], w, bs);
    }
    vecs[768 + t] = gs; vecs[770 + t] = bs + cb3[t];
  }
}

// ---------------- edge sort (counting sort by dst) ----------------
__global__ void hist_kernel(const int* __restrict__ dst, int* __restrict__ cnt) {
  int e = blockIdx.x * 256 + threadIdx.x;
  atomicAdd(&cnt[dst[e]], 1);
}

__global__ __launch_bounds__(1024) void scan32k(const int* __restrict__ cnt,
                                                int* __restrict__ base,
                                                int* __restrict__ run) {
  __shared__ int part[1024];
  int t = threadIdx.x;
  int loc[32]; int s = 0;
  const int* p = cnt + t * 32;
#pragma unroll
  for (int i = 0; i < 32; ++i) { loc[i] = s; s += p[i]; }
  part[t] = s;
  __syncthreads();
  for (int o = 1; o < 1024; o <<= 1) {
    int v = (t >= o) ? part[t - o] : 0;
    __syncthreads();
    part[t] += v;
    __syncthreads();
  }
  int ex = part[t] - s;
#pragma unroll
  for (int i = 0; i < 32; ++i) {
    int b = ex + loc[i];
    base[t * 32 + i] = b; run[t * 32 + i] = b;
  }
  if (t == 1023) base[32768] = part[1023];
}

__global__ void scatter_ids(const int* __restrict__ dst, int* __restrict__ run,
                            int* __restrict__ eorder) {
  int e = blockIdx.x * 256 + threadIdx.x;
  int p = atomicAdd(&run[dst[e]], 1);
  eorder[p] = e;
}

// agg[v] = sum over sorted in-edges: relu(msg0[e] + lin_b + xn[src[e]])
__global__ __launch_bounds__(256) void agg_fused(
    const ushort* __restrict__ msg0, const float* __restrict__ xn,
    const int* __restrict__ eorder, const int* __restrict__ base,
    const int* __restrict__ src, const float* __restrict__ lin_b,
    float* __restrict__ agg) {
  int node = blockIdx.x * 2 + (threadIdx.x >> 7);
  int c = threadIdx.x & 127;
  int b0 = base[node], b1 = base[node + 1];
  float bias = lin_b[c];
  float s = 0.f;
  for (int j = b0; j < b1; ++j) {
    int e = eorder[j];
    float m = bf2f(msg0[(size_t)e * 128 + c]) + bias + xn[(size_t)src[e] * 128 + c];
    s += fmaxf(m, 0.f);
  }
  agg[(size_t)node * 128 + c] = s;
}

// per-node sum & sumsq of h rows (for edge LN1 stats)
__global__ void s12_kernel(const float* __restrict__ h, float* __restrict__ s1,
                           float* __restrict__ s2) {
  int wid = threadIdx.x >> 6, lane = threadIdx.x & 63;
  int r = blockIdx.x * 4 + wid;
  const float* row = h + (size_t)r * 128;
  float v0 = row[lane], v1 = row[lane + 64];
  float s = v0 + v1;
  float q = v0 * v0 + v1 * v1;
#pragma unroll
  for (int o = 32; o; o >>= 1) { s += __shfl_xor(s, o); q += __shfl_xor(q, o); }
  if (lane == 0) { s1[r] = s; s2[r] = q; }
}

// ---------------- rowwise LN stats (mamba) ----------------
__global__ void stats_rows(const float* __restrict__ X, float* __restrict__ mu,
                           float* __restrict__ rs) {
  int wid = threadIdx.x >> 6, lane = threadIdx.x & 63;
  int r = blockIdx.x * 4 + wid;
  const float* row = X + (size_t)r * 128;
  float v0 = row[lane], v1 = row[lane + 64];
  float s = v0 + v1;
#pragma unroll
  for (int o = 32; o; o >>= 1) s += __shfl_xor(s, o);
  float m = s * (1.f / 128.f);
  float d0 = v0 - m, d1 = v1 - m;
  float q = d0 * d0 + d1 * d1;
#pragma unroll
  for (int o = 32; o; o >>= 1) q += __shfl_xor(q, o);
  if (lane == 0) { mu[r] = m; rs[r] = rsqrtf(q * (1.f / 128.f) + kEPS); }
}

// ---------------- A-load functors: ld8 returns bf16x8 ---------------------
struct ALPlainF {  // f32 source
  const float* A; int lda;
  DEV s16x8 ld8(int r, int k) const {
    float b[8];
    const float* p = A + (size_t)r * lda + k;
    *(float4*)b = L4(p); *(float4*)(b + 4) = L4(p + 4);
    return pk8(b);
  }
};
struct ALBf {  // already-bf16 source, pure copy
  const ushort* A; int lda;
  DEV s16x8 ld8(int r, int k) const {
    return *(const s16x8*)(A + (size_t)r * lda + k);
  }
};
struct ALBN {
  const float* A; const float* coef;
  DEV s16x8 ld8(int r, int k) const {
    const float* p = A + (size_t)r * 128 + k;
    float4 a0 = L4(p), a1 = L4(p + 4);
    float4 s0 = L4(coef + k), s1 = L4(coef + k + 4);
    float4 h0 = L4(coef + 128 + k), h1 = L4(coef + 132 + k);
    float b[8];
    b[0] = fmaf(a0.x, s0.x, h0.x); b[1] = fmaf(a0.y, s0.y, h0.y);
    b[2] = fmaf(a0.z, s0.z, h0.z); b[3] = fmaf(a0.w, s0.w, h0.w);
    b[4] = fmaf(a1.x, s1.x, h1.x); b[5] = fmaf(a1.y, s1.y, h1.y);
    b[6] = fmaf(a1.z, s1.z, h1.z); b[7] = fmaf(a1.w, s1.w, h1.w);
    return pk8(b);
  }
};
struct ALAdd2 {
  const float* X; const float* Y;
  DEV s16x8 ld8(int r, int k) const {
    const float* p = X + (size_t)r * 128 + k;
    const float* q = Y + (size_t)r * 128 + k;
    float4 a0 = L4(p), a1 = L4(p + 4), b0 = L4(q), b1 = L4(q + 4);
    float b[8];
    b[0] = a0.x + b0.x; b[1] = a0.y + b0.y; b[2] = a0.z + b0.z; b[3] = a0.w + b0.w;
    b[4] = a1.x + b1.x; b[5] = a1.y + b1.y; b[6] = a1.z + b1.z; b[7] = a1.w + b1.w;
    return pk8(b);
  }
};
struct ALLN {
  const float* A; int lda; const float* mu; const float* rs;
  const float* g; const float* b;
  DEV s16x8 ld8(int r, int k) const {
    float m = mu[r], s = rs[r];
    const float* p = A + (size_t)r * lda + k;
    float4 a0 = L4(p), a1 = L4(p + 4);
    float4 g0 = L4(g + k), g1 = L4(g + k + 4), b0 = L4(b + k), b1 = L4(b + k + 4);
    float o[8];
    o[0] = fmaf((a0.x - m) * s, g0.x, b0.x); o[1] = fmaf((a0.y - m) * s, g0.y, b0.y);
    o[2] = fmaf((a0.z - m) * s, g0.z, b0.z); o[3] = fmaf((a0.w - m) * s, g0.w, b0.w);
    o[4] = fmaf((a1.x - m) * s, g1.x, b1.x); o[5] = fmaf((a1.y - m) * s, g1.y, b1.y);
    o[6] = fmaf((a1.z - m) * s, g1.z, b1.z); o[7] = fmaf((a1.w - m) * s, g1.w, b1.w);
    return pk8(o);
  }
};
struct ALMambaY {  // (scan_y + Dm*xc) * silu(z), all bf16 inputs
  const ushort* y; const ushort* xc; const ushort* xz; const float* Dm;
  DEV s16x8 ld8(int r, int k) const {
    u16x8 yv = *(const u16x8*)(y + (size_t)r * 256 + k);
    u16x8 cv = *(const u16x8*)(xc + (size_t)r * 256 + k);
    u16x8 zv = *(const u16x8*)(xz + (size_t)r * 512 + 256 + k);
    s16x8 o;
#pragma unroll
    for (int j = 0; j < 8; ++j) {
      float zf = bf2f(zv[j]);
      float val = fmaf(Dm[k + j], bf2f(cv[j]), bf2f(yv[j])) * (zf * sigmoidf_(zf));
      o[j] = (short)f2bf(val);
    }
    return o;
  }
};

struct EPStore {
  float* C; int ldc;
  DEV void operator()(int r, int c, float v) const { C[(size_t)r * ldc + c] = v; }
};
struct EPStoreBf {
  ushort* C; int ldc;
  DEV void operator()(int r, int c, float v) const { C[(size_t)r * ldc + c] = f2bf(v); }
};
struct EPBiasLeakyBf {
  ushort* C; int ldc; const float* bias;
  DEV void operator()(int r, int c, float v) const {
    v += bias[c];
    v = v >= 0.f ? v : 0.01f * v;
    C[(size_t)r * ldc + c] = f2bf(v);
  }
};
struct EPBiasRelu {
  float* C; int ldc; const float* bias;
  DEV void operator()(int r, int c, float v) const {
    C[(size_t)r * ldc + c] = fmaxf(v + bias[c], 0.f);
  }
};
struct EPResidH {
  float* h;
  DEV void operator()(int r, int c, float v) const {
    size_t i = (size_t)r * 128 + c; h[i] = h[i] + v;
  }
};

// ------------- bf16 MFMA GEMM: 128x128 tile, BK=64, 256 thr (4 waves 2x2) ---
template <class AL, class EP>
__global__ __launch_bounds__(256) void gemm_mfma(AL aload, const ushort* __restrict__ Wt,
                                                 int Kdim, int Ncols, EP epi) {
  __shared__ __align__(16) char lds[32768];
  const int tid = threadIdx.x;
  const int lane = tid & 63;
  const int w = tid >> 6;
  const int wr = w >> 1, wc = w & 1;
  const int row0 = blockIdx.x * 128, col0 = blockIdx.y * 128;
  const int sm = tid >> 3;
  const int sk = (tid & 7) * 8;
  f32x4 acc[4][4];
#pragma unroll
  for (int i = 0; i < 4; ++i)
#pragma unroll
    for (int j = 0; j < 4; ++j) acc[i][j] = f32x4{0.f, 0.f, 0.f, 0.f};

  for (int kt = 0; kt < Kdim; kt += 64) {
#pragma unroll
    for (int i = 0; i < 4; ++i) {
      int n = i * 32 + sm;
      s16x8 v = *(const s16x8*)(Wt + (size_t)(col0 + n) * Kdim + kt + sk);
      *(s16x8*)(lds + 16384 + ((n * 128 + sk * 2) ^ ((n & 7) << 4))) = v;
    }
#pragma unroll
    for (int i = 0; i < 4; ++i) {
      int m = i * 32 + sm;
      s16x8 v = aload.ld8(row0 + m, kt + sk);
      *(s16x8*)(lds + ((m * 128 + sk * 2) ^ ((m & 7) << 4))) = v;
    }
    __syncthreads();
#pragma unroll
    for (int ks = 0; ks < 2; ++ks) {
      const int kb = ks * 64 + (lane >> 4) * 16;
      s16x8 av[4], bv[4];
#pragma unroll
      for (int i = 0; i < 4; ++i) {
        int r = wr * 64 + i * 16 + (lane & 15);
        av[i] = *(const s16x8*)(lds + ((r * 128 + kb) ^ ((r & 7) << 4)));
      }
#pragma unroll
      for (int j = 0; j < 4; ++j) {
        int n = wc * 64 + j * 16 + (lane & 15);
        bv[j] = *(const s16x8*)(lds + 16384 + ((n * 128 + kb) ^ ((n & 7) << 4)));
      }
#pragma unroll
      for (int i = 0; i < 4; ++i)
#pragma unroll
        for (int j = 0; j < 4; ++j)
          acc[i][j] = __builtin_amdgcn_mfma_f32_16x16x32_bf16(av[i], bv[j],
                                                              acc[i][j], 0, 0, 0);
    }
    __syncthreads();
  }
#pragma unroll
  for (int i = 0; i < 4; ++i)
#pragma unroll
    for (int q = 0; q < 4; ++q) {
      int r = row0 + wr * 64 + i * 16 + (lane >> 4) * 4 + q;
#pragma unroll
      for (int j = 0; j < 4; ++j) {
        int c = col0 + wc * 64 + j * 16 + (lane & 15);
        if (c < Ncols) epi(r, c, acc[i][j][q]);
      }
    }
}

// ---------------- mamba pieces ----------------
__global__ void conv_silu(const ushort* __restrict__ xz, const float* __restrict__ cw,
                          const float* __restrict__ cb, ushort* __restrict__ xc) {
  int r = blockIdx.x;       // b*512 + t
  int d = threadIdx.x;      // 256
  int t = r & 511;
  float acc = cb[d];
#pragma unroll
  for (int k = 0; k < 4; ++k) {
    int tt = t - 3 + k;
    if (tt >= 0) acc = fmaf(cw[d * 4 + k], bf2f(xz[(size_t)(r - 3 + k) * 512 + d]), acc);
  }
  float v = acc * sigmoidf_(acc);
  xc[(size_t)r * 256 + d] = f2bf(v);
}

// dt = softplus(dbl[:,:8] @ w_dt + b_dt); 8 rows/block, w_dt in regs
__global__ __launch_bounds__(256) void dt_kernel(const float* __restrict__ dbl,
                                                 const float* __restrict__ w_dt,
                                                 const float* __restrict__ b_dt,
                                                 float* __restrict__ dtb) {
  int d = threadIdx.x;
  size_t r0 = (size_t)blockIdx.x * 8;
  float wd[8];
#pragma unroll
  for (int j = 0; j < 8; ++j) wd[j] = w_dt[j * 256 + d];
  float bd = b_dt[d];
#pragma unroll
  for (int rr = 0; rr < 8; ++rr) {
    size_t r = r0 + rr;
    float a = bd;
#pragma unroll
    for (int j = 0; j < 8; ++j) a = fmaf(dbl[r * 40 + j], wd[j], a);
    dtb[r * 256 + d] = fmaxf(a, 0.f) + log1pf(__expf(-fabsf(a)));
  }
}

// scan v3 (best measured): LDS double-buffered TC=32 chunks; dtb f32.
// thread = (d, ng) 2 n-states; 8d x 8ng per wave; 512 blocks = 2/CU.
__global__ __launch_bounds__(256) void scan_kernel(
    const float* __restrict__ dtb, const ushort* __restrict__ xcb,
    const float* __restrict__ dbl, const float* __restrict__ A2,
    ushort* __restrict__ y) {
  constexpr int TC = 32;
  constexpr int NC = 512 / TC;
  __shared__ float  s_dt[2][TC * 32];
  __shared__ ushort s_xc[2][TC * 32];
  __shared__ float  s_bc[2][TC * 32];  // [j<16]=B[j], [16+j]=C[j]
  int b    = blockIdx.x >> 3;
  int dblk = blockIdx.x & 7;
  int d0   = dblk * 32;
  int tid  = threadIdx.x;
  int w = tid >> 6, lane = tid & 63;
  int ng = lane >> 3, dl = lane & 7;
  int dd = w * 8 + dl;
  int d  = d0 + dd;
  int n0 = ng * 2;
  float a0 = A2[d * 16 + n0], a1 = A2[d * 16 + n0 + 1];
  float h0 = 0.f, h1 = 0.f;
  const float*  pdt = dtb + (size_t)b * 512 * 256 + d0;
  const ushort* pxc = xcb + (size_t)b * 512 * 256 + d0;
  const float*  pbl = dbl + (size_t)b * 512 * 40;
  ushort* py = y + (size_t)b * 512 * 256 + d;
  const int stt = tid >> 3;
  const int sq  = (tid & 7) * 4;
  {
    float4 r0 = L4(pdt + (size_t)stt * 256 + sq);
    u16x4  r1 = *(const u16x4*)(pxc + (size_t)stt * 256 + sq);
    float4 r2 = L4(pbl + (size_t)stt * 40 + 8 + sq);
    *(float4*)&s_dt[0][stt * 32 + sq] = r0;
    *(u16x4*)&s_xc[0][stt * 32 + sq] = r1;
    *(float4*)&s_bc[0][stt * 32 + sq] = r2;
  }
  __syncthreads();
  for (int c = 0; c < NC; ++c) {
    const int buf = c & 1;
    float4 r0, r2; u16x4 r1;
    const bool more = (c + 1 < NC);
    if (more) {
      size_t t1 = (size_t)(c + 1) * TC + stt;
      r0 = L4(pdt + t1 * 256 + sq);
      r1 = *(const u16x4*)(pxc + t1 * 256 + sq);
      r2 = L4(pbl + t1 * 40 + 8 + sq);
    }
#pragma unroll
    for (int tt = 0; tt < TC; ++tt) {
      float dt = s_dt[buf][tt * 32 + dd];
      float xc = bf2f(s_xc[buf][tt * 32 + dd]);
      float2 B2 = *(const float2*)&s_bc[buf][tt * 32 + n0];
      float2 C2 = *(const float2*)&s_bc[buf][tt * 32 + 16 + n0];
      float u = dt * xc;
      h0 = fmaf(exp2f(dt * a0), h0, u * B2.x);
      h1 = fmaf(exp2f(dt * a1), h1, u * B2.y);
      float p = fmaf(h1, C2.y, h0 * C2.x);
      p += __shfl_xor(p, 8);
      p += __shfl_xor(p, 16);
      p += __shfl_xor(p, 32);
      if (ng == 0) py[(size_t)(c * TC + tt) * 256] = f2bf(p);
    }
    if (more) {
      *(float4*)&s_dt[buf ^ 1][stt * 32 + sq] = r0;
      *(u16x4*)&s_xc[buf ^ 1][stt * 32 + sq] = r1;
      *(float4*)&s_bc[buf ^ 1][stt * 32 + sq] = r2;
    }
    __syncthreads();
  }
}

// ------------- fused edge classifier; UV bf16, dst-sorted edge order --------
__global__ __launch_bounds__(256) void cls_fused(
    const ushort* __restrict__ UV, const int* __restrict__ src,
    const int* __restrict__ dst, const int* __restrict__ eorder,
    const float* __restrict__ s1, const float* __restrict__ s2,
    const float* __restrict__ vecs, const float* __restrict__ g2v,
    const ushort* __restrict__ cw2t, const float* __restrict__ g3v,
    const float* __restrict__ cw3, float* __restrict__ out) {
  __shared__ __align__(16) char ldsA[32768];
  __shared__ __align__(16) char ldsB[16384];
  __shared__ float lmu1[64], lrs1[64], lmu2[64], lrs2[64];
  __shared__ int   lsrc[64], ldst[64], le[64];
  __shared__ float lred[64][2][4];
  const float* G1  = vecs;
  const float* B1c = vecs + 256;
  const float* G2  = vecs + 512;
  const float* B2c = vecs + 640;
  const float* G3  = vecs + 768;
  const float* B3c = vecs + 770;
  int tid = threadIdx.x, lane = tid & 63, w = tid >> 6;
  int e0 = blockIdx.x * 64;
  if (tid < 64) {
    int e = eorder[e0 + tid];
    le[tid] = e;
    int sN = src[e], dN = dst[e];
    lsrc[tid] = sN; ldst[tid] = dN;
    float sum = s1[sN] + s1[dN];
    float sq  = s2[sN] + s2[dN];
    float m = sum * (1.f / 256.f);
    float v = sq * (1.f / 256.f) - m * m;
    lmu1[tid] = m; lrs1[tid] = rsqrtf(v + kEPS);
  }
  __syncthreads();
  {
    int row = tid >> 2, qq = tid & 3;
    const ushort* pu = UV + (size_t)lsrc[row] * 512;
    const ushort* pv = UV + (size_t)ldst[row] * 512 + 256;
    float r1 = lrs1[row];
    float rm1 = r1 * lmu1[row];
    float s = 0.f, q = 0.f;
#pragma unroll
    for (int it = 0; it < 8; ++it) {
      int k0 = qq * 8 + it * 32;
      u16x8 u8 = *(const u16x8*)(pu + k0);
      u16x8 v8 = *(const u16x8*)(pv + k0);
      float4 Ga = L4(G1 + k0), Gb = L4(G1 + k0 + 4);
      float4 Ba = L4(B1c + k0), Bb = L4(B1c + k0 + 4);
      float4 ga = L4(g2v + k0), gb = L4(g2v + k0 + 4);
      float tv[8], gg[8];
      tv[0] = fmaf(r1, bf2f(u8[0]) + bf2f(v8[0]), fmaf(-rm1, Ga.x, Ba.x)); gg[0] = ga.x;
      tv[1] = fmaf(r1, bf2f(u8[1]) + bf2f(v8[1]), fmaf(-rm1, Ga.y, Ba.y)); gg[1] = ga.y;
      tv[2] = fmaf(r1, bf2f(u8[2]) + bf2f(v8[2]), fmaf(-rm1, Ga.z, Ba.z)); gg[2] = ga.z;
      tv[3] = fmaf(r1, bf2f(u8[3]) + bf2f(v8[3]), fmaf(-rm1, Ga.w, Ba.w)); gg[3] = ga.w;
      tv[4] = fmaf(r1, bf2f(u8[4]) + bf2f(v8[4]), fmaf(-rm1, Gb.x, Bb.x)); gg[4] = gb.x;
      tv[5] = fmaf(r1, bf2f(u8[5]) + bf2f(v8[5]), fmaf(-rm1, Gb.y, Bb.y)); gg[5] = gb.y;
      tv[6] = fmaf(r1, bf2f(u8[6]) + bf2f(v8[6]), fmaf(-rm1, Gb.z, Bb.z)); gg[6] = gb.z;
      tv[7] = fmaf(r1, bf2f(u8[7]) + bf2f(v8[7]), fmaf(-rm1, Gb.w, Bb.w)); gg[7] = gb.w;
      s16x8 pk;
#pragma unroll
      for (int jj = 0; jj < 8; ++jj) {
        float t = tv[jj];
        t = t >= 0.f ? t : 0.01f * t;
        s += t; q += t * t;
        pk[jj] = (short)f2bf(t * gg[jj]);
      }
      *(s16x8*)(ldsA + ((row * 512 + k0 * 2) ^ ((row & 7) << 4))) = pk;
    }
    s += __shfl_xor(s, 1); s += __shfl_xor(s, 2);
    q += __shfl_xor(q, 1); q += __shfl_xor(q, 2);
    if (qq == 0) {
      float m2 = s * (1.f / 256.f);
      float v2 = q * (1.f / 256.f) - m2 * m2;
      lmu2[row] = m2; lrs2[row] = rsqrtf(v2 + kEPS);
    }
  }
  const int wr = w >> 1, wc = w & 1;
  const int sm = tid >> 3, sk8 = (tid & 7) * 8;
  f32x4 acc[2][4];
#pragma unroll
  for (int i = 0; i < 2; ++i)
#pragma unroll
    for (int j = 0; j < 4; ++j) acc[i][j] = f32x4{0.f, 0.f, 0.f, 0.f};
  for (int kt = 0; kt < 4; ++kt) {
    __syncthreads();
#pragma unroll
    for (int i = 0; i < 4; ++i) {
      int n = i * 32 + sm;
      s16x8 bvv = *(const s16x8*)(cw2t + (size_t)n * 256 + kt * 64 + sk8);
      *(s16x8*)(ldsB + ((n * 128 + sk8 * 2) ^ ((n & 7) << 4))) = bvv;
    }
    __syncthreads();
#pragma unroll
    for (int ks = 0; ks < 2; ++ks) {
      const int kbB = ks * 64 + (lane >> 4) * 16;
      const int kbA = kt * 128 + kbB;
      s16x8 av[2], bv[4];
#pragma unroll
      for (int i = 0; i < 2; ++i) {
        int r = wr * 32 + i * 16 + (lane & 15);
        av[i] = *(const s16x8*)(ldsA + ((r * 512 + kbA) ^ ((r & 7) << 4)));
      }
#pragma unroll
      for (int j = 0; j < 4; ++j) {
        int n = wc * 64 + j * 16 + (lane & 15);
        bv[j] = *(const s16x8*)(ldsB + ((n * 128 + kbB) ^ ((n & 7) << 4)));
      }
#pragma unroll
      for (int i = 0; i < 2; ++i)
#pragma unroll
        for (int j = 0; j < 4; ++j)
          acc[i][j] = __builtin_amdgcn_mfma_f32_16x16x32_bf16(av[i], bv[j],
                                                              acc[i][j], 0, 0, 0);
    }
  }
  {
    int g = lane >> 4, lo = lane & 15;
#pragma unroll
    for (int i = 0; i < 2; ++i) {
#pragma unroll
      for (int qv = 0; qv < 4; ++qv) {
        int row = wr * 32 + i * 16 + g * 4 + qv;
        float rs2v = lrs2[row];
        float rm2  = rs2v * lmu2[row];
        float sS = 0.f, sQ = 0.f, sP0 = 0.f, sP1 = 0.f;
#pragma unroll
        for (int j = 0; j < 4; ++j) {
          int col = wc * 64 + j * 16 + lo;
          float t2 = fmaf(rs2v, acc[i][j][qv], fmaf(-rm2, G2[col], B2c[col]));
          t2 = t2 >= 0.f ? t2 : 0.01f * t2;
          sS += t2; sQ += t2 * t2;
          float tg = t2 * g3v[col];
          sP0 = fmaf(tg, cw3[col * 2 + 0], sP0);
          sP1 = fmaf(tg, cw3[col * 2 + 1], sP1);
        }
#pragma unroll
        for (int o = 1; o < 16; o <<= 1) {
          sS += __shfl_xor(sS, o); sQ += __shfl_xor(sQ, o);
          sP0 += __shfl_xor(sP0, o); sP1 += __shfl_xor(sP1, o);
        }
        if (lo == 0) {
          lred[row][wc][0] = sS; lred[row][wc][1] = sQ;
          lred[row][wc][2] = sP0; lred[row][wc][3] = sP1;
        }
      }
    }
  }
  __syncthreads();
  if (tid < 64) {
    float S  = lred[tid][0][0] + lred[tid][1][0];
    float Q  = lred[tid][0][1] + lred[tid][1][1];
    float P0 = lred[tid][0][2] + lred[tid][1][2];
    float P1 = lred[tid][0][3] + lred[tid][1][3];
    float m3 = S * (1.f / 128.f);
    float v3 = Q * (1.f / 128.f) - m3 * m3;
    float r3 = rsqrtf(v3 + kEPS);
    size_t e = (size_t)le[tid];
    out[e * 2 + 0] = fmaf(r3, P0 - m3 * G3[0], B3c[0]);
    out[e * 2 + 1] = fmaf(r3, P1 - m3 * G3[1], B3c[1]);
  }
}

extern "C" void kernel_launch(void* const* d_in, const int* in_sizes, int n_in,
                              void* d_out, int out_size, void* d_ws, size_t ws_size,
                              hipStream_t stream) {
  const float* x      = (const float*)d_in[0];
  const int*   eidx   = (const int*)  d_in[1];
  const float* eattr  = (const float*)d_in[2];
  const float* bn_ng  = (const float*)d_in[3];
  const float* bn_nb  = (const float*)d_in[4];
  const float* bn_eg  = (const float*)d_in[5];
  const float* bn_eb  = (const float*)d_in[6];
  const float* lin_w  = (const float*)d_in[7];
  const float* lin_b  = (const float*)d_in[8];
  const float* w1     = (const float*)d_in[9];
  const float* b1     = (const float*)d_in[10];
  const float* w2     = (const float*)d_in[11];
  const float* b2     = (const float*)d_in[12];
  const float* mlng   = (const float*)d_in[13];
  const float* mlnb   = (const float*)d_in[14];
  const float* w_in   = (const float*)d_in[15];
  const float* conv_w = (const float*)d_in[16];
  const float* conv_b = (const float*)d_in[17];
  const float* w_x    = (const float*)d_in[18];
  const float* w_dt   = (const float*)d_in[19];
  const float* b_dt   = (const float*)d_in[20];
  const float* A_log  = (const float*)d_in[21];
  const float* Dm     = (const float*)d_in[22];
  const float* w_out  = (const float*)d_in[23];
  const float* ln1g   = (const float*)d_in[24];
  const float* ln1b   = (const float*)d_in[25];
  const float* cw1    = (const float*)d_in[26];
  const float* cb1    = (const float*)d_in[27];
  const float* ln2g   = (const float*)d_in[28];
  const float* ln2b   = (const float*)d_in[29];
  const float* cw2    = (const float*)d_in[30];
  const float* cb2    = (const float*)d_in[31];
  const float* ln3g   = (const float*)d_in[32];
  const float* ln3b   = (const float*)d_in[33];
  const float* cw3    = (const float*)d_in[34];
  const float* cb3    = (const float*)d_in[35];
  const int* src = eidx;
  const int* dst = eidx + kE;
  float* out = (float*)d_out;

  // ---- workspace layout ----
  char* ws = (char*)d_ws;
  const size_t MB = 1ull << 20;
  const size_t KB = 1024;
  if (ws_size < 212 * MB) return;
  float* bn_acc = (float*)ws;                       // 512 f32
  float* coef   = (float*)(ws + 4096);              // 512 f32
  float* A2     = (float*)(ws + 8192);              // 4096 f32
  ushort* wt = (ushort*)(ws + 64 * KB);
  ushort* wt_lin  = wt;             // 128x128
  ushort* wt_w1   = wt + 16384;     // 128x128
  ushort* wt_w2   = wt + 32768;     // 128x128
  ushort* wt_win  = wt + 49152;     // 512x128
  ushort* wt_wx   = wt + 114688;    // 128x256 (N=40 padded)
  ushort* wt_wout = wt + 147456;    // 128x256
  ushort* wt_uv   = wt + 180224;    // 512x128
  ushort* wt_cw2  = wt + 245760;    // 128x256
  float* mu   = (float*)(ws + 1 * MB);
  float* rsb  = (float*)(ws + 1 * MB + 256 * KB);
  float* s1b  = (float*)(ws + 1 * MB + 512 * KB);
  float* s2b  = (float*)(ws + 1 * MB + 768 * KB);
  float* vecs = (float*)(ws + 2 * MB);              // 772 f32
  int* cnt    = (int*)(ws + 2 * MB + 128 * KB);     // 32768
  int* base   = (int*)(ws + 2 * MB + 256 * KB);     // 32769
  int* run    = (int*)(ws + 2 * MB + 512 * KB);     // 32768
  int* eorder = (int*)(ws + 3 * MB);                // 262144
  float* h    = (float*)(ws + 4 * MB);              // 16 MB
  char*  S    = ws + 20 * MB;                       // phase-shared region
  // GNN phase
  float*  xn   = (float*)S;                    // 16 MB
  float*  agg  = (float*)(S + 16 * MB);        // 16 MB
  ushort* tmpb = (ushort*)(S + 32 * MB);       // 8 MB (bf16)
  ushort* msg0 = (ushort*)(S + 48 * MB);       // 64 MB (bf16)
  // mamba phase
  ushort* xzb = (ushort*)S;                    // N x 512 bf16 (32 MB)
  ushort* xcb = (ushort*)(S + 32 * MB);        // N x 256 bf16 (16 MB)
  float*  dbl = (float*)(S + 48 * MB);         // N x 40 f32 (5.25 MB)
  ushort* yb  = (ushort*)(S + 56 * MB);        // N x 256 bf16 (16 MB)
  float*  dtb = (float*)(S + 72 * MB);         // N x 256 f32 (32 MB)
  // classifier phase
  ushort* UV = (ushort*)S;                     // N x 512 bf16 (32 MB)

  // ---- weight prep ----
  prep_wt<<<64,  256, 0, stream>>>(lin_w, 128, 128, wt_lin);
  prep_wt<<<64,  256, 0, stream>>>(w1,    128, 128, wt_w1);
  prep_wt<<<64,  256, 0, stream>>>(w2,    128, 128, wt_w2);
  prep_wt<<<256, 256, 0, stream>>>(w_in,  128, 512, wt_win);
  prep_wt<<<128, 256, 0, stream>>>(w_x,   256, 40,  wt_wx);
  prep_wt<<<128, 256, 0, stream>>>(w_out, 256, 128, wt_wout);
  prep_wt<<<128, 256, 0, stream>>>(cw2,   256, 128, wt_cw2);
  prep_uv<<<256, 256, 0, stream>>>(cw1, ln1g, wt_uv);
  prep_vecs<<<1, 256, 0, stream>>>(cw1, ln1b, cb1, cw2, ln2g, ln2b, cb2,
                                   cw3, ln3g, ln3b, cb3, ln1g, vecs);

  // ---- edge sort by dst (counting sort) ----
  hipMemsetAsync(cnt, 0, 32768 * 4, stream);
  hist_kernel<<<kE / 256, 256, 0, stream>>>(dst, cnt);
  scan32k<<<1, 1024, 0, stream>>>(cnt, base, run);
  scatter_ids<<<kE / 256, 256, 0, stream>>>(dst, run, eorder);

  // ---- GNN ----
  hipMemsetAsync(bn_acc, 0, 512 * 4, stream);
  bn_partial2<<<256, 256, 0, stream>>>(x, kN, bn_acc, bn_acc + 128);
  bn_partial2<<<512, 256, 0, stream>>>(eattr, kE, bn_acc + 256, bn_acc + 384);
  bn_finalize<<<1, 256, 0, stream>>>(bn_acc, bn_ng, bn_nb, bn_eg, bn_eb, coef);
  a2prep<<<16, 256, 0, stream>>>(A_log, A2);
  bn_apply<<<kN * kH / 1024, 256, 0, stream>>>(x, coef, xn);

  // msg0 = BN(ea)@lin_w  (pure streaming GEMM, bf16 out, no gather)
  gemm_mfma<<<dim3(kE / 128, 1), 256, 0, stream>>>(
      ALBN{eattr, coef + 256}, wt_lin, 128, 128, EPStoreBf{msg0, 128});
  // agg[dst] = sum relu(msg0 + lin_b + xn[src]) over sorted edge lists
  agg_fused<<<kN / 2, 256, 0, stream>>>(msg0, xn, eorder, base, src, lin_b, agg);

  // h = relu(leaky((xn+agg)@w1 + b1)@w2 + b2)
  gemm_mfma<<<dim3(kN / 128, 1), 256, 0, stream>>>(
      ALAdd2{xn, agg}, wt_w1, 128, 128, EPBiasLeakyBf{tmpb, 128, b1});
  gemm_mfma<<<dim3(kN / 128, 1), 256, 0, stream>>>(
      ALBf{tmpb, 128}, wt_w2, 128, 128, EPBiasRelu{h, 128, b2});

  // ---- mamba x2 ----
  for (int pass = 0; pass < 2; ++pass) {
    stats_rows<<<kN / 4, 256, 0, stream>>>(h, mu, rsb);
    gemm_mfma<<<dim3(kN / 128, 4), 256, 0, stream>>>(
        ALLN{h, 128, mu, rsb, mlng, mlnb}, wt_win, 128, 512, EPStoreBf{xzb, 512});
    conv_silu<<<kN, 256, 0, stream>>>(xzb, conv_w, conv_b, xcb);
    gemm_mfma<<<dim3(kN / 128, 1), 256, 0, stream>>>(
        ALBf{xcb, 256}, wt_wx, 256, 40, EPStore{dbl, 40});
    dt_kernel<<<kN / 8, 256, 0, stream>>>(dbl, w_dt, b_dt, dtb);
    scan_kernel<<<512, 256, 0, stream>>>(dtb, xcb, dbl, A2, yb);
    gemm_mfma<<<dim3(kN / 128, 1), 256, 0, stream>>>(
        ALMambaY{yb, xcb, xzb, Dm}, wt_wout, 256, 128, EPResidH{h});
  }

  // ---- fused edge classifier (bf16 UV, dst-sorted order, scatter out) ----
  s12_kernel<<<kN / 4, 256, 0, stream>>>(h, s1b, s2b);
  gemm_mfma<<<dim3(kN / 128, 4), 256, 0, stream>>>(
      ALPlainF{h, 128}, wt_uv, 128, 512, EPStoreBf{UV, 512});
  cls_fused<<<kE / 64, 256, 0, stream>>>(UV, src, dst, eorder, s1b, s2b, vecs,
                                         ln2g, wt_cw2, ln3g, cw3, out);
}

// Round 16
// 1082.673 us; speedup vs baseline: 1.0308x; 1.0044x over previous
//
#include <hip/hip_runtime.h>

#define DEV __device__ __forceinline__

constexpr int   kH  = 128;
constexpr int   kN  = 32768;    // B*NP rows
constexpr int   kE  = 262144;   // edges
constexpr float kEPS = 1e-5f;
constexpr float kLOG2E = 1.4426950408889634f;

typedef short  s16x8 __attribute__((ext_vector_type(8)));
typedef ushort u16x8 __attribute__((ext_vector_type(8)));
typedef ushort u16x4 __attribute__((ext_vector_type(4)));
typedef float  f32x4 __attribute__((ext_vector_type(4)));

DEV float sigmoidf_(float v) { return 1.f / (1.f + __expf(-v)); }

DEV ushort f2bf(float f) {  // RTNE f32 -> bf16
  union { float f; unsigned u; } x{f};
  unsigned r = x.u + 0x7fff + ((x.u >> 16) & 1);
  return (ushort)(r >> 16);
}
DEV float bf2f(ushort u) {
  union { unsigned u; float f; } x{(unsigned)u << 16};
  return x.f;
}
DEV float4 L4(const float* p) { return *(const float4*)p; }
DEV s16x8 pk8(const float* v) {
  s16x8 r;
#pragma unroll
  for (int j = 0; j < 8; ++j) r[j] = (short)f2bf(v[j]);
  return r;
}

// ---------------- batchnorm column stats, vectorized ----------------
__global__ __launch_bounds__(256) void bn_partial2(const float* __restrict__ X, int R,
                                                   float* __restrict__ sum,
                                                   float* __restrict__ sq) {
  int t = threadIdx.x;
  int cg = (t & 31) * 4, rs = t >> 5;
  float sx = 0.f, sy = 0.f, sz = 0.f, sw = 0.f;
  float qx = 0.f, qy = 0.f, qz = 0.f, qw = 0.f;
  for (int r = blockIdx.x * 8 + rs; r < R; r += gridDim.x * 8) {
    float4 v = L4(X + (size_t)r * 128 + cg);
    sx += v.x; sy += v.y; sz += v.z; sw += v.w;
    qx = fmaf(v.x, v.x, qx); qy = fmaf(v.y, v.y, qy);
    qz = fmaf(v.z, v.z, qz); qw = fmaf(v.w, v.w, qw);
  }
  __shared__ float red[8][256];
  red[rs][(t & 31) * 8 + 0] = sx; red[rs][(t & 31) * 8 + 1] = sy;
  red[rs][(t & 31) * 8 + 2] = sz; red[rs][(t & 31) * 8 + 3] = sw;
  red[rs][(t & 31) * 8 + 4] = qx; red[rs][(t & 31) * 8 + 5] = qy;
  red[rs][(t & 31) * 8 + 6] = qz; red[rs][(t & 31) * 8 + 7] = qw;
  __syncthreads();
  if (rs == 0) {
    int cq = t & 31;
#pragma unroll
    for (int jj = 0; jj < 4; ++jj) {
      float S = 0.f, Q = 0.f;
#pragma unroll
      for (int i = 0; i < 8; ++i) {
        S += red[i][cq * 8 + jj];
        Q += red[i][cq * 8 + 4 + jj];
      }
      atomicAdd(&sum[cq * 4 + jj], S);
      atomicAdd(&sq[cq * 4 + jj], Q);
    }
  }
}

__global__ void bn_finalize(const float* __restrict__ acc,
                            const float* __restrict__ gx, const float* __restrict__ bx,
                            const float* __restrict__ ge, const float* __restrict__ be,
                            float* __restrict__ coef) {
  int t = threadIdx.x;
  if (t < 128) {
    float m  = acc[t]       * (1.f / 32768.f);
    float v  = acc[128 + t] * (1.f / 32768.f) - m * m;
    float sc = gx[t] * rsqrtf(v + kEPS);
    coef[t] = sc; coef[128 + t] = bx[t] - m * sc;
  } else {
    int c = t - 128;
    float m  = acc[256 + c] * (1.f / 262144.f);
    float v  = acc[384 + c] * (1.f / 262144.f) - m * m;
    float sc = ge[c] * rsqrtf(v + kEPS);
    coef[256 + c] = sc; coef[384 + c] = be[c] - m * sc;
  }
}

__global__ void bn_apply(const float* __restrict__ x, const float* __restrict__ coef,
                         float* __restrict__ xn) {
  size_t i = ((size_t)blockIdx.x * 256 + threadIdx.x) * 4;
  int c = (int)(i & 127);
  float4 v = L4(x + i);
  float4 s = L4(coef + c), h = L4(coef + 128 + c);
  float4 o;
  o.x = fmaf(v.x, s.x, h.x); o.y = fmaf(v.y, s.y, h.y);
  o.z = fmaf(v.z, s.z, h.z); o.w = fmaf(v.w, s.w, h.w);
  *(float4*)(xn + i) = o;
}

__global__ void a2prep(const float* __restrict__ A_log, float* __restrict__ A2) {
  int i = blockIdx.x * 256 + threadIdx.x;
  A2[i] = -__expf(A_log[i]) * kLOG2E;
}

// convert weight W[K][N] f32 -> Wt[Npad][K] bf16 (transposed, zero-padded cols)
__global__ void prep_wt(const float* __restrict__ W, int Kdim, int Ncols,
                        ushort* __restrict__ Wt) {
  int idx = blockIdx.x * 256 + threadIdx.x;
  int n = idx / Kdim, k = idx - n * Kdim;
  float v = (n < Ncols) ? W[(size_t)k * Ncols + n] : 0.f;
  Wt[idx] = f2bf(v);
}

__global__ void prep_uv(const float* __restrict__ cw1, const float* __restrict__ g1,
                        ushort* __restrict__ Wt) {
  int idx = blockIdx.x * 256 + threadIdx.x;  // 512*128
  int n = idx >> 7, k = idx & 127;
  int krow = (n < 256) ? k : 128 + k;
  int ncol = n & 255;
  Wt[idx] = f2bf(g1[krow] * cw1[(size_t)krow * 256 + ncol]);
}

// vecs layout: G1[256] B1c[256] G2[128] B2c[128] G3[2] B3c[2]
__global__ void prep_vecs(const float* __restrict__ cw1, const float* __restrict__ b1v,
                          const float* __restrict__ cb1,
                          const float* __restrict__ cw2, const float* __restrict__ g2v,
                          const float* __restrict__ b2v, const float* __restrict__ cb2,
                          const float* __restrict__ cw3, const float* __restrict__ g3v,
                          const float* __restrict__ b3v, const float* __restrict__ cb3,
                          const float* __restrict__ g1v, float* __restrict__ vecs) {
  int t = threadIdx.x;
  {
    float gs = 0.f, bs = 0.f;
    for (int k = 0; k < 256; ++k) {
      float w = cw1[(size_t)k * 256 + t];
      gs = fmaf(g1v[k], w, gs);
      bs = fmaf(b1v[k], w, bs);
    }
    vecs[t] = gs; vecs[256 + t] = bs + cb1[t];
  }
  if (t < 128) {
    float gs = 0.f, bs = 0.f;
    for (int k = 0; k < 256; ++k) {
      float w = cw2[(size_t)k * 128 + t];
      gs = fmaf(g2v[k], w, gs);
      bs = fmaf(b2v[k], w, bs);
    }
    vecs[512 + t] = gs; vecs[640 + t] = bs + cb2[t];
  }
  if (t < 2) {
    float gs = 0.f, bs = 0.f;
    for (int c = 0; c < 128; ++c) {
      float w = cw3[c * 2 + t];
      gs = fmaf(g3v[c], w, gs);
      bs = fmaf(b3v[c], w, bs);
    }
    vecs[768 + t] = gs; vecs[770 + t] = bs + cb3[t];
  }
}

// ---------------- edge sort (counting sort by dst) ----------------
__global__ void hist_kernel(const int* __restrict__ dst, int* __restrict__ cnt) {
  int e = blockIdx.x * 256 + threadIdx.x;
  atomicAdd(&cnt[dst[e]], 1);
}

__global__ __launch_bounds__(1024) void scan32k(const int* __restrict__ cnt,
                                                int* __restrict__ base,
                                                int* __restrict__ run) {
  __shared__ int part[1024];
  int t = threadIdx.x;
  int loc[32]; int s = 0;
  const int* p = cnt + t * 32;
#pragma unroll
  for (int i = 0; i < 32; ++i) { loc[i] = s; s += p[i]; }
  part[t] = s;
  __syncthreads();
  for (int o = 1; o < 1024; o <<= 1) {
    int v = (t >= o) ? part[t - o] : 0;
    __syncthreads();
    part[t] += v;
    __syncthreads();
  }
  int ex = part[t] - s;
#pragma unroll
  for (int i = 0; i < 32; ++i) {
    int b = ex + loc[i];
    base[t * 32 + i] = b; run[t * 32 + i] = b;
  }
  if (t == 1023) base[32768] = part[1023];
}

__global__ void scatter_ids(const int* __restrict__ dst, int* __restrict__ run,
                            int* __restrict__ eorder) {
  int e = blockIdx.x * 256 + threadIdx.x;
  int p = atomicAdd(&run[dst[e]], 1);
  eorder[p] = e;
}

// agg[v] = sum over sorted in-edges: relu(msg0[e] + lin_b + xn[src[e]])
__global__ __launch_bounds__(256) void agg_fused(
    const ushort* __restrict__ msg0, const float* __restrict__ xn,
    const int* __restrict__ eorder, const int* __restrict__ base,
    const int* __restrict__ src, const float* __restrict__ lin_b,
    float* __restrict__ agg) {
  int node = blockIdx.x * 2 + (threadIdx.x >> 7);
  int c = threadIdx.x & 127;
  int b0 = base[node], b1 = base[node + 1];
  float bias = lin_b[c];
  float s = 0.f;
  for (int j = b0; j < b1; ++j) {
    int e = eorder[j];
    float m = bf2f(msg0[(size_t)e * 128 + c]) + bias + xn[(size_t)src[e] * 128 + c];
    s += fmaxf(m, 0.f);
  }
  agg[(size_t)node * 128 + c] = s;
}

// ---------------- A-load functors: ld8 returns bf16x8 ---------------------
struct ALPlainF {  // f32 source
  const float* A; int lda;
  DEV s16x8 ld8(int r, int k) const {
    float b[8];
    const float* p = A + (size_t)r * lda + k;
    *(float4*)b = L4(p); *(float4*)(b + 4) = L4(p + 4);
    return pk8(b);
  }
};
struct ALBf {  // already-bf16 source, pure copy
  const ushort* A; int lda;
  DEV s16x8 ld8(int r, int k) const {
    return *(const s16x8*)(A + (size_t)r * lda + k);
  }
};
struct ALBN {
  const float* A; const float* coef;
  DEV s16x8 ld8(int r, int k) const {
    const float* p = A + (size_t)r * 128 + k;
    float4 a0 = L4(p), a1 = L4(p + 4);
    float4 s0 = L4(coef + k), s1 = L4(coef + k + 4);
    float4 h0 = L4(coef + 128 + k), h1 = L4(coef + 132 + k);
    float b[8];
    b[0] = fmaf(a0.x, s0.x, h0.x); b[1] = fmaf(a0.y, s0.y, h0.y);
    b[2] = fmaf(a0.z, s0.z, h0.z); b[3] = fmaf(a0.w, s0.w, h0.w);
    b[4] = fmaf(a1.x, s1.x, h1.x); b[5] = fmaf(a1.y, s1.y, h1.y);
    b[6] = fmaf(a1.z, s1.z, h1.z); b[7] = fmaf(a1.w, s1.w, h1.w);
    return pk8(b);
  }
};
struct ALAdd2 {
  const float* X; const float* Y;
  DEV s16x8 ld8(int r, int k) const {
    const float* p = X + (size_t)r * 128 + k;
    const float* q = Y + (size_t)r * 128 + k;
    float4 a0 = L4(p), a1 = L4(p + 4), b0 = L4(q), b1 = L4(q + 4);
    float b[8];
    b[0] = a0.x + b0.x; b[1] = a0.y + b0.y; b[2] = a0.z + b0.z; b[3] = a0.w + b0.w;
    b[4] = a1.x + b1.x; b[5] = a1.y + b1.y; b[6] = a1.z + b1.z; b[7] = a1.w + b1.w;
    return pk8(b);
  }
};
struct ALLN {
  const float* A; int lda; const float* mu; const float* rs;
  const float* g; const float* b;
  DEV s16x8 ld8(int r, int k) const {
    float m = mu[r], s = rs[r];
    const float* p = A + (size_t)r * lda + k;
    float4 a0 = L4(p), a1 = L4(p + 4);
    float4 g0 = L4(g + k), g1 = L4(g + k + 4), b0 = L4(b + k), b1 = L4(b + k + 4);
    float o[8];
    o[0] = fmaf((a0.x - m) * s, g0.x, b0.x); o[1] = fmaf((a0.y - m) * s, g0.y, b0.y);
    o[2] = fmaf((a0.z - m) * s, g0.z, b0.z); o[3] = fmaf((a0.w - m) * s, g0.w, b0.w);
    o[4] = fmaf((a1.x - m) * s, g1.x, b1.x); o[5] = fmaf((a1.y - m) * s, g1.y, b1.y);
    o[6] = fmaf((a1.z - m) * s, g1.z, b1.z); o[7] = fmaf((a1.w - m) * s, g1.w, b1.w);
    return pk8(o);
  }
};
struct ALMambaY {  // (scan_y + Dm*xc) * silu(z), all bf16 inputs
  const ushort* y; const ushort* xc; const ushort* xz; const float* Dm;
  DEV s16x8 ld8(int r, int k) const {
    u16x8 yv = *(const u16x8*)(y + (size_t)r * 256 + k);
    u16x8 cv = *(const u16x8*)(xc + (size_t)r * 256 + k);
    u16x8 zv = *(const u16x8*)(xz + (size_t)r * 512 + 256 + k);
    s16x8 o;
#pragma unroll
    for (int j = 0; j < 8; ++j) {
      float zf = bf2f(zv[j]);
      float val = fmaf(Dm[k + j], bf2f(cv[j]), bf2f(yv[j])) * (zf * sigmoidf_(zf));
      o[j] = (short)f2bf(val);
    }
    return o;
  }
};

// epilogues return the stored (post-activation) value for optional stats
struct EPStore {
  float* C; int ldc;
  DEV float operator()(int r, int c, float v) const {
    C[(size_t)r * ldc + c] = v; return v;
  }
};
struct EPStoreBf {
  ushort* C; int ldc;
  DEV float operator()(int r, int c, float v) const {
    C[(size_t)r * ldc + c] = f2bf(v); return v;
  }
};
struct EPBiasLeakyBf {
  ushort* C; int ldc; const float* bias;
  DEV float operator()(int r, int c, float v) const {
    v += bias[c];
    v = v >= 0.f ? v : 0.01f * v;
    C[(size_t)r * ldc + c] = f2bf(v);
    return v;
  }
};
struct EPBiasRelu {
  float* C; int ldc; const float* bias;
  DEV float operator()(int r, int c, float v) const {
    v = fmaxf(v + bias[c], 0.f);
    C[(size_t)r * ldc + c] = v;
    return v;
  }
};
struct EPResidH {
  float* h;
  DEV float operator()(int r, int c, float v) const {
    size_t i = (size_t)r * 128 + c;
    float nv = h[i] + v;
    h[i] = nv;
    return nv;
  }
};

// ------------- bf16 MFMA GEMM: 128x128 tile, BK=64, 256 thr (4 waves 2x2) ---
// STATS: 0=none, 1=write mu/rs of stored rows (Ncols must be 128),
//        2=write raw sum/sumsq (s1/s2). Stats computed on epilogue outputs.
template <int STATS, class AL, class EP>
__global__ __launch_bounds__(256) void gemm_mfma(AL aload, const ushort* __restrict__ Wt,
                                                 int Kdim, int Ncols, EP epi,
                                                 float* __restrict__ st1,
                                                 float* __restrict__ st2) {
  __shared__ __align__(16) char lds[32768];
  const int tid = threadIdx.x;
  const int lane = tid & 63;
  const int w = tid >> 6;
  const int wr = w >> 1, wc = w & 1;
  const int row0 = blockIdx.x * 128, col0 = blockIdx.y * 128;
  const int sm = tid >> 3;
  const int sk = (tid & 7) * 8;
  f32x4 acc[4][4];
#pragma unroll
  for (int i = 0; i < 4; ++i)
#pragma unroll
    for (int j = 0; j < 4; ++j) acc[i][j] = f32x4{0.f, 0.f, 0.f, 0.f};

  for (int kt = 0; kt < Kdim; kt += 64) {
#pragma unroll
    for (int i = 0; i < 4; ++i) {
      int n = i * 32 + sm;
      s16x8 v = *(const s16x8*)(Wt + (size_t)(col0 + n) * Kdim + kt + sk);
      *(s16x8*)(lds + 16384 + ((n * 128 + sk * 2) ^ ((n & 7) << 4))) = v;
    }
#pragma unroll
    for (int i = 0; i < 4; ++i) {
      int m = i * 32 + sm;
      s16x8 v = aload.ld8(row0 + m, kt + sk);
      *(s16x8*)(lds + ((m * 128 + sk * 2) ^ ((m & 7) << 4))) = v;
    }
    __syncthreads();
#pragma unroll
    for (int ks = 0; ks < 2; ++ks) {
      const int kb = ks * 64 + (lane >> 4) * 16;
      s16x8 av[4], bv[4];
#pragma unroll
      for (int i = 0; i < 4; ++i) {
        int r = wr * 64 + i * 16 + (lane & 15);
        av[i] = *(const s16x8*)(lds + ((r * 128 + kb) ^ ((r & 7) << 4)));
      }
#pragma unroll
      for (int j = 0; j < 4; ++j) {
        int n = wc * 64 + j * 16 + (lane & 15);
        bv[j] = *(const s16x8*)(lds + 16384 + ((n * 128 + kb) ^ ((n & 7) << 4)));
      }
#pragma unroll
      for (int i = 0; i < 4; ++i)
#pragma unroll
        for (int j = 0; j < 4; ++j)
          acc[i][j] = __builtin_amdgcn_mfma_f32_16x16x32_bf16(av[i], bv[j],
                                                              acc[i][j], 0, 0, 0);
    }
    __syncthreads();
  }
  if constexpr (STATS == 0) {
#pragma unroll
    for (int i = 0; i < 4; ++i)
#pragma unroll
      for (int q = 0; q < 4; ++q) {
        int r = row0 + wr * 64 + i * 16 + (lane >> 4) * 4 + q;
#pragma unroll
        for (int j = 0; j < 4; ++j) {
          int c = col0 + wc * 64 + j * 16 + (lane & 15);
          if (c < Ncols) epi(r, c, acc[i][j][q]);
        }
      }
  } else {
    __shared__ float sred[128][2][2];
#pragma unroll
    for (int i = 0; i < 4; ++i)
#pragma unroll
      for (int q = 0; q < 4; ++q) {
        int rloc = wr * 64 + i * 16 + (lane >> 4) * 4 + q;
        int r = row0 + rloc;
        float sS = 0.f, sQ = 0.f;
#pragma unroll
        for (int j = 0; j < 4; ++j) {
          int c = wc * 64 + j * 16 + (lane & 15);
          float v = epi(r, c, acc[i][j][q]);
          sS += v; sQ = fmaf(v, v, sQ);
        }
#pragma unroll
        for (int o = 1; o < 16; o <<= 1) {
          sS += __shfl_xor(sS, o); sQ += __shfl_xor(sQ, o);
        }
        if ((lane & 15) == 0) { sred[rloc][wc][0] = sS; sred[rloc][wc][1] = sQ; }
      }
    __syncthreads();
    if (tid < 128) {
      float S = sred[tid][0][0] + sred[tid][1][0];
      float Q = sred[tid][0][1] + sred[tid][1][1];
      if (STATS == 1) {
        float m = S * (1.f / 128.f);
        float v = Q * (1.f / 128.f) - m * m;
        st1[row0 + tid] = m;
        st2[row0 + tid] = rsqrtf(v + kEPS);
      } else {
        st1[row0 + tid] = S;
        st2[row0 + tid] = Q;
      }
    }
  }
}

// ---------------- mamba pieces ----------------
__global__ void conv_silu(const ushort* __restrict__ xz, const float* __restrict__ cw,
                          const float* __restrict__ cb, ushort* __restrict__ xc) {
  int r = blockIdx.x;       // b*512 + t
  int d = threadIdx.x;      // 256
  int t = r & 511;
  float acc = cb[d];
#pragma unroll
  for (int k = 0; k < 4; ++k) {
    int tt = t - 3 + k;
    if (tt >= 0) acc = fmaf(cw[d * 4 + k], bf2f(xz[(size_t)(r - 3 + k) * 512 + d]), acc);
  }
  float v = acc * sigmoidf_(acc);
  xc[(size_t)r * 256 + d] = f2bf(v);
}

// dt = softplus(dbl[:,:8] @ w_dt + b_dt); 8 rows/block, w_dt in regs
__global__ __launch_bounds__(256) void dt_kernel(const float* __restrict__ dbl,
                                                 const float* __restrict__ w_dt,
                                                 const float* __restrict__ b_dt,
                                                 float* __restrict__ dtb) {
  int d = threadIdx.x;
  size_t r0 = (size_t)blockIdx.x * 8;
  float wd[8];
#pragma unroll
  for (int j = 0; j < 8; ++j) wd[j] = w_dt[j * 256 + d];
  float bd = b_dt[d];
#pragma unroll
  for (int rr = 0; rr < 8; ++rr) {
    size_t r = r0 + rr;
    float a = bd;
#pragma unroll
    for (int j = 0; j < 8; ++j) a = fmaf(dbl[r * 40 + j], wd[j], a);
    dtb[r * 256 + d] = fmaxf(a, 0.f) + log1pf(__expf(-fabsf(a)));
  }
}

// scan v3 (best measured): LDS double-buffered TC=32 chunks; dtb f32.
__global__ __launch_bounds__(256) void scan_kernel(
    const float* __restrict__ dtb, const ushort* __restrict__ xcb,
    const float* __restrict__ dbl, const float* __restrict__ A2,
    ushort* __restrict__ y) {
  constexpr int TC = 32;
  constexpr int NC = 512 / TC;
  __shared__ float  s_dt[2][TC * 32];
  __shared__ ushort s_xc[2][TC * 32];
  __shared__ float  s_bc[2][TC * 32];  // [j<16]=B[j], [16+j]=C[j]
  int b    = blockIdx.x >> 3;
  int dblk = blockIdx.x & 7;
  int d0   = dblk * 32;
  int tid  = threadIdx.x;
  int w = tid >> 6, lane = tid & 63;
  int ng = lane >> 3, dl = lane & 7;
  int dd = w * 8 + dl;
  int d  = d0 + dd;
  int n0 = ng * 2;
  float a0 = A2[d * 16 + n0], a1 = A2[d * 16 + n0 + 1];
  float h0 = 0.f, h1 = 0.f;
  const float*  pdt = dtb + (size_t)b * 512 * 256 + d0;
  const ushort* pxc = xcb + (size_t)b * 512 * 256 + d0;
  const float*  pbl = dbl + (size_t)b * 512 * 40;
  ushort* py = y + (size_t)b * 512 * 256 + d;
  const int stt = tid >> 3;
  const int sq  = (tid & 7) * 4;
  {
    float4 r0 = L4(pdt + (size_t)stt * 256 + sq);
    u16x4  r1 = *(const u16x4*)(pxc + (size_t)stt * 256 + sq);
    float4 r2 = L4(pbl + (size_t)stt * 40 + 8 + sq);
    *(float4*)&s_dt[0][stt * 32 + sq] = r0;
    *(u16x4*)&s_xc[0][stt * 32 + sq] = r1;
    *(float4*)&s_bc[0][stt * 32 + sq] = r2;
  }
  __syncthreads();
  for (int c = 0; c < NC; ++c) {
    const int buf = c & 1;
    float4 r0, r2; u16x4 r1;
    const bool more = (c + 1 < NC);
    if (more) {
      size_t t1 = (size_t)(c + 1) * TC + stt;
      r0 = L4(pdt + t1 * 256 + sq);
      r1 = *(const u16x4*)(pxc + t1 * 256 + sq);
      r2 = L4(pbl + t1 * 40 + 8 + sq);
    }
#pragma unroll
    for (int tt = 0; tt < TC; ++tt) {
      float dt = s_dt[buf][tt * 32 + dd];
      float xc = bf2f(s_xc[buf][tt * 32 + dd]);
      float2 B2 = *(const float2*)&s_bc[buf][tt * 32 + n0];
      float2 C2 = *(const float2*)&s_bc[buf][tt * 32 + 16 + n0];
      float u = dt * xc;
      h0 = fmaf(exp2f(dt * a0), h0, u * B2.x);
      h1 = fmaf(exp2f(dt * a1), h1, u * B2.y);
      float p = fmaf(h1, C2.y, h0 * C2.x);
      p += __shfl_xor(p, 8);
      p += __shfl_xor(p, 16);
      p += __shfl_xor(p, 32);
      if (ng == 0) py[(size_t)(c * TC + tt) * 256] = f2bf(p);
    }
    if (more) {
      *(float4*)&s_dt[buf ^ 1][stt * 32 + sq] = r0;
      *(u16x4*)&s_xc[buf ^ 1][stt * 32 + sq] = r1;
      *(float4*)&s_bc[buf ^ 1][stt * 32 + sq] = r2;
    }
    __syncthreads();
  }
}

// ------------- fused edge classifier; UV bf16, dst-sorted edge order --------
__global__ __launch_bounds__(256) void cls_fused(
    const ushort* __restrict__ UV, const int* __restrict__ src,
    const int* __restrict__ dst, const int* __restrict__ eorder,
    const float* __restrict__ s1, const float* __restrict__ s2,
    const float* __restrict__ vecs, const float* __restrict__ g2v,
    const ushort* __restrict__ cw2t, const float* __restrict__ g3v,
    const float* __restrict__ cw3, float* __restrict__ out) {
  __shared__ __align__(16) char ldsA[32768];
  __shared__ __align__(16) char ldsB[16384];
  __shared__ float lmu1[64], lrs1[64], lmu2[64], lrs2[64];
  __shared__ int   lsrc[64], ldst[64], le[64];
  __shared__ float lred[64][2][4];
  const float* G1  = vecs;
  const float* B1c = vecs + 256;
  const float* G2  = vecs + 512;
  const float* B2c = vecs + 640;
  const float* G3  = vecs + 768;
  const float* B3c = vecs + 770;
  int tid = threadIdx.x, lane = tid & 63, w = tid >> 6;
  int e0 = blockIdx.x * 64;
  if (tid < 64) {
    int e = eorder[e0 + tid];
    le[tid] = e;
    int sN = src[e], dN = dst[e];
    lsrc[tid] = sN; ldst[tid] = dN;
    float sum = s1[sN] + s1[dN];
    float sq  = s2[sN] + s2[dN];
    float m = sum * (1.f / 256.f);
    float v = sq * (1.f / 256.f) - m * m;
    lmu1[tid] = m; lrs1[tid] = rsqrtf(v + kEPS);
  }
  __syncthreads();
  {
    int row = tid >> 2, qq = tid & 3;
    const ushort* pu = UV + (size_t)lsrc[row] * 512;
    const ushort* pv = UV + (size_t)ldst[row] * 512 + 256;
    float r1 = lrs1[row];
    float rm1 = r1 * lmu1[row];
    float s = 0.f, q = 0.f;
#pragma unroll
    for (int it = 0; it < 8; ++it) {
      int k0 = qq * 8 + it * 32;
      u16x8 u8 = *(const u16x8*)(pu + k0);
      u16x8 v8 = *(const u16x8*)(pv + k0);
      float4 Ga = L4(G1 + k0), Gb = L4(G1 + k0 + 4);
      float4 Ba = L4(B1c + k0), Bb = L4(B1c + k0 + 4);
      float4 ga = L4(g2v + k0), gb = L4(g2v + k0 + 4);
      float tv[8], gg[8];
      tv[0] = fmaf(r1, bf2f(u8[0]) + bf2f(v8[0]), fmaf(-rm1, Ga.x, Ba.x)); gg[0] = ga.x;
      tv[1] = fmaf(r1, bf2f(u8[1]) + bf2f(v8[1]), fmaf(-rm1, Ga.y, Ba.y)); gg[1] = ga.y;
      tv[2] = fmaf(r1, bf2f(u8[2]) + bf2f(v8[2]), fmaf(-rm1, Ga.z, Ba.z)); gg[2] = ga.z;
      tv[3] = fmaf(r1, bf2f(u8[3]) + bf2f(v8[3]), fmaf(-rm1, Ga.w, Ba.w)); gg[3] = ga.w;
      tv[4] = fmaf(r1, bf2f(u8[4]) + bf2f(v8[4]), fmaf(-rm1, Gb.x, Bb.x)); gg[4] = gb.x;
      tv[5] = fmaf(r1, bf2f(u8[5]) + bf2f(v8[5]), fmaf(-rm1, Gb.y, Bb.y)); gg[5] = gb.y;
      tv[6] = fmaf(r1, bf2f(u8[6]) + bf2f(v8[6]), fmaf(-rm1, Gb.z, Bb.z)); gg[6] = gb.z;
      tv[7] = fmaf(r1, bf2f(u8[7]) + bf2f(v8[7]), fmaf(-rm1, Gb.w, Bb.w)); gg[7] = gb.w;
      s16x8 pk;
#pragma unroll
      for (int jj = 0; jj < 8; ++jj) {
        float t = tv[jj];
        t = t >= 0.f ? t : 0.01f * t;
        s += t; q += t * t;
        pk[jj] = (short)f2bf(t * gg[jj]);
      }
      *(s16x8*)(ldsA + ((row * 512 + k0 * 2) ^ ((row & 7) << 4))) = pk;
    }
    s += __shfl_xor(s, 1); s += __shfl_xor(s, 2);
    q += __shfl_xor(q, 1); q += __shfl_xor(q, 2);
    if (qq == 0) {
      float m2 = s * (1.f / 256.f);
      float v2 = q * (1.f / 256.f) - m2 * m2;
      lmu2[row] = m2; lrs2[row] = rsqrtf(v2 + kEPS);
    }
  }
  const int wr = w >> 1, wc = w & 1;
  const int sm = tid >> 3, sk8 = (tid & 7) * 8;
  f32x4 acc[2][4];
#pragma unroll
  for (int i = 0; i < 2; ++i)
#pragma unroll
    for (int j = 0; j < 4; ++j) acc[i][j] = f32x4{0.f, 0.f, 0.f, 0.f};
  for (int kt = 0; kt < 4; ++kt) {
    __syncthreads();
#pragma unroll
    for (int i = 0; i < 4; ++i) {
      int n = i * 32 + sm;
      s16x8 bvv = *(const s16x8*)(cw2t + (size_t)n * 256 + kt * 64 + sk8);
      *(s16x8*)(ldsB + ((n * 128 + sk8 * 2) ^ ((n & 7) << 4))) = bvv;
    }
    __syncthreads();
#pragma unroll
    for (int ks = 0; ks < 2; ++ks) {
      const int kbB = ks * 64 + (lane >> 4) * 16;
      const int kbA = kt * 128 + kbB;
      s16x8 av[2], bv[4];
#pragma unroll
      for (int i = 0; i < 2; ++i) {
        int r = wr * 32 + i * 16 + (lane & 15);
        av[i] = *(const s16x8*)(ldsA + ((r * 512 + kbA) ^ ((r & 7) << 4)));
      }
#pragma unroll
      for (int j = 0; j < 4; ++j) {
        int n = wc * 64 + j * 16 + (lane & 15);
        bv[j] = *(const s16x8*)(ldsB + ((n * 128 + kbB) ^ ((n & 7) << 4)));
      }
#pragma unroll
      for (int i = 0; i < 2; ++i)
#pragma unroll
        for (int j = 0; j < 4; ++j)
          acc[i][j] = __builtin_amdgcn_mfma_f32_16x16x32_bf16(av[i], bv[j],
                                                              acc[i][j], 0, 0, 0);
    }
  }
  {
    int g = lane >> 4, lo = lane & 15;
#pragma unroll
    for (int i = 0; i < 2; ++i) {
#pragma unroll
      for (int qv = 0; qv < 4; ++qv) {
        int row = wr * 32 + i * 16 + g * 4 + qv;
        float rs2v = lrs2[row];
        float rm2  = rs2v * lmu2[row];
        float sS = 0.f, sQ = 0.f, sP0 = 0.f, sP1 = 0.f;
#pragma unroll
        for (int j = 0; j < 4; ++j) {
          int col = wc * 64 + j * 16 + lo;
          float t2 = fmaf(rs2v, acc[i][j][qv], fmaf(-rm2, G2[col], B2c[col]));
          t2 = t2 >= 0.f ? t2 : 0.01f * t2;
          sS += t2; sQ += t2 * t2;
          float tg = t2 * g3v[col];
          sP0 = fmaf(tg, cw3[col * 2 + 0], sP0);
          sP1 = fmaf(tg, cw3[col * 2 + 1], sP1);
        }
#pragma unroll
        for (int o = 1; o < 16; o <<= 1) {
          sS += __shfl_xor(sS, o); sQ += __shfl_xor(sQ, o);
          sP0 += __shfl_xor(sP0, o); sP1 += __shfl_xor(sP1, o);
        }
        if (lo == 0) {
          lred[row][wc][0] = sS; lred[row][wc][1] = sQ;
          lred[row][wc][2] = sP0; lred[row][wc][3] = sP1;
        }
      }
    }
  }
  __syncthreads();
  if (tid < 64) {
    float S  = lred[tid][0][0] + lred[tid][1][0];
    float Q  = lred[tid][0][1] + lred[tid][1][1];
    float P0 = lred[tid][0][2] + lred[tid][1][2];
    float P1 = lred[tid][0][3] + lred[tid][1][3];
    float m3 = S * (1.f / 128.f);
    float v3 = Q * (1.f / 128.f) - m3 * m3;
    float r3 = rsqrtf(v3 + kEPS);
    size_t e = (size_t)le[tid];
    out[e * 2 + 0] = fmaf(r3, P0 - m3 * G3[0], B3c[0]);
    out[e * 2 + 1] = fmaf(r3, P1 - m3 * G3[1], B3c[1]);
  }
}

extern "C" void kernel_launch(void* const* d_in, const int* in_sizes, int n_in,
                              void* d_out, int out_size, void* d_ws, size_t ws_size,
                              hipStream_t stream) {
  const float* x      = (const float*)d_in[0];
  const int*   eidx   = (const int*)  d_in[1];
  const float* eattr  = (const float*)d_in[2];
  const float* bn_ng  = (const float*)d_in[3];
  const float* bn_nb  = (const float*)d_in[4];
  const float* bn_eg  = (const float*)d_in[5];
  const float* bn_eb  = (const float*)d_in[6];
  const float* lin_w  = (const float*)d_in[7];
  const float* lin_b  = (const float*)d_in[8];
  const float* w1     = (const float*)d_in[9];
  const float* b1     = (const float*)d_in[10];
  const float* w2     = (const float*)d_in[11];
  const float* b2     = (const float*)d_in[12];
  const float* mlng   = (const float*)d_in[13];
  const float* mlnb   = (const float*)d_in[14];
  const float* w_in   = (const float*)d_in[15];
  const float* conv_w = (const float*)d_in[16];
  const float* conv_b = (const float*)d_in[17];
  const float* w_x    = (const float*)d_in[18];
  const float* w_dt   = (const float*)d_in[19];
  const float* b_dt   = (const float*)d_in[20];
  const float* A_log  = (const float*)d_in[21];
  const float* Dm     = (const float*)d_in[22];
  const float* w_out  = (const float*)d_in[23];
  const float* ln1g   = (const float*)d_in[24];
  const float* ln1b   = (const float*)d_in[25];
  const float* cw1    = (const float*)d_in[26];
  const float* cb1    = (const float*)d_in[27];
  const float* ln2g   = (const float*)d_in[28];
  const float* ln2b   = (const float*)d_in[29];
  const float* cw2    = (const float*)d_in[30];
  const float* cb2    = (const float*)d_in[31];
  const float* ln3g   = (const float*)d_in[32];
  const float* ln3b   = (const float*)d_in[33];
  const float* cw3    = (const float*)d_in[34];
  const float* cb3    = (const float*)d_in[35];
  const int* src = eidx;
  const int* dst = eidx + kE;
  float* out = (float*)d_out;

  // ---- workspace layout ----
  char* ws = (char*)d_ws;
  const size_t MB = 1ull << 20;
  const size_t KB = 1024;
  if (ws_size < 212 * MB) return;
  float* bn_acc = (float*)ws;                       // 512 f32
  float* coef   = (float*)(ws + 4096);              // 512 f32
  float* A2     = (float*)(ws + 8192);              // 4096 f32
  ushort* wt = (ushort*)(ws + 64 * KB);
  ushort* wt_lin  = wt;             // 128x128
  ushort* wt_w1   = wt + 16384;     // 128x128
  ushort* wt_w2   = wt + 32768;     // 128x128
  ushort* wt_win  = wt + 49152;     // 512x128
  ushort* wt_wx   = wt + 114688;    // 128x256 (N=40 padded)
  ushort* wt_wout = wt + 147456;    // 128x256
  ushort* wt_uv   = wt + 180224;    // 512x128
  ushort* wt_cw2  = wt + 245760;    // 128x256
  float* mu   = (float*)(ws + 1 * MB);
  float* rsb  = (float*)(ws + 1 * MB + 256 * KB);
  float* s1b  = (float*)(ws + 1 * MB + 512 * KB);
  float* s2b  = (float*)(ws + 1 * MB + 768 * KB);
  float* vecs = (float*)(ws + 2 * MB);              // 772 f32
  int* cnt    = (int*)(ws + 2 * MB + 128 * KB);     // 32768
  int* base   = (int*)(ws + 2 * MB + 256 * KB);     // 32769
  int* run    = (int*)(ws + 2 * MB + 512 * KB);     // 32768
  int* eorder = (int*)(ws + 3 * MB);                // 262144
  float* h    = (float*)(ws + 4 * MB);              // 16 MB
  char*  S    = ws + 20 * MB;                       // phase-shared region
  // GNN phase
  float*  xn   = (float*)S;                    // 16 MB
  float*  agg  = (float*)(S + 16 * MB);        // 16 MB
  ushort* tmpb = (ushort*)(S + 32 * MB);       // 8 MB (bf16)
  ushort* msg0 = (ushort*)(S + 48 * MB);       // 64 MB (bf16)
  // mamba phase
  ushort* xzb = (ushort*)S;                    // N x 512 bf16 (32 MB)
  ushort* xcb = (ushort*)(S + 32 * MB);        // N x 256 bf16 (16 MB)
  float*  dbl = (float*)(S + 48 * MB);         // N x 40 f32 (5.25 MB)
  ushort* yb  = (ushort*)(S + 56 * MB);        // N x 256 bf16 (16 MB)
  float*  dtb = (float*)(S + 72 * MB);         // N x 256 f32 (32 MB)
  // classifier phase
  ushort* UV = (ushort*)S;                     // N x 512 bf16 (32 MB)

  // ---- weight prep ----
  prep_wt<<<64,  256, 0, stream>>>(lin_w, 128, 128, wt_lin);
  prep_wt<<<64,  256, 0, stream>>>(w1,    128, 128, wt_w1);
  prep_wt<<<64,  256, 0, stream>>>(w2,    128, 128, wt_w2);
  prep_wt<<<256, 256, 0, stream>>>(w_in,  128, 512, wt_win);
  prep_wt<<<128, 256, 0, stream>>>(w_x,   256, 40,  wt_wx);
  prep_wt<<<128, 256, 0, stream>>>(w_out, 256, 128, wt_wout);
  prep_wt<<<128, 256, 0, stream>>>(cw2,   256, 128, wt_cw2);
  prep_uv<<<256, 256, 0, stream>>>(cw1, ln1g, wt_uv);
  prep_vecs<<<1, 256, 0, stream>>>(cw1, ln1b, cb1, cw2, ln2g, ln2b, cb2,
                                   cw3, ln3g, ln3b, cb3, ln1g, vecs);

  // ---- edge sort by dst (counting sort) ----
  hipMemsetAsync(cnt, 0, 32768 * 4, stream);
  hist_kernel<<<kE / 256, 256, 0, stream>>>(dst, cnt);
  scan32k<<<1, 1024, 0, stream>>>(cnt, base, run);
  scatter_ids<<<kE / 256, 256, 0, stream>>>(dst, run, eorder);

  // ---- GNN ----
  hipMemsetAsync(bn_acc, 0, 512 * 4, stream);
  bn_partial2<<<256, 256, 0, stream>>>(x, kN, bn_acc, bn_acc + 128);
  bn_partial2<<<512, 256, 0, stream>>>(eattr, kE, bn_acc + 256, bn_acc + 384);
  bn_finalize<<<1, 256, 0, stream>>>(bn_acc, bn_ng, bn_nb, bn_eg, bn_eb, coef);
  a2prep<<<16, 256, 0, stream>>>(A_log, A2);
  bn_apply<<<kN * kH / 1024, 256, 0, stream>>>(x, coef, xn);

  // msg0 = BN(ea)@lin_w  (pure streaming GEMM, bf16 out, no gather)
  gemm_mfma<0><<<dim3(kE / 128, 1), 256, 0, stream>>>(
      ALBN{eattr, coef + 256}, wt_lin, 128, 128, EPStoreBf{msg0, 128},
      nullptr, nullptr);
  // agg[dst] = sum relu(msg0 + lin_b + xn[src]) over sorted edge lists
  agg_fused<<<kN / 2, 256, 0, stream>>>(msg0, xn, eorder, base, src, lin_b, agg);

  // h = relu(leaky((xn+agg)@w1 + b1)@w2 + b2); w2 epilogue emits LN stats
  gemm_mfma<0><<<dim3(kN / 128, 1), 256, 0, stream>>>(
      ALAdd2{xn, agg}, wt_w1, 128, 128, EPBiasLeakyBf{tmpb, 128, b1},
      nullptr, nullptr);
  gemm_mfma<1><<<dim3(kN / 128, 1), 256, 0, stream>>>(
      ALBf{tmpb, 128}, wt_w2, 128, 128, EPBiasRelu{h, 128, b2}, mu, rsb);

  // ---- mamba x2 (stats produced by previous epilogue) ----
  for (int pass = 0; pass < 2; ++pass) {
    gemm_mfma<0><<<dim3(kN / 128, 4), 256, 0, stream>>>(
        ALLN{h, 128, mu, rsb, mlng, mlnb}, wt_win, 128, 512,
        EPStoreBf{xzb, 512}, nullptr, nullptr);
    conv_silu<<<kN, 256, 0, stream>>>(xzb, conv_w, conv_b, xcb);
    gemm_mfma<0><<<dim3(kN / 128, 1), 256, 0, stream>>>(
        ALBf{xcb, 256}, wt_wx, 256, 40, EPStore{dbl, 40}, nullptr, nullptr);
    dt_kernel<<<kN / 8, 256, 0, stream>>>(dbl, w_dt, b_dt, dtb);
    scan_kernel<<<512, 256, 0, stream>>>(dtb, xcb, dbl, A2, yb);
    if (pass == 0) {
      // epilogue emits LN stats of updated h for pass 1
      gemm_mfma<1><<<dim3(kN / 128, 1), 256, 0, stream>>>(
          ALMambaY{yb, xcb, xzb, Dm}, wt_wout, 256, 128, EPResidH{h}, mu, rsb);
    } else {
      // epilogue emits raw sum/sumsq of final h for the edge classifier
      gemm_mfma<2><<<dim3(kN / 128, 1), 256, 0, stream>>>(
          ALMambaY{yb, xcb, xzb, Dm}, wt_wout, 256, 128, EPResidH{h}, s1b, s2b);
    }
  }

  // ---- fused edge classifier (bf16 UV, dst-sorted order, scatter out) ----
  gemm_mfma<0><<<dim3(kN / 128, 4), 256, 0, stream>>>(
      ALPlainF{h, 128}, wt_uv, 128, 512, EPStoreBf{UV, 512}, nullptr, nullptr);
  cls_fused<<<kE / 64, 256, 0, stream>>>(UV, src, dst, eorder, s1b, s2b, vecs,
                                         ln2g, wt_cw2, ln3g, cw3, out);
}

// Round 17
// 1081.416 us; speedup vs baseline: 1.0320x; 1.0012x over previous
//
#include <hip/hip_runtime.h>

#define DEV __device__ __forceinline__

constexpr int   kH  = 128;
constexpr int   kN  = 32768;    // B*NP rows
constexpr int   kE  = 262144;   // edges
constexpr float kEPS = 1e-5f;
constexpr float kLOG2E = 1.4426950408889634f;

typedef short  s16x8 __attribute__((ext_vector_type(8)));
typedef ushort u16x8 __attribute__((ext_vector_type(8)));
typedef ushort u16x4 __attribute__((ext_vector_type(4)));
typedef float  f32x4 __attribute__((ext_vector_type(4)));

DEV float sigmoidf_(float v) { return 1.f / (1.f + __expf(-v)); }

DEV ushort f2bf(float f) {  // RTNE f32 -> bf16
  union { float f; unsigned u; } x{f};
  unsigned r = x.u + 0x7fff + ((x.u >> 16) & 1);
  return (ushort)(r >> 16);
}
DEV float bf2f(ushort u) {
  union { unsigned u; float f; } x{(unsigned)u << 16};
  return x.f;
}
DEV float4 L4(const float* p) { return *(const float4*)p; }
DEV s16x8 pk8(const float* v) {
  s16x8 r;
#pragma unroll
  for (int j = 0; j < 8; ++j) r[j] = (short)f2bf(v[j]);
  return r;
}

// ---------------- batchnorm column stats, vectorized ----------------
__global__ __launch_bounds__(256) void bn_partial2(const float* __restrict__ X, int R,
                                                   float* __restrict__ sum,
                                                   float* __restrict__ sq) {
  int t = threadIdx.x;
  int cg = (t & 31) * 4, rs = t >> 5;
  float sx = 0.f, sy = 0.f, sz = 0.f, sw = 0.f;
  float qx = 0.f, qy = 0.f, qz = 0.f, qw = 0.f;
  for (int r = blockIdx.x * 8 + rs; r < R; r += gridDim.x * 8) {
    float4 v = L4(X + (size_t)r * 128 + cg);
    sx += v.x; sy += v.y; sz += v.z; sw += v.w;
    qx = fmaf(v.x, v.x, qx); qy = fmaf(v.y, v.y, qy);
    qz = fmaf(v.z, v.z, qz); qw = fmaf(v.w, v.w, qw);
  }
  __shared__ float red[8][256];
  red[rs][(t & 31) * 8 + 0] = sx; red[rs][(t & 31) * 8 + 1] = sy;
  red[rs][(t & 31) * 8 + 2] = sz; red[rs][(t & 31) * 8 + 3] = sw;
  red[rs][(t & 31) * 8 + 4] = qx; red[rs][(t & 31) * 8 + 5] = qy;
  red[rs][(t & 31) * 8 + 6] = qz; red[rs][(t & 31) * 8 + 7] = qw;
  __syncthreads();
  if (rs == 0) {
    int cq = t & 31;
#pragma unroll
    for (int jj = 0; jj < 4; ++jj) {
      float S = 0.f, Q = 0.f;
#pragma unroll
      for (int i = 0; i < 8; ++i) {
        S += red[i][cq * 8 + jj];
        Q += red[i][cq * 8 + 4 + jj];
      }
      atomicAdd(&sum[cq * 4 + jj], S);
      atomicAdd(&sq[cq * 4 + jj], Q);
    }
  }
}

__global__ void bn_finalize(const float* __restrict__ acc,
                            const float* __restrict__ gx, const float* __restrict__ bx,
                            const float* __restrict__ ge, const float* __restrict__ be,
                            float* __restrict__ coef) {
  int t = threadIdx.x;
  if (t < 128) {
    float m  = acc[t]       * (1.f / 32768.f);
    float v  = acc[128 + t] * (1.f / 32768.f) - m * m;
    float sc = gx[t] * rsqrtf(v + kEPS);
    coef[t] = sc; coef[128 + t] = bx[t] - m * sc;
  } else {
    int c = t - 128;
    float m  = acc[256 + c] * (1.f / 262144.f);
    float v  = acc[384 + c] * (1.f / 262144.f) - m * m;
    float sc = ge[c] * rsqrtf(v + kEPS);
    coef[256 + c] = sc; coef[384 + c] = be[c] - m * sc;
  }
}

__global__ void bn_apply(const float* __restrict__ x, const float* __restrict__ coef,
                         float* __restrict__ xn) {
  size_t i = ((size_t)blockIdx.x * 256 + threadIdx.x) * 4;
  int c = (int)(i & 127);
  float4 v = L4(x + i);
  float4 s = L4(coef + c), h = L4(coef + 128 + c);
  float4 o;
  o.x = fmaf(v.x, s.x, h.x); o.y = fmaf(v.y, s.y, h.y);
  o.z = fmaf(v.z, s.z, h.z); o.w = fmaf(v.w, s.w, h.w);
  *(float4*)(xn + i) = o;
}

__global__ void a2prep(const float* __restrict__ A_log, float* __restrict__ A2) {
  int i = blockIdx.x * 256 + threadIdx.x;
  A2[i] = -__expf(A_log[i]) * kLOG2E;
}

// convert weight W[K][N] f32 -> Wt[Npad][K] bf16 (transposed, zero-padded cols)
__global__ void prep_wt(const float* __restrict__ W, int Kdim, int Ncols,
                        ushort* __restrict__ Wt) {
  int idx = blockIdx.x * 256 + threadIdx.x;
  int n = idx / Kdim, k = idx - n * Kdim;
  float v = (n < Ncols) ? W[(size_t)k * Ncols + n] : 0.f;
  Wt[idx] = f2bf(v);
}

__global__ void prep_uv(const float* __restrict__ cw1, const float* __restrict__ g1,
                        ushort* __restrict__ Wt) {
  int idx = blockIdx.x * 256 + threadIdx.x;  // 512*128
  int n = idx >> 7, k = idx & 127;
  int krow = (n < 256) ? k : 128 + k;
  int ncol = n & 255;
  Wt[idx] = f2bf(g1[krow] * cw1[(size_t)krow * 256 + ncol]);
}

// vecs layout: G1[256] B1c[256] G2[128] B2c[128] G3[2] B3c[2]
__global__ void prep_vecs(const float* __restrict__ cw1, const float* __restrict__ b1v,
                          const float* __restrict__ cb1,
                          const float* __restrict__ cw2, const float* __restrict__ g2v,
                          const float* __restrict__ b2v, const float* __restrict__ cb2,
                          const float* __restrict__ cw3, const float* __restrict__ g3v,
                          const float* __restrict__ b3v, const float* __restrict__ cb3,
                          const float* __restrict__ g1v, float* __restrict__ vecs) {
  int t = threadIdx.x;
  {
    float gs = 0.f, bs = 0.f;
    for (int k = 0; k < 256; ++k) {
      float w = cw1[(size_t)k * 256 + t];
      gs = fmaf(g1v[k], w, gs);
      bs = fmaf(b1v[k], w, bs);
    }
    vecs[t] = gs; vecs[256 + t] = bs + cb1[t];
  }
  if (t < 128) {
    float gs = 0.f, bs = 0.f;
    for (int k = 0; k < 256; ++k) {
      float w = cw2[(size_t)k * 128 + t];
      gs = fmaf(g2v[k], w, gs);
      bs = fmaf(b2v[k], w, bs);
    }
    vecs[512 + t] = gs; vecs[640 + t] = bs + cb2[t];
  }
  if (t < 2) {
    float gs = 0.f, bs = 0.f;
    for (int c = 0; c < 128; ++c) {
      float w = cw3[c * 2 + t];
      gs = fmaf(g3v[c], w, gs);
      bs = fmaf(b3v[c], w, bs);
    }
    vecs[768 + t] = gs; vecs[770 + t] = bs + cb3[t];
  }
}

// ---------------- edge sort (counting sort by dst) ----------------
__global__ void hist_kernel(const int* __restrict__ dst, int* __restrict__ cnt) {
  int e = blockIdx.x * 256 + threadIdx.x;
  atomicAdd(&cnt[dst[e]], 1);
}

__global__ __launch_bounds__(1024) void scan32k(const int* __restrict__ cnt,
                                                int* __restrict__ base,
                                                int* __restrict__ run) {
  __shared__ int part[1024];
  int t = threadIdx.x;
  int loc[32]; int s = 0;
  const int* p = cnt + t * 32;
#pragma unroll
  for (int i = 0; i < 32; ++i) { loc[i] = s; s += p[i]; }
  part[t] = s;
  __syncthreads();
  for (int o = 1; o < 1024; o <<= 1) {
    int v = (t >= o) ? part[t - o] : 0;
    __syncthreads();
    part[t] += v;
    __syncthreads();
  }
  int ex = part[t] - s;
#pragma unroll
  for (int i = 0; i < 32; ++i) {
    int b = ex + loc[i];
    base[t * 32 + i] = b; run[t * 32 + i] = b;
  }
  if (t == 1023) base[32768] = part[1023];
}

__global__ void scatter_ids(const int* __restrict__ dst, int* __restrict__ run,
                            int* __restrict__ eorder) {
  int e = blockIdx.x * 256 + threadIdx.x;
  int p = atomicAdd(&run[dst[e]], 1);
  eorder[p] = e;
}

// agg[v] = sum over sorted in-edges: relu(msg0[e] + lin_b + xn[src[e]])
__global__ __launch_bounds__(256) void agg_fused(
    const ushort* __restrict__ msg0, const float* __restrict__ xn,
    const int* __restrict__ eorder, const int* __restrict__ base,
    const int* __restrict__ src, const float* __restrict__ lin_b,
    float* __restrict__ agg) {
  int node = blockIdx.x * 2 + (threadIdx.x >> 7);
  int c = threadIdx.x & 127;
  int b0 = base[node], b1 = base[node + 1];
  float bias = lin_b[c];
  float s = 0.f;
  for (int j = b0; j < b1; ++j) {
    int e = eorder[j];
    float m = bf2f(msg0[(size_t)e * 128 + c]) + bias + xn[(size_t)src[e] * 128 + c];
    s += fmaxf(m, 0.f);
  }
  agg[(size_t)node * 128 + c] = s;
}

// ---------------- A-load functors: ld8 returns bf16x8 ---------------------
struct ALPlainF {  // f32 source
  const float* A; int lda;
  DEV s16x8 ld8(int r, int k) const {
    float b[8];
    const float* p = A + (size_t)r * lda + k;
    *(float4*)b = L4(p); *(float4*)(b + 4) = L4(p + 4);
    return pk8(b);
  }
};
struct ALBf {  // already-bf16 source, pure copy
  const ushort* A; int lda;
  DEV s16x8 ld8(int r, int k) const {
    return *(const s16x8*)(A + (size_t)r * lda + k);
  }
};
struct ALBN {
  const float* A; const float* coef;
  DEV s16x8 ld8(int r, int k) const {
    const float* p = A + (size_t)r * 128 + k;
    float4 a0 = L4(p), a1 = L4(p + 4);
    float4 s0 = L4(coef + k), s1 = L4(coef + k + 4);
    float4 h0 = L4(coef + 128 + k), h1 = L4(coef + 132 + k);
    float b[8];
    b[0] = fmaf(a0.x, s0.x, h0.x); b[1] = fmaf(a0.y, s0.y, h0.y);
    b[2] = fmaf(a0.z, s0.z, h0.z); b[3] = fmaf(a0.w, s0.w, h0.w);
    b[4] = fmaf(a1.x, s1.x, h1.x); b[5] = fmaf(a1.y, s1.y, h1.y);
    b[6] = fmaf(a1.z, s1.z, h1.z); b[7] = fmaf(a1.w, s1.w, h1.w);
    return pk8(b);
  }
};
struct ALAdd2 {
  const float* X; const float* Y;
  DEV s16x8 ld8(int r, int k) const {
    const float* p = X + (size_t)r * 128 + k;
    const float* q = Y + (size_t)r * 128 + k;
    float4 a0 = L4(p), a1 = L4(p + 4), b0 = L4(q), b1 = L4(q + 4);
    float b[8];
    b[0] = a0.x + b0.x; b[1] = a0.y + b0.y; b[2] = a0.z + b0.z; b[3] = a0.w + b0.w;
    b[4] = a1.x + b1.x; b[5] = a1.y + b1.y; b[6] = a1.z + b1.z; b[7] = a1.w + b1.w;
    return pk8(b);
  }
};
struct ALLN {
  const float* A; int lda; const float* mu; const float* rs;
  const float* g; const float* b;
  DEV s16x8 ld8(int r, int k) const {
    float m = mu[r], s = rs[r];
    const float* p = A + (size_t)r * lda + k;
    float4 a0 = L4(p), a1 = L4(p + 4);
    float4 g0 = L4(g + k), g1 = L4(g + k + 4), b0 = L4(b + k), b1 = L4(b + k + 4);
    float o[8];
    o[0] = fmaf((a0.x - m) * s, g0.x, b0.x); o[1] = fmaf((a0.y - m) * s, g0.y, b0.y);
    o[2] = fmaf((a0.z - m) * s, g0.z, b0.z); o[3] = fmaf((a0.w - m) * s, g0.w, b0.w);
    o[4] = fmaf((a1.x - m) * s, g1.x, b1.x); o[5] = fmaf((a1.y - m) * s, g1.y, b1.y);
    o[6] = fmaf((a1.z - m) * s, g1.z, b1.z); o[7] = fmaf((a1.w - m) * s, g1.w, b1.w);
    return pk8(o);
  }
};
struct ALMambaY {  // (scan_y + Dm*xc) * silu(z), all bf16 inputs
  const ushort* y; const ushort* xc; const ushort* xz; const float* Dm;
  DEV s16x8 ld8(int r, int k) const {
    u16x8 yv = *(const u16x8*)(y + (size_t)r * 256 + k);
    u16x8 cv = *(const u16x8*)(xc + (size_t)r * 256 + k);
    u16x8 zv = *(const u16x8*)(xz + (size_t)r * 512 + 256 + k);
    s16x8 o;
#pragma unroll
    for (int j = 0; j < 8; ++j) {
      float zf = bf2f(zv[j]);
      float val = fmaf(Dm[k + j], bf2f(cv[j]), bf2f(yv[j])) * (zf * sigmoidf_(zf));
      o[j] = (short)f2bf(val);
    }
    return o;
  }
};

// epilogues return the stored (post-activation) value for optional stats
struct EPStore {
  float* C; int ldc;
  DEV float operator()(int r, int c, float v) const {
    C[(size_t)r * ldc + c] = v; return v;
  }
};
struct EPStoreBf {
  ushort* C; int ldc;
  DEV float operator()(int r, int c, float v) const {
    C[(size_t)r * ldc + c] = f2bf(v); return v;
  }
};
struct EPBiasLeakyBf {
  ushort* C; int ldc; const float* bias;
  DEV float operator()(int r, int c, float v) const {
    v += bias[c];
    v = v >= 0.f ? v : 0.01f * v;
    C[(size_t)r * ldc + c] = f2bf(v);
    return v;
  }
};
struct EPBiasRelu {
  float* C; int ldc; const float* bias;
  DEV float operator()(int r, int c, float v) const {
    v = fmaxf(v + bias[c], 0.f);
    C[(size_t)r * ldc + c] = v;
    return v;
  }
};
struct EPResidH {
  float* h;
  DEV float operator()(int r, int c, float v) const {
    size_t i = (size_t)r * 128 + c;
    float nv = h[i] + v;
    h[i] = nv;
    return nv;
  }
};

// ------------- bf16 MFMA GEMM: 128x128 tile, BK=64, 256 thr (4 waves 2x2) ---
// STATS: 0=none, 1=write mu/rs of stored rows (Ncols must be 128),
//        2=write raw sum/sumsq (s1/s2). Stats computed on epilogue outputs.
template <int STATS, class AL, class EP>
__global__ __launch_bounds__(256) void gemm_mfma(AL aload, const ushort* __restrict__ Wt,
                                                 int Kdim, int Ncols, EP epi,
                                                 float* __restrict__ st1,
                                                 float* __restrict__ st2) {
  __shared__ __align__(16) char lds[32768];
  const int tid = threadIdx.x;
  const int lane = tid & 63;
  const int w = tid >> 6;
  const int wr = w >> 1, wc = w & 1;
  const int row0 = blockIdx.x * 128, col0 = blockIdx.y * 128;
  const int sm = tid >> 3;
  const int sk = (tid & 7) * 8;
  f32x4 acc[4][4];
#pragma unroll
  for (int i = 0; i < 4; ++i)
#pragma unroll
    for (int j = 0; j < 4; ++j) acc[i][j] = f32x4{0.f, 0.f, 0.f, 0.f};

  for (int kt = 0; kt < Kdim; kt += 64) {
#pragma unroll
    for (int i = 0; i < 4; ++i) {
      int n = i * 32 + sm;
      s16x8 v = *(const s16x8*)(Wt + (size_t)(col0 + n) * Kdim + kt + sk);
      *(s16x8*)(lds + 16384 + ((n * 128 + sk * 2) ^ ((n & 7) << 4))) = v;
    }
#pragma unroll
    for (int i = 0; i < 4; ++i) {
      int m = i * 32 + sm;
      s16x8 v = aload.ld8(row0 + m, kt + sk);
      *(s16x8*)(lds + ((m * 128 + sk * 2) ^ ((m & 7) << 4))) = v;
    }
    __syncthreads();
#pragma unroll
    for (int ks = 0; ks < 2; ++ks) {
      const int kb = ks * 64 + (lane >> 4) * 16;
      s16x8 av[4], bv[4];
#pragma unroll
      for (int i = 0; i < 4; ++i) {
        int r = wr * 64 + i * 16 + (lane & 15);
        av[i] = *(const s16x8*)(lds + ((r * 128 + kb) ^ ((r & 7) << 4)));
      }
#pragma unroll
      for (int j = 0; j < 4; ++j) {
        int n = wc * 64 + j * 16 + (lane & 15);
        bv[j] = *(const s16x8*)(lds + 16384 + ((n * 128 + kb) ^ ((n & 7) << 4)));
      }
#pragma unroll
      for (int i = 0; i < 4; ++i)
#pragma unroll
        for (int j = 0; j < 4; ++j)
          acc[i][j] = __builtin_amdgcn_mfma_f32_16x16x32_bf16(av[i], bv[j],
                                                              acc[i][j], 0, 0, 0);
    }
    __syncthreads();
  }
  if constexpr (STATS == 0) {
#pragma unroll
    for (int i = 0; i < 4; ++i)
#pragma unroll
      for (int q = 0; q < 4; ++q) {
        int r = row0 + wr * 64 + i * 16 + (lane >> 4) * 4 + q;
#pragma unroll
        for (int j = 0; j < 4; ++j) {
          int c = col0 + wc * 64 + j * 16 + (lane & 15);
          if (c < Ncols) epi(r, c, acc[i][j][q]);
        }
      }
  } else {
    __shared__ float sred[128][2][2];
#pragma unroll
    for (int i = 0; i < 4; ++i)
#pragma unroll
      for (int q = 0; q < 4; ++q) {
        int rloc = wr * 64 + i * 16 + (lane >> 4) * 4 + q;
        int r = row0 + rloc;
        float sS = 0.f, sQ = 0.f;
#pragma unroll
        for (int j = 0; j < 4; ++j) {
          int c = wc * 64 + j * 16 + (lane & 15);
          float v = epi(r, c, acc[i][j][q]);
          sS += v; sQ = fmaf(v, v, sQ);
        }
#pragma unroll
        for (int o = 1; o < 16; o <<= 1) {
          sS += __shfl_xor(sS, o); sQ += __shfl_xor(sQ, o);
        }
        if ((lane & 15) == 0) { sred[rloc][wc][0] = sS; sred[rloc][wc][1] = sQ; }
      }
    __syncthreads();
    if (tid < 128) {
      float S = sred[tid][0][0] + sred[tid][1][0];
      float Q = sred[tid][0][1] + sred[tid][1][1];
      if (STATS == 1) {
        float m = S * (1.f / 128.f);
        float v = Q * (1.f / 128.f) - m * m;
        st1[row0 + tid] = m;
        st2[row0 + tid] = rsqrtf(v + kEPS);
      } else {
        st1[row0 + tid] = S;
        st2[row0 + tid] = Q;
      }
    }
  }
}

// ---------------- mamba pieces ----------------
__global__ void conv_silu(const ushort* __restrict__ xz, const float* __restrict__ cw,
                          const float* __restrict__ cb, ushort* __restrict__ xc) {
  int r = blockIdx.x;       // b*512 + t
  int d = threadIdx.x;      // 256
  int t = r & 511;
  float acc = cb[d];
#pragma unroll
  for (int k = 0; k < 4; ++k) {
    int tt = t - 3 + k;
    if (tt >= 0) acc = fmaf(cw[d * 4 + k], bf2f(xz[(size_t)(r - 3 + k) * 512 + d]), acc);
  }
  float v = acc * sigmoidf_(acc);
  xc[(size_t)r * 256 + d] = f2bf(v);
}

// scan v7: v3 structure (TC=32, 8d x 8ng, 512 blocks) with dt computed in the
// staging phase (once per (t,d), w_dt slice in regs) — dtb buffer eliminated.
__global__ __launch_bounds__(256) void scan_kernel(
    const ushort* __restrict__ xcb, const float* __restrict__ dbl,
    const float* __restrict__ A2, const float* __restrict__ w_dt,
    const float* __restrict__ b_dt, ushort* __restrict__ y) {
  constexpr int TC = 32;
  constexpr int NC = 512 / TC;
  __shared__ float  s_dt[2][TC * 32];
  __shared__ ushort s_xc[2][TC * 32];
  __shared__ float  s_bc[2][TC * 32];  // [j<16]=B[j], [16+j]=C[j]
  int b    = blockIdx.x >> 3;
  int dblk = blockIdx.x & 7;
  int d0   = dblk * 32;
  int tid  = threadIdx.x;
  int w = tid >> 6, lane = tid & 63;
  int ng = lane >> 3, dl = lane & 7;
  int dd = w * 8 + dl;
  int d  = d0 + dd;
  int n0 = ng * 2;
  float a0 = A2[d * 16 + n0], a1 = A2[d * 16 + n0 + 1];
  float h0 = 0.f, h1 = 0.f;
  const ushort* pxc = xcb + (size_t)b * 512 * 256 + d0;
  const float*  pbl = dbl + (size_t)b * 512 * 40;
  ushort* py = y + (size_t)b * 512 * 256 + d;
  const int stt = tid >> 3;         // staging t-row 0..31
  const int sq  = (tid & 7) * 4;    // staging d-quad 0..28

  // per-thread w_dt slice for d = d0+sq..+3 (32 regs) + bias
  float4 wdv[8];
#pragma unroll
  for (int j = 0; j < 8; ++j) wdv[j] = L4(w_dt + j * 256 + d0 + sq);
  float4 bdv = L4(b_dt + d0 + sq);

  // dt = softplus(dbl[t][0:8] @ w_dt + b_dt) for this thread's 4 d-columns
  auto compute_dt = [&](float4 da, float4 db) -> float4 {
    float a[4] = {bdv.x, bdv.y, bdv.z, bdv.w};
    float in[8] = {da.x, da.y, da.z, da.w, db.x, db.y, db.z, db.w};
#pragma unroll
    for (int j = 0; j < 8; ++j) {
      a[0] = fmaf(in[j], wdv[j].x, a[0]);
      a[1] = fmaf(in[j], wdv[j].y, a[1]);
      a[2] = fmaf(in[j], wdv[j].z, a[2]);
      a[3] = fmaf(in[j], wdv[j].w, a[3]);
    }
    float4 r;
    r.x = fmaxf(a[0], 0.f) + log1pf(__expf(-fabsf(a[0])));
    r.y = fmaxf(a[1], 0.f) + log1pf(__expf(-fabsf(a[1])));
    r.z = fmaxf(a[2], 0.f) + log1pf(__expf(-fabsf(a[2])));
    r.w = fmaxf(a[3], 0.f) + log1pf(__expf(-fabsf(a[3])));
    return r;
  };

  {  // prologue: stage chunk 0
    float4 da = L4(pbl + (size_t)stt * 40);
    float4 db = L4(pbl + (size_t)stt * 40 + 4);
    float4 r2 = L4(pbl + (size_t)stt * 40 + 8 + sq);
    u16x4  r1 = *(const u16x4*)(pxc + (size_t)stt * 256 + sq);
    float4 dtv = compute_dt(da, db);
    *(float4*)&s_dt[0][stt * 32 + sq] = dtv;
    *(u16x4*)&s_xc[0][stt * 32 + sq] = r1;
    *(float4*)&s_bc[0][stt * 32 + sq] = r2;
  }
  __syncthreads();

  for (int c = 0; c < NC; ++c) {
    const int buf = c & 1;
    float4 da, db, r2; u16x4 r1;
    const bool more = (c + 1 < NC);
    if (more) {  // issue next chunk's loads early (hide under compute)
      size_t t1 = (size_t)(c + 1) * TC + stt;
      da = L4(pbl + t1 * 40);
      db = L4(pbl + t1 * 40 + 4);
      r2 = L4(pbl + t1 * 40 + 8 + sq);
      r1 = *(const u16x4*)(pxc + t1 * 256 + sq);
    }
#pragma unroll
    for (int tt = 0; tt < TC; ++tt) {
      float dt = s_dt[buf][tt * 32 + dd];
      float xc = bf2f(s_xc[buf][tt * 32 + dd]);
      float2 B2 = *(const float2*)&s_bc[buf][tt * 32 + n0];
      float2 C2 = *(const float2*)&s_bc[buf][tt * 32 + 16 + n0];
      float u = dt * xc;
      h0 = fmaf(exp2f(dt * a0), h0, u * B2.x);
      h1 = fmaf(exp2f(dt * a1), h1, u * B2.y);
      float p = fmaf(h1, C2.y, h0 * C2.x);
      p += __shfl_xor(p, 8);
      p += __shfl_xor(p, 16);
      p += __shfl_xor(p, 32);
      if (ng == 0) py[(size_t)(c * TC + tt) * 256] = f2bf(p);
    }
    if (more) {  // write-late: compute dt from loaded dbl, store to other buf
      float4 dtv = compute_dt(da, db);
      *(float4*)&s_dt[buf ^ 1][stt * 32 + sq] = dtv;
      *(u16x4*)&s_xc[buf ^ 1][stt * 32 + sq] = r1;
      *(float4*)&s_bc[buf ^ 1][stt * 32 + sq] = r2;
    }
    __syncthreads();
  }
}

// ------------- fused edge classifier; UV bf16, dst-sorted edge order --------
__global__ __launch_bounds__(256) void cls_fused(
    const ushort* __restrict__ UV, const int* __restrict__ src,
    const int* __restrict__ dst, const int* __restrict__ eorder,
    const float* __restrict__ s1, const float* __restrict__ s2,
    const float* __restrict__ vecs, const float* __restrict__ g2v,
    const ushort* __restrict__ cw2t, const float* __restrict__ g3v,
    const float* __restrict__ cw3, float* __restrict__ out) {
  __shared__ __align__(16) char ldsA[32768];
  __shared__ __align__(16) char ldsB[16384];
  __shared__ float lmu1[64], lrs1[64], lmu2[64], lrs2[64];
  __shared__ int   lsrc[64], ldst[64], le[64];
  __shared__ float lred[64][2][4];
  const float* G1  = vecs;
  const float* B1c = vecs + 256;
  const float* G2  = vecs + 512;
  const float* B2c = vecs + 640;
  const float* G3  = vecs + 768;
  const float* B3c = vecs + 770;
  int tid = threadIdx.x, lane = tid & 63, w = tid >> 6;
  int e0 = blockIdx.x * 64;
  if (tid < 64) {
    int e = eorder[e0 + tid];
    le[tid] = e;
    int sN = src[e], dN = dst[e];
    lsrc[tid] = sN; ldst[tid] = dN;
    float sum = s1[sN] + s1[dN];
    float sq  = s2[sN] + s2[dN];
    float m = sum * (1.f / 256.f);
    float v = sq * (1.f / 256.f) - m * m;
    lmu1[tid] = m; lrs1[tid] = rsqrtf(v + kEPS);
  }
  __syncthreads();
  {
    int row = tid >> 2, qq = tid & 3;
    const ushort* pu = UV + (size_t)lsrc[row] * 512;
    const ushort* pv = UV + (size_t)ldst[row] * 512 + 256;
    float r1 = lrs1[row];
    float rm1 = r1 * lmu1[row];
    float s = 0.f, q = 0.f;
#pragma unroll
    for (int it = 0; it < 8; ++it) {
      int k0 = qq * 8 + it * 32;
      u16x8 u8 = *(const u16x8*)(pu + k0);
      u16x8 v8 = *(const u16x8*)(pv + k0);
      float4 Ga = L4(G1 + k0), Gb = L4(G1 + k0 + 4);
      float4 Ba = L4(B1c + k0), Bb = L4(B1c + k0 + 4);
      float4 ga = L4(g2v + k0), gb = L4(g2v + k0 + 4);
      float tv[8], gg[8];
      tv[0] = fmaf(r1, bf2f(u8[0]) + bf2f(v8[0]), fmaf(-rm1, Ga.x, Ba.x)); gg[0] = ga.x;
      tv[1] = fmaf(r1, bf2f(u8[1]) + bf2f(v8[1]), fmaf(-rm1, Ga.y, Ba.y)); gg[1] = ga.y;
      tv[2] = fmaf(r1, bf2f(u8[2]) + bf2f(v8[2]), fmaf(-rm1, Ga.z, Ba.z)); gg[2] = ga.z;
      tv[3] = fmaf(r1, bf2f(u8[3]) + bf2f(v8[3]), fmaf(-rm1, Ga.w, Ba.w)); gg[3] = ga.w;
      tv[4] = fmaf(r1, bf2f(u8[4]) + bf2f(v8[4]), fmaf(-rm1, Gb.x, Bb.x)); gg[4] = gb.x;
      tv[5] = fmaf(r1, bf2f(u8[5]) + bf2f(v8[5]), fmaf(-rm1, Gb.y, Bb.y)); gg[5] = gb.y;
      tv[6] = fmaf(r1, bf2f(u8[6]) + bf2f(v8[6]), fmaf(-rm1, Gb.z, Bb.z)); gg[6] = gb.z;
      tv[7] = fmaf(r1, bf2f(u8[7]) + bf2f(v8[7]), fmaf(-rm1, Gb.w, Bb.w)); gg[7] = gb.w;
      s16x8 pk;
#pragma unroll
      for (int jj = 0; jj < 8; ++jj) {
        float t = tv[jj];
        t = t >= 0.f ? t : 0.01f * t;
        s += t; q += t * t;
        pk[jj] = (short)f2bf(t * gg[jj]);
      }
      *(s16x8*)(ldsA + ((row * 512 + k0 * 2) ^ ((row & 7) << 4))) = pk;
    }
    s += __shfl_xor(s, 1); s += __shfl_xor(s, 2);
    q += __shfl_xor(q, 1); q += __shfl_xor(q, 2);
    if (qq == 0) {
      float m2 = s * (1.f / 256.f);
      float v2 = q * (1.f / 256.f) - m2 * m2;
      lmu2[row] = m2; lrs2[row] = rsqrtf(v2 + kEPS);
    }
  }
  const int wr = w >> 1, wc = w & 1;
  const int sm = tid >> 3, sk8 = (tid & 7) * 8;
  f32x4 acc[2][4];
#pragma unroll
  for (int i = 0; i < 2; ++i)
#pragma unroll
    for (int j = 0; j < 4; ++j) acc[i][j] = f32x4{0.f, 0.f, 0.f, 0.f};
  for (int kt = 0; kt < 4; ++kt) {
    __syncthreads();
#pragma unroll
    for (int i = 0; i < 4; ++i) {
      int n = i * 32 + sm;
      s16x8 bvv = *(const s16x8*)(cw2t + (size_t)n * 256 + kt * 64 + sk8);
      *(s16x8*)(ldsB + ((n * 128 + sk8 * 2) ^ ((n & 7) << 4))) = bvv;
    }
    __syncthreads();
#pragma unroll
    for (int ks = 0; ks < 2; ++ks) {
      const int kbB = ks * 64 + (lane >> 4) * 16;
      const int kbA = kt * 128 + kbB;
      s16x8 av[2], bv[4];
#pragma unroll
      for (int i = 0; i < 2; ++i) {
        int r = wr * 32 + i * 16 + (lane & 15);
        av[i] = *(const s16x8*)(ldsA + ((r * 512 + kbA) ^ ((r & 7) << 4)));
      }
#pragma unroll
      for (int j = 0; j < 4; ++j) {
        int n = wc * 64 + j * 16 + (lane & 15);
        bv[j] = *(const s16x8*)(ldsB + ((n * 128 + kbB) ^ ((n & 7) << 4)));
      }
#pragma unroll
      for (int i = 0; i < 2; ++i)
#pragma unroll
        for (int j = 0; j < 4; ++j)
          acc[i][j] = __builtin_amdgcn_mfma_f32_16x16x32_bf16(av[i], bv[j],
                                                              acc[i][j], 0, 0, 0);
    }
  }
  {
    int g = lane >> 4, lo = lane & 15;
#pragma unroll
    for (int i = 0; i < 2; ++i) {
#pragma unroll
      for (int qv = 0; qv < 4; ++qv) {
        int row = wr * 32 + i * 16 + g * 4 + qv;
        float rs2v = lrs2[row];
        float rm2  = rs2v * lmu2[row];
        float sS = 0.f, sQ = 0.f, sP0 = 0.f, sP1 = 0.f;
#pragma unroll
        for (int j = 0; j < 4; ++j) {
          int col = wc * 64 + j * 16 + lo;
          float t2 = fmaf(rs2v, acc[i][j][qv], fmaf(-rm2, G2[col], B2c[col]));
          t2 = t2 >= 0.f ? t2 : 0.01f * t2;
          sS += t2; sQ += t2 * t2;
          float tg = t2 * g3v[col];
          sP0 = fmaf(tg, cw3[col * 2 + 0], sP0);
          sP1 = fmaf(tg, cw3[col * 2 + 1], sP1);
        }
#pragma unroll
        for (int o = 1; o < 16; o <<= 1) {
          sS += __shfl_xor(sS, o); sQ += __shfl_xor(sQ, o);
          sP0 += __shfl_xor(sP0, o); sP1 += __shfl_xor(sP1, o);
        }
        if (lo == 0) {
          lred[row][wc][0] = sS; lred[row][wc][1] = sQ;
          lred[row][wc][2] = sP0; lred[row][wc][3] = sP1;
        }
      }
    }
  }
  __syncthreads();
  if (tid < 64) {
    float S  = lred[tid][0][0] + lred[tid][1][0];
    float Q  = lred[tid][0][1] + lred[tid][1][1];
    float P0 = lred[tid][0][2] + lred[tid][1][2];
    float P1 = lred[tid][0][3] + lred[tid][1][3];
    float m3 = S * (1.f / 128.f);
    float v3 = Q * (1.f / 128.f) - m3 * m3;
    float r3 = rsqrtf(v3 + kEPS);
    size_t e = (size_t)le[tid];
    out[e * 2 + 0] = fmaf(r3, P0 - m3 * G3[0], B3c[0]);
    out[e * 2 + 1] = fmaf(r3, P1 - m3 * G3[1], B3c[1]);
  }
}

extern "C" void kernel_launch(void* const* d_in, const int* in_sizes, int n_in,
                              void* d_out, int out_size, void* d_ws, size_t ws_size,
                              hipStream_t stream) {
  const float* x      = (const float*)d_in[0];
  const int*   eidx   = (const int*)  d_in[1];
  const float* eattr  = (const float*)d_in[2];
  const float* bn_ng  = (const float*)d_in[3];
  const float* bn_nb  = (const float*)d_in[4];
  const float* bn_eg  = (const float*)d_in[5];
  const float* bn_eb  = (const float*)d_in[6];
  const float* lin_w  = (const float*)d_in[7];
  const float* lin_b  = (const float*)d_in[8];
  const float* w1     = (const float*)d_in[9];
  const float* b1     = (const float*)d_in[10];
  const float* w2     = (const float*)d_in[11];
  const float* b2     = (const float*)d_in[12];
  const float* mlng   = (const float*)d_in[13];
  const float* mlnb   = (const float*)d_in[14];
  const float* w_in   = (const float*)d_in[15];
  const float* conv_w = (const float*)d_in[16];
  const float* conv_b = (const float*)d_in[17];
  const float* w_x    = (const float*)d_in[18];
  const float* w_dt   = (const float*)d_in[19];
  const float* b_dt   = (const float*)d_in[20];
  const float* A_log  = (const float*)d_in[21];
  const float* Dm     = (const float*)d_in[22];
  const float* w_out  = (const float*)d_in[23];
  const float* ln1g   = (const float*)d_in[24];
  const float* ln1b   = (const float*)d_in[25];
  const float* cw1    = (const float*)d_in[26];
  const float* cb1    = (const float*)d_in[27];
  const float* ln2g   = (const float*)d_in[28];
  const float* ln2b   = (const float*)d_in[29];
  const float* cw2    = (const float*)d_in[30];
  const float* cb2    = (const float*)d_in[31];
  const float* ln3g   = (const float*)d_in[32];
  const float* ln3b   = (const float*)d_in[33];
  const float* cw3    = (const float*)d_in[34];
  const float* cb3    = (const float*)d_in[35];
  const int* src = eidx;
  const int* dst = eidx + kE;
  float* out = (float*)d_out;

  // ---- workspace layout ----
  char* ws = (char*)d_ws;
  const size_t MB = 1ull << 20;
  const size_t KB = 1024;
  if (ws_size < 212 * MB) return;
  float* bn_acc = (float*)ws;                       // 512 f32
  float* coef   = (float*)(ws + 4096);              // 512 f32
  float* A2     = (float*)(ws + 8192);              // 4096 f32
  ushort* wt = (ushort*)(ws + 64 * KB);
  ushort* wt_lin  = wt;             // 128x128
  ushort* wt_w1   = wt + 16384;     // 128x128
  ushort* wt_w2   = wt + 32768;     // 128x128
  ushort* wt_win  = wt + 49152;     // 512x128
  ushort* wt_wx   = wt + 114688;    // 128x256 (N=40 padded)
  ushort* wt_wout = wt + 147456;    // 128x256
  ushort* wt_uv   = wt + 180224;    // 512x128
  ushort* wt_cw2  = wt + 245760;    // 128x256
  float* mu   = (float*)(ws + 1 * MB);
  float* rsb  = (float*)(ws + 1 * MB + 256 * KB);
  float* s1b  = (float*)(ws + 1 * MB + 512 * KB);
  float* s2b  = (float*)(ws + 1 * MB + 768 * KB);
  float* vecs = (float*)(ws + 2 * MB);              // 772 f32
  int* cnt    = (int*)(ws + 2 * MB + 128 * KB);     // 32768
  int* base   = (int*)(ws + 2 * MB + 256 * KB);     // 32769
  int* run    = (int*)(ws + 2 * MB + 512 * KB);     // 32768
  int* eorder = (int*)(ws + 3 * MB);                // 262144
  float* h    = (float*)(ws + 4 * MB);              // 16 MB
  char*  S    = ws + 20 * MB;                       // phase-shared region
  // GNN phase
  float*  xn   = (float*)S;                    // 16 MB
  float*  agg  = (float*)(S + 16 * MB);        // 16 MB
  ushort* tmpb = (ushort*)(S + 32 * MB);       // 8 MB (bf16)
  ushort* msg0 = (ushort*)(S + 48 * MB);       // 64 MB (bf16)
  // mamba phase
  ushort* xzb = (ushort*)S;                    // N x 512 bf16 (32 MB)
  ushort* xcb = (ushort*)(S + 32 * MB);        // N x 256 bf16 (16 MB)
  float*  dbl = (float*)(S + 48 * MB);         // N x 40 f32 (5.25 MB)
  ushort* yb  = (ushort*)(S + 56 * MB);        // N x 256 bf16 (16 MB)
  // classifier phase
  ushort* UV = (ushort*)S;                     // N x 512 bf16 (32 MB)

  // ---- weight prep ----
  prep_wt<<<64,  256, 0, stream>>>(lin_w, 128, 128, wt_lin);
  prep_wt<<<64,  256, 0, stream>>>(w1,    128, 128, wt_w1);
  prep_wt<<<64,  256, 0, stream>>>(w2,    128, 128, wt_w2);
  prep_wt<<<256, 256, 0, stream>>>(w_in,  128, 512, wt_win);
  prep_wt<<<128, 256, 0, stream>>>(w_x,   256, 40,  wt_wx);
  prep_wt<<<128, 256, 0, stream>>>(w_out, 256, 128, wt_wout);
  prep_wt<<<128, 256, 0, stream>>>(cw2,   256, 128, wt_cw2);
  prep_uv<<<256, 256, 0, stream>>>(cw1, ln1g, wt_uv);
  prep_vecs<<<1, 256, 0, stream>>>(cw1, ln1b, cb1, cw2, ln2g, ln2b, cb2,
                                   cw3, ln3g, ln3b, cb3, ln1g, vecs);

  // ---- edge sort by dst (counting sort) ----
  hipMemsetAsync(cnt, 0, 32768 * 4, stream);
  hist_kernel<<<kE / 256, 256, 0, stream>>>(dst, cnt);
  scan32k<<<1, 1024, 0, stream>>>(cnt, base, run);
  scatter_ids<<<kE / 256, 256, 0, stream>>>(dst, run, eorder);

  // ---- GNN ----
  hipMemsetAsync(bn_acc, 0, 512 * 4, stream);
  bn_partial2<<<256, 256, 0, stream>>>(x, kN, bn_acc, bn_acc + 128);
  bn_partial2<<<512, 256, 0, stream>>>(eattr, kE, bn_acc + 256, bn_acc + 384);
  bn_finalize<<<1, 256, 0, stream>>>(bn_acc, bn_ng, bn_nb, bn_eg, bn_eb, coef);
  a2prep<<<16, 256, 0, stream>>>(A_log, A2);
  bn_apply<<<kN * kH / 1024, 256, 0, stream>>>(x, coef, xn);

  // msg0 = BN(ea)@lin_w  (pure streaming GEMM, bf16 out, no gather)
  gemm_mfma<0><<<dim3(kE / 128, 1), 256, 0, stream>>>(
      ALBN{eattr, coef + 256}, wt_lin, 128, 128, EPStoreBf{msg0, 128},
      nullptr, nullptr);
  // agg[dst] = sum relu(msg0 + lin_b + xn[src]) over sorted edge lists
  agg_fused<<<kN / 2, 256, 0, stream>>>(msg0, xn, eorder, base, src, lin_b, agg);

  // h = relu(leaky((xn+agg)@w1 + b1)@w2 + b2); w2 epilogue emits LN stats
  gemm_mfma<0><<<dim3(kN / 128, 1), 256, 0, stream>>>(
      ALAdd2{xn, agg}, wt_w1, 128, 128, EPBiasLeakyBf{tmpb, 128, b1},
      nullptr, nullptr);
  gemm_mfma<1><<<dim3(kN / 128, 1), 256, 0, stream>>>(
      ALBf{tmpb, 128}, wt_w2, 128, 128, EPBiasRelu{h, 128, b2}, mu, rsb);

  // ---- mamba x2 (stats produced by previous epilogue; dt fused in scan) ----
  for (int pass = 0; pass < 2; ++pass) {
    gemm_mfma<0><<<dim3(kN / 128, 4), 256, 0, stream>>>(
        ALLN{h, 128, mu, rsb, mlng, mlnb}, wt_win, 128, 512,
        EPStoreBf{xzb, 512}, nullptr, nullptr);
    conv_silu<<<kN, 256, 0, stream>>>(xzb, conv_w, conv_b, xcb);
    gemm_mfma<0><<<dim3(kN / 128, 1), 256, 0, stream>>>(
        ALBf{xcb, 256}, wt_wx, 256, 40, EPStore{dbl, 40}, nullptr, nullptr);
    scan_kernel<<<512, 256, 0, stream>>>(xcb, dbl, A2, w_dt, b_dt, yb);
    if (pass == 0) {
      gemm_mfma<1><<<dim3(kN / 128, 1), 256, 0, stream>>>(
          ALMambaY{yb, xcb, xzb, Dm}, wt_wout, 256, 128, EPResidH{h}, mu, rsb);
    } else {
      gemm_mfma<2><<<dim3(kN / 128, 1), 256, 0, stream>>>(
          ALMambaY{yb, xcb, xzb, Dm}, wt_wout, 256, 128, EPResidH{h}, s1b, s2b);
    }
  }

  // ---- fused edge classifier (bf16 UV, dst-sorted order, scatter out) ----
  gemm_mfma<0><<<dim3(kN / 128, 4), 256, 0, stream>>>(
      ALPlainF{h, 128}, wt_uv, 128, 512, EPStoreBf{UV, 512}, nullptr, nullptr);
  cls_fused<<<kE / 64, 256, 0, stream>>>(UV, src, dst, eorder, s1b, s2b, vecs,
                                         ln2g, wt_cw2, ln3g, cw3, out);
}